// Round 1
// baseline (8997.122 us; speedup 1.0000x reference)
//
#include <hip/hip_runtime.h>

#define DEVFN __device__ __forceinline__

// ---------------------------------------------------------------- utilities
struct OpSum { DEVFN float operator()(float a, float b) const { return a + b; } };
struct OpMax { DEVFN float operator()(float a, float b) const { return fmaxf(a, b); } };

// Recursive-halving butterfly over lane-distance D..1 on a per-lane value
// array v[0..CH). After completion each lane owns a shrunken slice; `base`
// is the owned slice's start index in the original [0, CH0) value space.
template<int CH, int D, typename OP, int NV>
DEVFN void halve(float (&v)[NV], int lane, int& base) {
  if constexpr (D >= 1) {
    OP op;
    if constexpr (CH > 1) {
      constexpr int H = CH / 2;
      #pragma unroll
      for (int i = 0; i < H; ++i) {
        float send = (lane & D) ? v[i] : v[H + i];
        float r = __shfl_xor(send, D);
        float keep = (lane & D) ? v[H + i] : v[i];
        v[i] = op(keep, r);
      }
      if (lane & D) base += H;
      halve<H, (D >> 1), OP, NV>(v, lane, base);
    } else {
      v[0] = op(v[0], __shfl_xor(v[0], D));
      halve<CH, (D >> 1), OP, NV>(v, lane, base);
    }
  }
}

// Sum + sumsq of channels a[OFF..OFF+CC) across all T threads of the block,
// written to prow[statoff + 0..2*CC). Deterministic (shfl tree + LDS combine).
template<int CC, int OFF, int NA, int T>
DEVFN void do_stats(const float (&a)[NA], int tid, float* spart, float* prow, int statoff) {
  float v[2 * CC];
  #pragma unroll
  for (int j = 0; j < CC; ++j) { float x = a[OFF + j]; v[2 * j] = x; v[2 * j + 1] = x * x; }
  int lane = tid & 63, base = 0;
  halve<2 * CC, 32, OpSum, 2 * CC>(v, lane, base);
  constexpr int F = (2 * CC) / 64 > 0 ? (2 * CC) / 64 : 1;
  int wv = tid >> 6;
  #pragma unroll
  for (int i = 0; i < F; ++i) spart[wv * 128 + base + i] = v[i];
  __syncthreads();
  constexpr int NW = T / 64;
  if (tid < 2 * CC) {
    float s2 = 0.f;
    #pragma unroll
    for (int w = 0; w < NW; ++w) s2 += spart[w * 128 + tid];
    prow[statoff + tid] = s2;
  }
  __syncthreads();
}

// ---------------------------------------------------------------- FPS
// One block per batch. Deterministic start idx 0; argmax ties -> lowest index
// (matches jnp.argmax). Per-thread 8 points in registers.
__global__ __launch_bounds__(1024) void fps_kernel(const float* __restrict__ pts,
                                                   float4* __restrict__ cent) {
  const int b = blockIdx.x;
  const int t = threadIdx.x;
  __shared__ float rd[16];
  __shared__ int ri[16];
  __shared__ int sbi;
  const float* p = pts + (size_t)b * 8192 * 3;
  float px[8], py[8], pz[8], dd[8];
  #pragma unroll
  for (int j = 0; j < 8; ++j) {
    const int i = t + j * 1024;
    px[j] = p[i * 3 + 0]; py[j] = p[i * 3 + 1]; pz[j] = p[i * 3 + 2];
    dd[j] = 1e10f;
  }
  float cx = p[0], cy = p[1], cz = p[2];
  for (int it = 0; it < 1024; ++it) {
    if (t == 0) cent[b * 1024 + it] = make_float4(cx, cy, cz, 0.f);
    float bd = -1.f; int bidx = 0;
    #pragma unroll
    for (int j = 0; j < 8; ++j) {
      const float dx = px[j] - cx, dy = py[j] - cy, dz = pz[j] - cz;
      float d = dx * dx + dy * dy + dz * dz;
      d = fminf(dd[j], d);
      dd[j] = d;
      if (d > bd) { bd = d; bidx = t + j * 1024; }   // ascending j -> lowest idx on tie
    }
    #pragma unroll
    for (int m = 32; m >= 1; m >>= 1) {
      const float od = __shfl_xor(bd, m);
      const int   oi = __shfl_xor(bidx, m);
      if (od > bd || (od == bd && oi < bidx)) { bd = od; bidx = oi; }
    }
    if ((t & 63) == 0) { rd[t >> 6] = bd; ri[t >> 6] = bidx; }
    __syncthreads();
    if (t == 0) {
      float gb = rd[0]; int gi = ri[0];
      #pragma unroll
      for (int w = 1; w < 16; ++w) {
        const float od = rd[w]; const int oi = ri[w];
        if (od > gb || (od == gb && oi < gi)) { gb = od; gi = oi; }
      }
      sbi = gi;
    }
    __syncthreads();
    const int cur = sbi;
    cx = p[cur * 3 + 0]; cy = p[cur * 3 + 1]; cz = p[cur * 3 + 2];  // same-addr broadcast load
  }
}

// ---------------------------------------------------------------- kNN
// One wave per query. Maintains top-64 (d2,idx) as sorted u64 keys across the
// wave; bitonic sort of each 64-candidate chunk + bitonic merge. Sorted
// ascending by (d2, idx) so first K entries serve all three scales.
__global__ __launch_bounds__(256) void knn_kernel(const float* __restrict__ pts,
                                                  const float4* __restrict__ cent,
                                                  int* __restrict__ knn) {
  const int wid = (blockIdx.x * 256 + threadIdx.x) >> 6;
  const int lane = threadIdx.x & 63;
  const int b = wid >> 10;
  const float4 q = cent[wid];
  const float q2 = q.x * q.x + q.y * q.y + q.z * q.z;
  const float* p = pts + (size_t)b * 8192 * 3;
  unsigned long long R = ~0ull;
  for (int c0 = 0; c0 < 8192; c0 += 64) {
    const int i = c0 + lane;
    const float x = p[i * 3], y = p[i * 3 + 1], z = p[i * 3 + 2];
    const float p2 = x * x + y * y + z * z;
    const float dot = q.x * x + q.y * y + q.z * z;
    float d2 = q2 - 2.f * dot + p2;
    d2 = fmaxf(d2, 0.f);                 // kill tiny negative self-distance / -0
    unsigned u = __float_as_uint(d2);
    u = (u & 0x80000000u) ? ~u : (u | 0x80000000u);
    unsigned long long key = ((unsigned long long)u << 32) | (unsigned)i;
    const unsigned long long rmax = __shfl(R, 63);
    if (__all(key >= rmax)) continue;    // no candidate can enter top-64
    // full bitonic sort (ascending across lanes)
    #pragma unroll
    for (int kk = 2; kk <= 64; kk <<= 1) {
      #pragma unroll
      for (int j = kk >> 1; j >= 1; j >>= 1) {
        const unsigned long long o = __shfl_xor(key, j);
        const bool up = ((lane & kk) == 0);
        const bool takeMin = (((lane & j) == 0) == up);
        key = takeMin ? (key < o ? key : o) : (key > o ? key : o);
      }
    }
    // merge: R(asc) with reversed C(desc) -> elementwise min is bitonic, holds 64 smallest
    const unsigned long long crev = __shfl_xor(key, 63);
    unsigned long long m = R < crev ? R : crev;
    #pragma unroll
    for (int j = 32; j >= 1; j >>= 1) {
      const unsigned long long o = __shfl_xor(m, j);
      const bool takeMin = ((lane & j) == 0);
      m = takeMin ? (m < o ? m : o) : (m > o ? m : o);
    }
    R = m;
  }
  knn[wid * 64 + lane] = (int)(R & 0xffffffffu);
}

// ---------------------------------------------------------------- weight transpose
__global__ __launch_bounds__(256) void transpose_kernel(const float* __restrict__ w,
                                                        float* __restrict__ wt, int O, int C) {
  const int i = blockIdx.x * 256 + threadIdx.x;
  if (i < O * C) { const int o = i / C, c = i - o * C; wt[c * O + o] = w[o * C + c]; }
}

// ---------------------------------------------------------------- BN finalize
__global__ __launch_bounds__(256) void finalize_kernel(const float* __restrict__ partials, int nb,
    const float* __restrict__ g, const float* __restrict__ be, float n,
    float* __restrict__ sc, float* __restrict__ sh, int CO) {
  __shared__ float tot[256];
  const int j = threadIdx.x;
  if (j < 2 * CO) {
    float s = 0.f;
    for (int r = 0; r < nb; ++r) s += partials[(size_t)r * 256 + j];
    tot[j] = s;
  }
  __syncthreads();
  if (j < CO) {
    const float m = tot[2 * j] / n;
    const float v = tot[2 * j + 1] / n - m * m;
    const float inv = 1.0f / sqrtf(v + 1e-5f);
    const float scv = g[j] * inv;
    sc[j] = scv;
    sh[j] = be[j] - m * scv;
  }
}

// ---------------------------------------------------------------- layer-2 chunk helper
template<int CHI, int K_, int C1, int C2, int L, int BOFF, int T>
DEVFN void layer2_chunk(const float* myrow, const float* __restrict__ w2t,
                        const float* __restrict__ b2, const float* __restrict__ sc2,
                        const float* __restrict__ sh2, int tid, int b, int s,
                        float* spart, float* prow, float* __restrict__ out) {
  constexpr int CB = CHI * 64;
  float a2[64];
  #pragma unroll
  for (int j = 0; j < 64; ++j) a2[j] = b2[CB + j];
  for (int c = 0; c < C1; ++c) {
    const float zc = myrow[c];
    #pragma unroll
    for (int j = 0; j < 64; ++j) a2[j] += zc * w2t[c * C2 + CB + j];
  }
  if constexpr (L == 2) {
    do_stats<64, 0, 64, T>(a2, tid, spart, prow, 2 * CB);
  } else {
    #pragma unroll
    for (int j = 0; j < 64; ++j) a2[j] = fmaxf(0.f, a2[j] * sc2[CB + j] + sh2[CB + j]);
    int lane = tid & 63, base = 0;
    halve<64, (K_ >> 1), OpMax, 64>(a2, lane, base);
    constexpr int F = 64 / K_;
    #pragma unroll
    for (int i = 0; i < F; ++i)
      out[(size_t)(b * 1024 + s) * 320 + BOFF + CB + base + i] = a2[i];
  }
}

// ---------------------------------------------------------------- fused MLP pass
// L=0/1/2: compute forward up to layer L, emit per-block (sum,sumsq) partials
// of pre-BN x_L. L=3: full forward + BN affine + relu + max-over-K + store.
template<int K_, int C0, int C1, int C2, int L, int BOFF, int T>
__global__ __launch_bounds__(T) void pass_kernel(
    const float* __restrict__ pts, const int* __restrict__ knn,
    const float* __restrict__ w0, const float* __restrict__ b0,
    const float* __restrict__ w1t, const float* __restrict__ b1,
    const float* __restrict__ w2t, const float* __restrict__ b2,
    const float* __restrict__ scsh, float* __restrict__ partials,
    float* __restrict__ out) {
  constexpr int CMAX = (C0 > C1 ? C0 : C1);
  constexpr int ROWW = (L >= 1) ? (CMAX + 1) : 1;
  constexpr int SPN = (L <= 2) ? (T / 64) * 128 : 1;
  __shared__ float zrow[T * ROWW];
  __shared__ float spart[SPN];
  const int tid = threadIdx.x;
  const int e = blockIdx.x * T + tid;
  const int b = e / (1024 * K_);
  const int rem = e - b * (1024 * K_);
  const int s = rem / K_;
  const int k = rem - s * K_;
  const int pidx = knn[(b * 1024 + s) * 64 + k];
  const float* pp = pts + ((size_t)b * 8192 + pidx) * 3;
  const float zx = pp[0], zy = pp[1], zz = pp[2];
  float* prow = partials + (size_t)blockIdx.x * 256;

  // layer 0 (3 -> C0), weights wave-uniform -> scalar loads
  float a0[C0];
  #pragma unroll
  for (int o = 0; o < C0; ++o)
    a0[o] = b0[o] + zx * w0[o * 3 + 0] + zy * w0[o * 3 + 1] + zz * w0[o * 3 + 2];

  if constexpr (L == 0) {
    do_stats<C0, 0, C0, T>(a0, tid, spart, prow, 0);
    return;
  }
  {
    const float* sc0 = scsh + 0;
    const float* sh0 = scsh + 128;
    float* myrow = zrow + tid * ROWW;
    #pragma unroll
    for (int o = 0; o < C0; ++o) myrow[o] = fmaxf(0.f, a0[o] * sc0[o] + sh0[o]);

    // layer 1 (C0 -> C1)
    float a1[C1];
    #pragma unroll
    for (int o = 0; o < C1; ++o) a1[o] = b1[o];
    for (int c = 0; c < C0; ++c) {
      const float zc = myrow[c];
      #pragma unroll
      for (int o = 0; o < C1; ++o) a1[o] += zc * w1t[c * C1 + o];
    }
    if constexpr (L == 1) {
      do_stats<(C1 > 64 ? 64 : C1), 0, C1, T>(a1, tid, spart, prow, 0);
      if constexpr (C1 > 64) do_stats<C1 - 64, 64, C1, T>(a1, tid, spart, prow, 128);
      return;
    }
    const float* sc1 = scsh + 256;
    const float* sh1 = scsh + 384;
    #pragma unroll
    for (int o = 0; o < C1; ++o) myrow[o] = fmaxf(0.f, a1[o] * sc1[o] + sh1[o]);

    // layer 2 (C1 -> C2), chunked by 64 output channels
    const float* sc2 = scsh + 512;
    const float* sh2 = scsh + 640;
    layer2_chunk<0, K_, C1, C2, L, BOFF, T>(myrow, w2t, b2, sc2, sh2, tid, b, s, spart, prow, out);
    if constexpr (C2 > 64)
      layer2_chunk<1, K_, C1, C2, L, BOFF, T>(myrow, w2t, b2, sc2, sh2, tid, b, s, spart, prow, out);
  }
}

// ---------------------------------------------------------------- host side
template<int K_, int C0, int C1, int C2, int BOFF>
static void run_branch(const float* pts, const int* knn,
                       const float* const* W_, const float* const* B_,
                       const float* const* G_, const float* const* BE_,
                       float* scsh, float* partials, float* w1t, float* w2t,
                       float* out, hipStream_t stream) {
  constexpr int T = 128;
  constexpr int NE = 8 * 1024 * K_;
  constexpr int NB = NE / T;
  transpose_kernel<<<(C0 * C1 + 255) / 256, 256, 0, stream>>>(W_[1], w1t, C1, C0);
  transpose_kernel<<<(C1 * C2 + 255) / 256, 256, 0, stream>>>(W_[2], w2t, C2, C1);
  pass_kernel<K_, C0, C1, C2, 0, BOFF, T><<<NB, T, 0, stream>>>(
      pts, knn, W_[0], B_[0], w1t, B_[1], w2t, B_[2], scsh, partials, out);
  finalize_kernel<<<1, 256, 0, stream>>>(partials, NB, G_[0], BE_[0], (float)NE,
                                         scsh + 0, scsh + 128, C0);
  pass_kernel<K_, C0, C1, C2, 1, BOFF, T><<<NB, T, 0, stream>>>(
      pts, knn, W_[0], B_[0], w1t, B_[1], w2t, B_[2], scsh, partials, out);
  finalize_kernel<<<1, 256, 0, stream>>>(partials, NB, G_[1], BE_[1], (float)NE,
                                         scsh + 256, scsh + 384, C1);
  pass_kernel<K_, C0, C1, C2, 2, BOFF, T><<<NB, T, 0, stream>>>(
      pts, knn, W_[0], B_[0], w1t, B_[1], w2t, B_[2], scsh, partials, out);
  finalize_kernel<<<1, 256, 0, stream>>>(partials, NB, G_[2], BE_[2], (float)NE,
                                         scsh + 512, scsh + 640, C2);
  pass_kernel<K_, C0, C1, C2, 3, BOFF, T><<<NB, T, 0, stream>>>(
      pts, knn, W_[0], B_[0], w1t, B_[1], w2t, B_[2], scsh, partials, out);
}

extern "C" void kernel_launch(void* const* d_in, const int* in_sizes, int n_in,
                              void* d_out, int out_size, void* d_ws, size_t ws_size,
                              hipStream_t stream) {
  (void)in_sizes; (void)n_in; (void)out_size; (void)ws_size;
  const float* pts = (const float*)d_in[0];
  const float* W_[9]; const float* B_[9]; const float* G_[9]; const float* BE_[9];
  for (int m = 0; m < 9; ++m) {
    W_[m]  = (const float*)d_in[1 + m * 4 + 0];
    B_[m]  = (const float*)d_in[1 + m * 4 + 1];
    G_[m]  = (const float*)d_in[1 + m * 4 + 2];
    BE_[m] = (const float*)d_in[1 + m * 4 + 3];
  }
  char* ws = (char*)d_ws;
  float4* cent    = (float4*)ws;                                   // 8192 * 16 B
  int*    knn     = (int*)(ws + 131072);                           // 524288 * 4 B
  float*  partials= (float*)(ws + 131072 + 2097152);               // 4096 * 256 * 4 B
  float*  scsh    = (float*)(ws + 131072 + 2097152 + 4194304);     // 768 * 4 B
  float*  w1t     = (float*)(ws + 131072 + 2097152 + 4194304 + 4096);
  float*  w2t     = w1t + 64 * 96;
  float*  out     = (float*)d_out;

  fps_kernel<<<8, 1024, 0, stream>>>(pts, cent);
  knn_kernel<<<2048, 256, 0, stream>>>(pts, cent, knn);

  run_branch<16, 32, 32, 64, 0>(pts, knn, W_ + 0, B_ + 0, G_ + 0, BE_ + 0,
                                scsh, partials, w1t, w2t, out, stream);
  run_branch<32, 64, 64, 128, 64>(pts, knn, W_ + 3, B_ + 3, G_ + 3, BE_ + 3,
                                  scsh, partials, w1t, w2t, out, stream);
  run_branch<64, 64, 96, 128, 192>(pts, knn, W_ + 6, B_ + 6, G_ + 6, BE_ + 6,
                                   scsh, partials, w1t, w2t, out, stream);
}

// Round 5
// 3937.615 us; speedup vs baseline: 2.2849x; 2.2849x over previous
//
#include <hip/hip_runtime.h>
#include <hip/hip_bf16.h>

#define DEVFN __device__ __forceinline__

// ---------------------------------------------------------------- utilities
struct OpSum { DEVFN float operator()(float a, float b) const { return a + b; } };
struct OpMax { DEVFN float operator()(float a, float b) const { return fmaxf(a, b); } };

// Recursive-halving butterfly over lane-distance D..1 on a per-lane value
// array v[0..CH). After completion each lane owns a shrunken slice; `base`
// is the owned slice's start index in the original [0, CH0) value space.
template<int CH, int D, typename OP, int NV>
DEVFN void halve(float (&v)[NV], int lane, int& base) {
  if constexpr (D >= 1) {
    OP op;
    if constexpr (CH > 1) {
      constexpr int H = CH / 2;
      #pragma unroll
      for (int i = 0; i < H; ++i) {
        float send = (lane & D) ? v[i] : v[H + i];
        float r = __shfl_xor(send, D);
        float keep = (lane & D) ? v[H + i] : v[i];
        v[i] = op(keep, r);
      }
      if (lane & D) base += H;
      halve<H, (D >> 1), OP, NV>(v, lane, base);
    } else {
      v[0] = op(v[0], __shfl_xor(v[0], D));
      halve<CH, (D >> 1), OP, NV>(v, lane, base);
    }
  }
}

// Sum + sumsq of channels a[OFF..OFF+CC) across all T threads of the block,
// written to prow[statoff + 0..2*CC). Deterministic (shfl tree + LDS combine).
// spart rows are 256 floats per wave. Requires 2*CC <= min(T, 64... ) — all
// uses here have 2*CC = 64 <= T.
template<int CC, int OFF, int NA, int T>
DEVFN void do_stats(const float (&a)[NA], int tid, float* spart, float* prow, int statoff) {
  float v[2 * CC];
  #pragma unroll
  for (int j = 0; j < CC; ++j) { float x = a[OFF + j]; v[2 * j] = x; v[2 * j + 1] = x * x; }
  int lane = tid & 63, base = 0;
  halve<2 * CC, 32, OpSum, 2 * CC>(v, lane, base);
  constexpr int F = (2 * CC) / 64 > 0 ? (2 * CC) / 64 : 1;
  int wv = tid >> 6;
  #pragma unroll
  for (int i = 0; i < F; ++i) spart[wv * 256 + base + i] = v[i];
  __syncthreads();
  constexpr int NW = T / 64;
  if (tid < 2 * CC) {
    float s2 = 0.f;
    #pragma unroll
    for (int w = 0; w < NW; ++w) s2 += spart[w * 256 + tid];
    prow[statoff + tid] = s2;
  }
  __syncthreads();
}

// ---------------------------------------------------------------- FPS
// One block of 512 per batch, 16 pts/thread. Proven selection semantics
// (explicit (dist, idx) compares); coords re-fetched from global by index
// (same-address broadcast load). Single barrier per iteration via parity
// double-buffered LDS slots. Functionally equivalent to round-1 (verified:
// R3 and R4 produced bit-identical outputs).
__global__ __launch_bounds__(512) void fps_kernel(const float* __restrict__ pts,
                                                  float4* __restrict__ cent) {
  const int b = blockIdx.x, t = threadIdx.x;
  const int lane = t & 63, wv = t >> 6;
  __shared__ float rd[2][8];
  __shared__ int   ri[2][8];
  const float* p = pts + (size_t)b * 8192 * 3;
  float px[16], py[16], pz[16], dd[16];
  #pragma unroll
  for (int j = 0; j < 16; ++j) {
    const int i = t + j * 512;
    px[j] = p[i * 3]; py[j] = p[i * 3 + 1]; pz[j] = p[i * 3 + 2];
    dd[j] = 1e10f;
  }
  float cx = p[0], cy = p[1], cz = p[2];
  for (int it = 0; it < 1024; ++it) {
    if (t == 0) cent[b * 1024 + it] = make_float4(cx, cy, cz, 0.f);
    const int par = it & 1;
    float bd = -1.f; int bi = 0;
    #pragma unroll
    for (int j = 0; j < 16; ++j) {
      const float dx = px[j] - cx, dy = py[j] - cy, dz = pz[j] - cz;
      float d = fminf(dd[j], dx * dx + dy * dy + dz * dz);
      dd[j] = d;
      if (d > bd) { bd = d; bi = t + j * 512; }   // ascending j -> lowest idx on tie
    }
    #pragma unroll
    for (int m = 32; m >= 1; m >>= 1) {
      const float od = __shfl_xor(bd, m);
      const int   oi = __shfl_xor(bi, m);
      if (od > bd || (od == bd && oi < bi)) { bd = od; bi = oi; }
    }
    if (lane == 0) { rd[par][wv] = bd; ri[par][wv] = bi; }
    __syncthreads();
    float gb = rd[par][0]; int gi = ri[par][0];
    #pragma unroll
    for (int w = 1; w < 8; ++w) {
      const float od = rd[par][w]; const int oi = ri[par][w];
      if (od > gb || (od == gb && oi < gi)) { gb = od; gi = oi; }
    }
    cx = p[gi * 3]; cy = p[gi * 3 + 1]; cz = p[gi * 3 + 2];  // broadcast load
  }
}

// ---------------------------------------------------------------- kNN
// One wave per query; sorted top-64 (d2,idx) u64 keys; prefix serves k=16/32.
__global__ __launch_bounds__(256) void knn_kernel(const float* __restrict__ pts,
                                                  const float4* __restrict__ cent,
                                                  int* __restrict__ knn) {
  const int wid = (blockIdx.x * 256 + threadIdx.x) >> 6;
  const int lane = threadIdx.x & 63;
  const int b = wid >> 10;
  const float4 q = cent[wid];
  const float q2 = q.x * q.x + q.y * q.y + q.z * q.z;
  const float* p = pts + (size_t)b * 8192 * 3;
  unsigned long long R = ~0ull;
  for (int c0 = 0; c0 < 8192; c0 += 64) {
    const int i = c0 + lane;
    const float x = p[i * 3], y = p[i * 3 + 1], z = p[i * 3 + 2];
    const float p2 = x * x + y * y + z * z;
    const float dot = q.x * x + q.y * y + q.z * z;
    float d2 = q2 - 2.f * dot + p2;
    d2 = fmaxf(d2, 0.f);
    unsigned u = __float_as_uint(d2);
    u = (u & 0x80000000u) ? ~u : (u | 0x80000000u);
    unsigned long long key = ((unsigned long long)u << 32) | (unsigned)i;
    const unsigned long long rmax = __shfl(R, 63);
    if (__all(key >= rmax)) continue;
    #pragma unroll
    for (int kk = 2; kk <= 64; kk <<= 1) {
      #pragma unroll
      for (int j = kk >> 1; j >= 1; j >>= 1) {
        const unsigned long long o = __shfl_xor(key, j);
        const bool up = ((lane & kk) == 0);
        const bool takeMin = (((lane & j) == 0) == up);
        key = takeMin ? (key < o ? key : o) : (key > o ? key : o);
      }
    }
    const unsigned long long crev = __shfl_xor(key, 63);
    unsigned long long m = R < crev ? R : crev;
    #pragma unroll
    for (int j = 32; j >= 1; j >>= 1) {
      const unsigned long long o = __shfl_xor(m, j);
      const bool takeMin = ((lane & j) == 0);
      m = takeMin ? (m < o ? m : o) : (m > o ? m : o);
    }
    R = m;
  }
  knn[wid * 64 + lane] = (int)(R & 0xffffffffu);
}

// ---------------------------------------------------------------- weight transpose (w2 only)
__global__ __launch_bounds__(256) void transpose_kernel(const float* __restrict__ w,
                                                        float* __restrict__ wt, int O, int C) {
  const int i = blockIdx.x * 256 + threadIdx.x;
  if (i < O * C) { const int o = i / C, c = i - o * C; wt[c * O + o] = w[o * C + c]; }
}

// ---------------------------------------------------------------- stats reduction, stage A
// 32 blocks x 256 threads; block r sums its fixed row chunk (deterministic).
__global__ __launch_bounds__(256) void reduce_rows_kernel(const float* __restrict__ partials,
                                                          int nb, float* __restrict__ out32) {
  const int r0 = blockIdx.x, j = threadIdx.x;
  const int chunk = (nb + 31) / 32;
  const int lo = r0 * chunk;
  const int hi = (lo + chunk < nb) ? lo + chunk : nb;
  float s = 0.f;
  for (int r = lo; r < hi; ++r) s += partials[(size_t)r * 256 + j];
  out32[r0 * 256 + j] = s;
}

// ---------------------------------------------------------------- BN finalize
__global__ __launch_bounds__(256) void finalize_kernel(const float* __restrict__ partials, int nb,
    const float* __restrict__ g, const float* __restrict__ be, float n,
    float* __restrict__ sc, float* __restrict__ sh, int CO) {
  __shared__ float tot[256];
  const int j = threadIdx.x;
  if (j < 2 * CO) {
    float s = 0.f;
    for (int r = 0; r < nb; ++r) s += partials[(size_t)r * 256 + j];
    tot[j] = s;
  }
  __syncthreads();
  if (j < CO) {
    const float m = tot[2 * j] / n;
    const float v = tot[2 * j + 1] / n - m * m;
    const float inv = 1.0f / sqrtf(v + 1e-5f);
    const float scv = g[j] * inv;
    sc[j] = scv;
    sh[j] = be[j] - m * scv;
  }
}

// ---------------------------------------------------------------- fused MLP pass
// L=0/1/2: forward up to layer L, emit per-block (sum,sumsq) partials of
// pre-BN x_L. L=3: full forward + BN + relu + max-over-K + store.
// act0 lives in registers (layer-1 c-loop unrolled); act1 stored bf16 in LDS.
template<int K_, int C0, int C1, int C2, int L, int BOFF, int T>
__global__ __launch_bounds__(T) void pass_kernel(
    const float* __restrict__ pts, const int* __restrict__ knnidx,
    const float* __restrict__ w0, const float* __restrict__ b0,
    const float* __restrict__ w1, const float* __restrict__ b1,
    const float* __restrict__ w2t, const float* __restrict__ b2,
    const float* __restrict__ scsh, float* __restrict__ partials,
    float* __restrict__ out) {
  constexpr int RS = C1 + 1;
  constexpr int NAROW = (L >= 2) ? T * RS : 1;
  __shared__ __hip_bfloat16 arow[NAROW];
  __shared__ float spart[(T / 64) * 256];
  const int tid = threadIdx.x;
  const int lane = tid & 63;
  const int e = blockIdx.x * T + tid;
  const int b = e / (1024 * K_);
  const int rem = e - b * (1024 * K_);
  const int s = rem / K_;
  const int pidx = knnidx[(b * 1024 + s) * 64 + (rem - s * K_)];
  const float* pp = pts + ((size_t)b * 8192 + pidx) * 3;
  const float zx = pp[0], zy = pp[1], zz = pp[2];
  float* prow = partials + (size_t)blockIdx.x * 256;

  // layer 0 (3 -> C0)
  float a0[C0];
  #pragma unroll
  for (int o = 0; o < C0; ++o)
    a0[o] = b0[o] + zx * w0[3 * o] + zy * w0[3 * o + 1] + zz * w0[3 * o + 2];

  if constexpr (L == 0) {
    do_stats<(C0 > 32 ? 32 : C0), 0, C0, T>(a0, tid, spart, prow, 0);
    if constexpr (C0 > 32) do_stats<C0 - 32, 32, C0, T>(a0, tid, spart, prow, 64);
    return;
  }
  {
    const float* sc0 = scsh + 0;
    const float* sh0 = scsh + 128;
    #pragma unroll
    for (int o = 0; o < C0; ++o) a0[o] = fmaxf(0.f, a0[o] * sc0[o] + sh0[o]);
  }

  // layer 1 (C0 -> C1): one output at a time, c unrolled over register act0
  if constexpr (L == 1) {
    float* swl = spart + (tid >> 6) * 256;
    for (int o = 0; o < C1; ++o) {
      float s0 = 0.f, s1 = 0.f, s2 = 0.f, s3 = 0.f;
      #pragma unroll
      for (int c = 0; c < C0; c += 4) {
        s0 += a0[c]     * w1[o * C0 + c];
        s1 += a0[c + 1] * w1[o * C0 + c + 1];
        s2 += a0[c + 2] * w1[o * C0 + c + 2];
        s3 += a0[c + 3] * w1[o * C0 + c + 3];
      }
      const float x = b1[o] + ((s0 + s1) + (s2 + s3));
      float sm = x, sq = x * x;
      #pragma unroll
      for (int m = 32; m >= 1; m >>= 1) { sm += __shfl_xor(sm, m); sq += __shfl_xor(sq, m); }
      if (lane == 0) { swl[2 * o] = sm; swl[2 * o + 1] = sq; }
    }
    __syncthreads();
    // BUGFIX (R2-R4): 2*C1 can exceed T (branch 3: 192 > 128). Strided loop so
    // ALL columns are written; the old `if (tid < 2*C1)` left prow[128..191]
    // stale -> garbage var -> sc1~0 -> dead channels 64..95 (absmax 2.92).
    for (int col = tid; col < 2 * C1; col += T) {
      float s2_ = 0.f;
      #pragma unroll
      for (int w = 0; w < T / 64; ++w) s2_ += spart[w * 256 + col];
      prow[col] = s2_;
    }
    return;
  }

  // L >= 2: act1 -> LDS (bf16)
  {
    const float* sc1 = scsh + 256;
    const float* sh1 = scsh + 384;
    for (int o = 0; o < C1; ++o) {
      float s0 = 0.f, s1 = 0.f, s2 = 0.f, s3 = 0.f;
      #pragma unroll
      for (int c = 0; c < C0; c += 4) {
        s0 += a0[c]     * w1[o * C0 + c];
        s1 += a0[c + 1] * w1[o * C0 + c + 1];
        s2 += a0[c + 2] * w1[o * C0 + c + 2];
        s3 += a0[c + 3] * w1[o * C0 + c + 3];
      }
      const float x = b1[o] + ((s0 + s1) + (s2 + s3));
      arow[tid * RS + o] = __float2bfloat16(fmaxf(0.f, x * sc1[o] + sh1[o]));
    }
  }

  // layer 2 (C1 -> C2), output chunks of 32
  const float* sc2 = scsh + 512;
  const float* sh2 = scsh + 640;
  const size_t orow = (size_t)(b * 1024 + s) * 320 + BOFF;
  #pragma unroll
  for (int CB = 0; CB < C2; CB += 32) {
    float acc[32];
    #pragma unroll
    for (int j = 0; j < 32; ++j) acc[j] = b2[CB + j];
    for (int c = 0; c < C1; ++c) {
      const float zc = __bfloat162float(arow[tid * RS + c]);
      #pragma unroll
      for (int j = 0; j < 32; ++j) acc[j] += zc * w2t[c * C2 + CB + j];
    }
    if constexpr (L == 2) {
      do_stats<32, 0, 32, T>(acc, tid, spart, prow, 2 * CB);
    } else {
      #pragma unroll
      for (int j = 0; j < 32; ++j) acc[j] = fmaxf(0.f, acc[j] * sc2[CB + j] + sh2[CB + j]);
      int base = 0;
      halve<32, (K_ >> 1), OpMax, 32>(acc, lane, base);
      constexpr int F = (32 / K_ > 0) ? (32 / K_) : 1;  // K=64: lane pairs dup-write same value
      #pragma unroll
      for (int i = 0; i < F; ++i) out[orow + CB + base + i] = acc[i];
    }
  }
}

// ---------------------------------------------------------------- host side
template<int K_, int C0, int C1, int C2, int BOFF>
static void run_branch(const float* pts, const int* knn_,
                       const float* const* W_, const float* const* B_,
                       const float* const* G_, const float* const* BE_,
                       float* scsh, float* partials, float* partials2, float* w2t,
                       float* out, hipStream_t stream) {
  constexpr int T = 128;
  constexpr int NE = 8 * 1024 * K_;
  constexpr int NB = NE / T;
  transpose_kernel<<<(C1 * C2 + 255) / 256, 256, 0, stream>>>(W_[2], w2t, C2, C1);
  pass_kernel<K_, C0, C1, C2, 0, BOFF, T><<<NB, T, 0, stream>>>(
      pts, knn_, W_[0], B_[0], W_[1], B_[1], w2t, B_[2], scsh, partials, out);
  reduce_rows_kernel<<<32, 256, 0, stream>>>(partials, NB, partials2);
  finalize_kernel<<<1, 256, 0, stream>>>(partials2, 32, G_[0], BE_[0], (float)NE,
                                         scsh + 0, scsh + 128, C0);
  pass_kernel<K_, C0, C1, C2, 1, BOFF, T><<<NB, T, 0, stream>>>(
      pts, knn_, W_[0], B_[0], W_[1], B_[1], w2t, B_[2], scsh, partials, out);
  reduce_rows_kernel<<<32, 256, 0, stream>>>(partials, NB, partials2);
  finalize_kernel<<<1, 256, 0, stream>>>(partials2, 32, G_[1], BE_[1], (float)NE,
                                         scsh + 256, scsh + 384, C1);
  pass_kernel<K_, C0, C1, C2, 2, BOFF, T><<<NB, T, 0, stream>>>(
      pts, knn_, W_[0], B_[0], W_[1], B_[1], w2t, B_[2], scsh, partials, out);
  reduce_rows_kernel<<<32, 256, 0, stream>>>(partials, NB, partials2);
  finalize_kernel<<<1, 256, 0, stream>>>(partials2, 32, G_[2], BE_[2], (float)NE,
                                         scsh + 512, scsh + 640, C2);
  pass_kernel<K_, C0, C1, C2, 3, BOFF, T><<<NB, T, 0, stream>>>(
      pts, knn_, W_[0], B_[0], W_[1], B_[1], w2t, B_[2], scsh, partials, out);
}

extern "C" void kernel_launch(void* const* d_in, const int* in_sizes, int n_in,
                              void* d_out, int out_size, void* d_ws, size_t ws_size,
                              hipStream_t stream) {
  (void)in_sizes; (void)n_in; (void)out_size; (void)ws_size;
  const float* pts = (const float*)d_in[0];
  const float* W_[9]; const float* B_[9]; const float* G_[9]; const float* BE_[9];
  for (int m = 0; m < 9; ++m) {
    W_[m]  = (const float*)d_in[1 + m * 4 + 0];
    B_[m]  = (const float*)d_in[1 + m * 4 + 1];
    G_[m]  = (const float*)d_in[1 + m * 4 + 2];
    BE_[m] = (const float*)d_in[1 + m * 4 + 3];
  }
  char* ws = (char*)d_ws;
  float4* cent      = (float4*)ws;                                  // 131072 B
  int*    knn_      = (int*)(ws + 131072);                          // 2 MB
  float*  partials  = (float*)(ws + 131072 + 2097152);              // 4 MB
  float*  scsh      = (float*)(ws + 131072 + 2097152 + 4194304);    // 4 KB
  float*  w2t       = (float*)(ws + 131072 + 2097152 + 4194304 + 4096);   // 48 KB
  float*  partials2 = (float*)(ws + 131072 + 2097152 + 4194304 + 4096 + 49152); // 32 KB
  float*  out       = (float*)d_out;

  fps_kernel<<<8, 512, 0, stream>>>(pts, cent);
  knn_kernel<<<2048, 256, 0, stream>>>(pts, cent, knn_);

  run_branch<16, 32, 32, 64, 0>(pts, knn_, W_ + 0, B_ + 0, G_ + 0, BE_ + 0,
                                scsh, partials, partials2, w2t, out, stream);
  run_branch<32, 64, 64, 128, 64>(pts, knn_, W_ + 3, B_ + 3, G_ + 3, BE_ + 3,
                                  scsh, partials, partials2, w2t, out, stream);
  run_branch<64, 64, 96, 128, 192>(pts, knn_, W_ + 6, B_ + 6, G_ + 6, BE_ + 6,
                                   scsh, partials, partials2, w2t, out, stream);
}

// Round 6
// 3660.100 us; speedup vs baseline: 2.4582x; 1.0758x over previous
//
#include <hip/hip_runtime.h>
#include <hip/hip_bf16.h>

#define DEVFN __device__ __forceinline__

// ---------------------------------------------------------------- utilities
struct OpSum { DEVFN float operator()(float a, float b) const { return a + b; } };
struct OpMax { DEVFN float operator()(float a, float b) const { return fmaxf(a, b); } };

// Recursive-halving butterfly over lane-distance D..1 on a per-lane value
// array v[0..CH). After completion each lane owns a shrunken slice; `base`
// is the owned slice's start index in the original [0, CH0) value space.
template<int CH, int D, typename OP, int NV>
DEVFN void halve(float (&v)[NV], int lane, int& base) {
  if constexpr (D >= 1) {
    OP op;
    if constexpr (CH > 1) {
      constexpr int H = CH / 2;
      #pragma unroll
      for (int i = 0; i < H; ++i) {
        float send = (lane & D) ? v[i] : v[H + i];
        float r = __shfl_xor(send, D);
        float keep = (lane & D) ? v[H + i] : v[i];
        v[i] = op(keep, r);
      }
      if (lane & D) base += H;
      halve<H, (D >> 1), OP, NV>(v, lane, base);
    } else {
      v[0] = op(v[0], __shfl_xor(v[0], D));
      halve<CH, (D >> 1), OP, NV>(v, lane, base);
    }
  }
}

// Sum + sumsq of channels a[OFF..OFF+CC) across all T threads of the block,
// written to prow[statoff + 0..2*CC). Deterministic (shfl tree + LDS combine).
// spart rows are 256 floats per wave. All uses here have 2*CC = 64 <= T.
template<int CC, int OFF, int NA, int T>
DEVFN void do_stats(const float (&a)[NA], int tid, float* spart, float* prow, int statoff) {
  float v[2 * CC];
  #pragma unroll
  for (int j = 0; j < CC; ++j) { float x = a[OFF + j]; v[2 * j] = x; v[2 * j + 1] = x * x; }
  int lane = tid & 63, base = 0;
  halve<2 * CC, 32, OpSum, 2 * CC>(v, lane, base);
  constexpr int F = (2 * CC) / 64 > 0 ? (2 * CC) / 64 : 1;
  int wv = tid >> 6;
  #pragma unroll
  for (int i = 0; i < F; ++i) spart[wv * 256 + base + i] = v[i];
  __syncthreads();
  constexpr int NW = T / 64;
  if (tid < 2 * CC) {
    float s2 = 0.f;
    #pragma unroll
    for (int w = 0; w < NW; ++w) s2 += spart[w * 256 + tid];
    prow[statoff + tid] = s2;
  }
  __syncthreads();
}

// ---------------------------------------------------------------- FPS
// One block of 512 per batch, 16 pts/thread. (dist,~idx) packed as u64 key
// (d>=0 -> float bits order-preserving; ~idx -> lowest index wins ties,
// proven equivalent to explicit compares). Winner COORDS are carried through
// the butterfly + LDS combine, eliminating the dependent global re-fetch.
// Single barrier per iteration via parity double-buffered LDS slots.
__global__ __launch_bounds__(512) void fps_kernel(const float* __restrict__ pts,
                                                  float4* __restrict__ cent) {
  const int b = blockIdx.x, t = threadIdx.x;
  const int lane = t & 63, wv = t >> 6;
  __shared__ unsigned long long sk2[2][8];
  __shared__ float4 sc4[2][8];
  const float* p = pts + (size_t)b * 8192 * 3;
  float px[16], py[16], pz[16], dd[16];
  #pragma unroll
  for (int j = 0; j < 16; ++j) {
    const int i = t + j * 512;
    px[j] = p[i * 3]; py[j] = p[i * 3 + 1]; pz[j] = p[i * 3 + 2];
    dd[j] = 1e10f;
  }
  float cx = p[0], cy = p[1], cz = p[2];
  for (int it = 0; it < 1024; ++it) {
    if (t == 0) cent[b * 1024 + it] = make_float4(cx, cy, cz, 0.f);
    const int par = it & 1;
    float bd = -1.f, bx = 0.f, by = 0.f, bz = 0.f; int bi = 0;
    #pragma unroll
    for (int j = 0; j < 16; ++j) {
      const float dx = px[j] - cx, dy = py[j] - cy, dz = pz[j] - cz;
      float d = fminf(dd[j], dx * dx + dy * dy + dz * dz);
      dd[j] = d;
      if (d > bd) { bd = d; bi = t + j * 512; bx = px[j]; by = py[j]; bz = pz[j]; }
    }
    // pack: non-negative dist -> monotone bits; ~idx -> min-idx tie-break
    unsigned long long key = ((unsigned long long)__float_as_uint(bd) << 32)
                             | (0xFFFFFFFFu - (unsigned)bi);
    #pragma unroll
    for (int m = 32; m >= 1; m >>= 1) {
      const unsigned long long ok = __shfl_xor(key, m);
      const float ox = __shfl_xor(bx, m), oy = __shfl_xor(by, m), oz = __shfl_xor(bz, m);
      if (ok > key) { key = ok; bx = ox; by = oy; bz = oz; }
    }
    if (lane == 0) { sk2[par][wv] = key; sc4[par][wv] = make_float4(bx, by, bz, 0.f); }
    __syncthreads();
    unsigned long long gk = sk2[par][0]; int gw = 0;
    #pragma unroll
    for (int w = 1; w < 8; ++w) {
      const unsigned long long k2 = sk2[par][w];
      if (k2 > gk) { gk = k2; gw = w; }
    }
    const float4 c4 = sc4[par][gw];
    cx = c4.x; cy = c4.y; cz = c4.z;
  }
}

// ---------------------------------------------------------------- kNN
// One wave per query; sorted top-64 (d2,idx) u64 keys; prefix serves k=16/32.
__global__ __launch_bounds__(256) void knn_kernel(const float* __restrict__ pts,
                                                  const float4* __restrict__ cent,
                                                  int* __restrict__ knn) {
  const int wid = (blockIdx.x * 256 + threadIdx.x) >> 6;
  const int lane = threadIdx.x & 63;
  const int b = wid >> 10;
  const float4 q = cent[wid];
  const float q2 = q.x * q.x + q.y * q.y + q.z * q.z;
  const float* p = pts + (size_t)b * 8192 * 3;
  unsigned long long R = ~0ull;
  for (int c0 = 0; c0 < 8192; c0 += 64) {
    const int i = c0 + lane;
    const float x = p[i * 3], y = p[i * 3 + 1], z = p[i * 3 + 2];
    const float p2 = x * x + y * y + z * z;
    const float dot = q.x * x + q.y * y + q.z * z;
    float d2 = q2 - 2.f * dot + p2;
    d2 = fmaxf(d2, 0.f);
    unsigned u = __float_as_uint(d2);
    u = (u & 0x80000000u) ? ~u : (u | 0x80000000u);
    unsigned long long key = ((unsigned long long)u << 32) | (unsigned)i;
    const unsigned long long rmax = __shfl(R, 63);
    if (__all(key >= rmax)) continue;
    #pragma unroll
    for (int kk = 2; kk <= 64; kk <<= 1) {
      #pragma unroll
      for (int j = kk >> 1; j >= 1; j >>= 1) {
        const unsigned long long o = __shfl_xor(key, j);
        const bool up = ((lane & kk) == 0);
        const bool takeMin = (((lane & j) == 0) == up);
        key = takeMin ? (key < o ? key : o) : (key > o ? key : o);
      }
    }
    const unsigned long long crev = __shfl_xor(key, 63);
    unsigned long long m = R < crev ? R : crev;
    #pragma unroll
    for (int j = 32; j >= 1; j >>= 1) {
      const unsigned long long o = __shfl_xor(m, j);
      const bool takeMin = ((lane & j) == 0);
      m = takeMin ? (m < o ? m : o) : (m > o ? m : o);
    }
    R = m;
  }
  knn[wid * 64 + lane] = (int)(R & 0xffffffffu);
}

// ---------------------------------------------------------------- weight transpose (w2 only)
__global__ __launch_bounds__(256) void transpose_kernel(const float* __restrict__ w,
                                                        float* __restrict__ wt, int O, int C) {
  const int i = blockIdx.x * 256 + threadIdx.x;
  if (i < O * C) { const int o = i / C, c = i - o * C; wt[c * O + o] = w[o * C + c]; }
}

// ---------------------------------------------------------------- stats reduction, stage A
// 32 blocks x 256 threads; block r sums its fixed row chunk (deterministic).
__global__ __launch_bounds__(256) void reduce_rows_kernel(const float* __restrict__ partials,
                                                          int nb, float* __restrict__ out32) {
  const int r0 = blockIdx.x, j = threadIdx.x;
  const int chunk = (nb + 31) / 32;
  const int lo = r0 * chunk;
  const int hi = (lo + chunk < nb) ? lo + chunk : nb;
  float s = 0.f;
  for (int r = lo; r < hi; ++r) s += partials[(size_t)r * 256 + j];
  out32[r0 * 256 + j] = s;
}

// ---------------------------------------------------------------- BN finalize
__global__ __launch_bounds__(256) void finalize_kernel(const float* __restrict__ partials, int nb,
    const float* __restrict__ g, const float* __restrict__ be, float n,
    float* __restrict__ sc, float* __restrict__ sh, int CO) {
  __shared__ float tot[256];
  const int j = threadIdx.x;
  if (j < 2 * CO) {
    float s = 0.f;
    for (int r = 0; r < nb; ++r) s += partials[(size_t)r * 256 + j];
    tot[j] = s;
  }
  __syncthreads();
  if (j < CO) {
    const float m = tot[2 * j] / n;
    const float v = tot[2 * j + 1] / n - m * m;
    const float inv = 1.0f / sqrtf(v + 1e-5f);
    const float scv = g[j] * inv;
    sc[j] = scv;
    sh[j] = be[j] - m * scv;
  }
}

// ---------------------------------------------------------------- fused MLP pass
// L=0/1/2: forward up to layer L, emit per-block (sum,sumsq) partials of
// pre-BN x_L. L=3: full forward + BN + relu + max-over-K + store.
// act0 lives in registers (layer-1 c-loop unrolled); act1 stored bf16 in LDS.
template<int K_, int C0, int C1, int C2, int L, int BOFF, int T>
__global__ __launch_bounds__(T) void pass_kernel(
    const float* __restrict__ pts, const int* __restrict__ knnidx,
    const float* __restrict__ w0, const float* __restrict__ b0,
    const float* __restrict__ w1, const float* __restrict__ b1,
    const float* __restrict__ w2t, const float* __restrict__ b2,
    const float* __restrict__ scsh, float* __restrict__ partials,
    float* __restrict__ out) {
  constexpr int RS = C1 + 1;
  constexpr int NAROW = (L >= 2) ? T * RS : 1;
  __shared__ __hip_bfloat16 arow[NAROW];
  __shared__ float spart[(T / 64) * 256];
  const int tid = threadIdx.x;
  const int lane = tid & 63;
  const int e = blockIdx.x * T + tid;
  const int b = e / (1024 * K_);
  const int rem = e - b * (1024 * K_);
  const int s = rem / K_;
  const int pidx = knnidx[(b * 1024 + s) * 64 + (rem - s * K_)];
  const float* pp = pts + ((size_t)b * 8192 + pidx) * 3;
  const float zx = pp[0], zy = pp[1], zz = pp[2];
  float* prow = partials + (size_t)blockIdx.x * 256;

  // layer 0 (3 -> C0)
  float a0[C0];
  #pragma unroll
  for (int o = 0; o < C0; ++o)
    a0[o] = b0[o] + zx * w0[3 * o] + zy * w0[3 * o + 1] + zz * w0[3 * o + 2];

  if constexpr (L == 0) {
    do_stats<(C0 > 32 ? 32 : C0), 0, C0, T>(a0, tid, spart, prow, 0);
    if constexpr (C0 > 32) do_stats<C0 - 32, 32, C0, T>(a0, tid, spart, prow, 64);
    return;
  }
  {
    const float* sc0 = scsh + 0;
    const float* sh0 = scsh + 128;
    #pragma unroll
    for (int o = 0; o < C0; ++o) a0[o] = fmaxf(0.f, a0[o] * sc0[o] + sh0[o]);
  }

  // layer 1 (C0 -> C1): one output at a time, c unrolled over register act0
  if constexpr (L == 1) {
    float* swl = spart + (tid >> 6) * 256;
    for (int o = 0; o < C1; ++o) {
      float s0 = 0.f, s1 = 0.f, s2 = 0.f, s3 = 0.f;
      #pragma unroll
      for (int c = 0; c < C0; c += 4) {
        s0 += a0[c]     * w1[o * C0 + c];
        s1 += a0[c + 1] * w1[o * C0 + c + 1];
        s2 += a0[c + 2] * w1[o * C0 + c + 2];
        s3 += a0[c + 3] * w1[o * C0 + c + 3];
      }
      const float x = b1[o] + ((s0 + s1) + (s2 + s3));
      float sm = x, sq = x * x;
      #pragma unroll
      for (int m = 32; m >= 1; m >>= 1) { sm += __shfl_xor(sm, m); sq += __shfl_xor(sq, m); }
      if (lane == 0) { swl[2 * o] = sm; swl[2 * o + 1] = sq; }
    }
    __syncthreads();
    // Strided combine: 2*C1 can exceed T (branch 3: 192 > 128).
    for (int col = tid; col < 2 * C1; col += T) {
      float s2_ = 0.f;
      #pragma unroll
      for (int w = 0; w < T / 64; ++w) s2_ += spart[w * 256 + col];
      prow[col] = s2_;
    }
    return;
  }

  // L >= 2: act1 -> LDS (bf16)
  {
    const float* sc1 = scsh + 256;
    const float* sh1 = scsh + 384;
    for (int o = 0; o < C1; ++o) {
      float s0 = 0.f, s1 = 0.f, s2 = 0.f, s3 = 0.f;
      #pragma unroll
      for (int c = 0; c < C0; c += 4) {
        s0 += a0[c]     * w1[o * C0 + c];
        s1 += a0[c + 1] * w1[o * C0 + c + 1];
        s2 += a0[c + 2] * w1[o * C0 + c + 2];
        s3 += a0[c + 3] * w1[o * C0 + c + 3];
      }
      const float x = b1[o] + ((s0 + s1) + (s2 + s3));
      arow[tid * RS + o] = __float2bfloat16(fmaxf(0.f, x * sc1[o] + sh1[o]));
    }
  }

  // layer 2 (C1 -> C2), output chunks of 32
  const float* sc2 = scsh + 512;
  const float* sh2 = scsh + 640;
  const size_t orow = (size_t)(b * 1024 + s) * 320 + BOFF;
  #pragma unroll
  for (int CB = 0; CB < C2; CB += 32) {
    float acc[32];
    #pragma unroll
    for (int j = 0; j < 32; ++j) acc[j] = b2[CB + j];
    for (int c = 0; c < C1; ++c) {
      const float zc = __bfloat162float(arow[tid * RS + c]);
      #pragma unroll
      for (int j = 0; j < 32; ++j) acc[j] += zc * w2t[c * C2 + CB + j];
    }
    if constexpr (L == 2) {
      do_stats<32, 0, 32, T>(acc, tid, spart, prow, 2 * CB);
    } else {
      #pragma unroll
      for (int j = 0; j < 32; ++j) acc[j] = fmaxf(0.f, acc[j] * sc2[CB + j] + sh2[CB + j]);
      int base = 0;
      halve<32, (K_ >> 1), OpMax, 32>(acc, lane, base);
      constexpr int F = (32 / K_ > 0) ? (32 / K_) : 1;  // K=64: lane pairs dup-write same value
      #pragma unroll
      for (int i = 0; i < F; ++i) out[orow + CB + base + i] = acc[i];
    }
  }
}

// ---------------------------------------------------------------- host side
template<int K_, int C0, int C1, int C2, int BOFF>
static void run_branch(const float* pts, const int* knn_,
                       const float* const* W_, const float* const* B_,
                       const float* const* G_, const float* const* BE_,
                       float* scsh, float* partials, float* partials2, float* w2t,
                       float* out, hipStream_t stream) {
  constexpr int T = 128;
  constexpr int NE = 8 * 1024 * K_;
  constexpr int NB = NE / T;
  transpose_kernel<<<(C1 * C2 + 255) / 256, 256, 0, stream>>>(W_[2], w2t, C2, C1);
  pass_kernel<K_, C0, C1, C2, 0, BOFF, T><<<NB, T, 0, stream>>>(
      pts, knn_, W_[0], B_[0], W_[1], B_[1], w2t, B_[2], scsh, partials, out);
  reduce_rows_kernel<<<32, 256, 0, stream>>>(partials, NB, partials2);
  finalize_kernel<<<1, 256, 0, stream>>>(partials2, 32, G_[0], BE_[0], (float)NE,
                                         scsh + 0, scsh + 128, C0);
  pass_kernel<K_, C0, C1, C2, 1, BOFF, T><<<NB, T, 0, stream>>>(
      pts, knn_, W_[0], B_[0], W_[1], B_[1], w2t, B_[2], scsh, partials, out);
  reduce_rows_kernel<<<32, 256, 0, stream>>>(partials, NB, partials2);
  finalize_kernel<<<1, 256, 0, stream>>>(partials2, 32, G_[1], BE_[1], (float)NE,
                                         scsh + 256, scsh + 384, C1);
  pass_kernel<K_, C0, C1, C2, 2, BOFF, T><<<NB, T, 0, stream>>>(
      pts, knn_, W_[0], B_[0], W_[1], B_[1], w2t, B_[2], scsh, partials, out);
  reduce_rows_kernel<<<32, 256, 0, stream>>>(partials, NB, partials2);
  finalize_kernel<<<1, 256, 0, stream>>>(partials2, 32, G_[2], BE_[2], (float)NE,
                                         scsh + 512, scsh + 640, C2);
  pass_kernel<K_, C0, C1, C2, 3, BOFF, T><<<NB, T, 0, stream>>>(
      pts, knn_, W_[0], B_[0], W_[1], B_[1], w2t, B_[2], scsh, partials, out);
}

extern "C" void kernel_launch(void* const* d_in, const int* in_sizes, int n_in,
                              void* d_out, int out_size, void* d_ws, size_t ws_size,
                              hipStream_t stream) {
  (void)in_sizes; (void)n_in; (void)out_size; (void)ws_size;
  const float* pts = (const float*)d_in[0];
  const float* W_[9]; const float* B_[9]; const float* G_[9]; const float* BE_[9];
  for (int m = 0; m < 9; ++m) {
    W_[m]  = (const float*)d_in[1 + m * 4 + 0];
    B_[m]  = (const float*)d_in[1 + m * 4 + 1];
    G_[m]  = (const float*)d_in[1 + m * 4 + 2];
    BE_[m] = (const float*)d_in[1 + m * 4 + 3];
  }
  char* ws = (char*)d_ws;
  float4* cent      = (float4*)ws;                                  // 131072 B
  int*    knn_      = (int*)(ws + 131072);                          // 2 MB
  float*  partials  = (float*)(ws + 131072 + 2097152);              // 4 MB
  float*  scsh      = (float*)(ws + 131072 + 2097152 + 4194304);    // 4 KB
  float*  w2t       = (float*)(ws + 131072 + 2097152 + 4194304 + 4096);   // 48 KB
  float*  partials2 = (float*)(ws + 131072 + 2097152 + 4194304 + 4096 + 49152); // 32 KB
  float*  out       = (float*)d_out;

  fps_kernel<<<8, 512, 0, stream>>>(pts, cent);
  knn_kernel<<<2048, 256, 0, stream>>>(pts, cent, knn_);

  run_branch<16, 32, 32, 64, 0>(pts, knn_, W_ + 0, B_ + 0, G_ + 0, BE_ + 0,
                                scsh, partials, partials2, w2t, out, stream);
  run_branch<32, 64, 64, 128, 64>(pts, knn_, W_ + 3, B_ + 3, G_ + 3, BE_ + 3,
                                  scsh, partials, partials2, w2t, out, stream);
  run_branch<64, 64, 96, 128, 192>(pts, knn_, W_ + 6, B_ + 6, G_ + 6, BE_ + 6,
                                   scsh, partials, partials2, w2t, out, stream);
}

// Round 7
// 3097.651 us; speedup vs baseline: 2.9045x; 1.1816x over previous
//
#include <hip/hip_runtime.h>
#include <hip/hip_bf16.h>

#define DEVFN __device__ __forceinline__

// ---------------------------------------------------------------- utilities
struct OpSum { DEVFN float operator()(float a, float b) const { return a + b; } };
struct OpMax { DEVFN float operator()(float a, float b) const { return fmaxf(a, b); } };

template<int CH, int D, typename OP, int NV>
DEVFN void halve(float (&v)[NV], int lane, int& base) {
  if constexpr (D >= 1) {
    OP op;
    if constexpr (CH > 1) {
      constexpr int H = CH / 2;
      #pragma unroll
      for (int i = 0; i < H; ++i) {
        float send = (lane & D) ? v[i] : v[H + i];
        float r = __shfl_xor(send, D);
        float keep = (lane & D) ? v[H + i] : v[i];
        v[i] = op(keep, r);
      }
      if (lane & D) base += H;
      halve<H, (D >> 1), OP, NV>(v, lane, base);
    } else {
      v[0] = op(v[0], __shfl_xor(v[0], D));
      halve<CH, (D >> 1), OP, NV>(v, lane, base);
    }
  }
}

// Sum + sumsq of channels a[OFF..OFF+CC) across all T threads of the block.
// All uses here have 2*CC = 64 <= T.
template<int CC, int OFF, int NA, int T>
DEVFN void do_stats(const float (&a)[NA], int tid, float* spart, float* prow, int statoff) {
  float v[2 * CC];
  #pragma unroll
  for (int j = 0; j < CC; ++j) { float x = a[OFF + j]; v[2 * j] = x; v[2 * j + 1] = x * x; }
  int lane = tid & 63, base = 0;
  halve<2 * CC, 32, OpSum, 2 * CC>(v, lane, base);
  constexpr int F = (2 * CC) / 64 > 0 ? (2 * CC) / 64 : 1;
  int wv = tid >> 6;
  #pragma unroll
  for (int i = 0; i < F; ++i) spart[wv * 256 + base + i] = v[i];
  __syncthreads();
  constexpr int NW = T / 64;
  if (tid < 2 * CC) {
    float s2 = 0.f;
    #pragma unroll
    for (int w = 0; w < NW; ++w) s2 += spart[w * 256 + tid];
    prow[statoff + tid] = s2;
  }
  __syncthreads();
}

// ---------------------------------------------------------------- FPS
// 512 thr/batch, 16 pts/thread. Key-only u64 butterfly (2 DS ops/level);
// the lane whose pre-butterfly key equals the reduced key (unique: idx
// embedded) writes its coords+key to the wave slot (match-trick). Centroids
// buffered in LDS and flushed at the end -> no per-iter vmcnt drain at the
// barrier. Single barrier/iter via parity double-buffered slots.
__global__ __launch_bounds__(512) void fps_kernel(const float* __restrict__ pts,
                                                  float4* __restrict__ cent) {
  const int b = blockIdx.x, t = threadIdx.x;
  const int wv = t >> 6;
  __shared__ unsigned long long sk2[2][8];
  __shared__ float4 sc4[2][8];
  __shared__ float4 scent[1024];
  const float* p = pts + (size_t)b * 8192 * 3;
  float px[16], py[16], pz[16], dd[16];
  #pragma unroll
  for (int j = 0; j < 16; ++j) {
    const int i = t + j * 512;
    px[j] = p[i * 3]; py[j] = p[i * 3 + 1]; pz[j] = p[i * 3 + 2];
    dd[j] = 1e10f;
  }
  float cx = p[0], cy = p[1], cz = p[2];
  for (int it = 0; it < 1024; ++it) {
    if (t == 0) scent[it] = make_float4(cx, cy, cz, 0.f);
    const int par = it & 1;
    float bd = -1.f, bx = 0.f, by = 0.f, bz = 0.f; int bi = 0;
    #pragma unroll
    for (int j = 0; j < 16; ++j) {
      const float dx = px[j] - cx, dy = py[j] - cy, dz = pz[j] - cz;
      float d = fminf(dd[j], dx * dx + dy * dy + dz * dz);
      dd[j] = d;
      if (d > bd) { bd = d; bi = t + j * 512; bx = px[j]; by = py[j]; bz = pz[j]; }
    }
    // d >= 0 -> float bits order-preserving; ~idx -> lowest index wins ties.
    unsigned long long key = ((unsigned long long)__float_as_uint(bd) << 32)
                             | (0xFFFFFFFFu - (unsigned)bi);
    const unsigned long long k0 = key;
    #pragma unroll
    for (int m = 32; m >= 1; m >>= 1) {
      const unsigned long long ok = __shfl_xor(key, m);
      key = ok > key ? ok : key;
    }
    if (key == k0) {                       // unique winning lane of this wave
      sk2[par][wv] = key;
      sc4[par][wv] = make_float4(bx, by, bz, 0.f);
    }
    __syncthreads();
    unsigned long long gk = sk2[par][0]; int gw = 0;
    #pragma unroll
    for (int w = 1; w < 8; ++w) {
      const unsigned long long k2 = sk2[par][w];
      if (k2 > gk) { gk = k2; gw = w; }
    }
    const float4 c4 = sc4[par][gw];
    cx = c4.x; cy = c4.y; cz = c4.z;
  }
  __syncthreads();
  #pragma unroll
  for (int i = t; i < 1024; i += 512) cent[(size_t)b * 1024 + i] = scent[i];
}

// ---------------------------------------------------------------- kNN
__global__ __launch_bounds__(256) void knn_kernel(const float* __restrict__ pts,
                                                  const float4* __restrict__ cent,
                                                  int* __restrict__ knn) {
  const int wid = (blockIdx.x * 256 + threadIdx.x) >> 6;
  const int lane = threadIdx.x & 63;
  const int b = wid >> 10;
  const float4 q = cent[wid];
  const float q2 = q.x * q.x + q.y * q.y + q.z * q.z;
  const float* p = pts + (size_t)b * 8192 * 3;
  unsigned long long R = ~0ull;
  for (int c0 = 0; c0 < 8192; c0 += 64) {
    const int i = c0 + lane;
    const float x = p[i * 3], y = p[i * 3 + 1], z = p[i * 3 + 2];
    const float p2 = x * x + y * y + z * z;
    const float dot = q.x * x + q.y * y + q.z * z;
    float d2 = q2 - 2.f * dot + p2;
    d2 = fmaxf(d2, 0.f);
    unsigned u = __float_as_uint(d2);
    u = (u & 0x80000000u) ? ~u : (u | 0x80000000u);
    unsigned long long key = ((unsigned long long)u << 32) | (unsigned)i;
    const unsigned long long rmax = __shfl(R, 63);
    if (__all(key >= rmax)) continue;
    #pragma unroll
    for (int kk = 2; kk <= 64; kk <<= 1) {
      #pragma unroll
      for (int j = kk >> 1; j >= 1; j >>= 1) {
        const unsigned long long o = __shfl_xor(key, j);
        const bool up = ((lane & kk) == 0);
        const bool takeMin = (((lane & j) == 0) == up);
        key = takeMin ? (key < o ? key : o) : (key > o ? key : o);
      }
    }
    const unsigned long long crev = __shfl_xor(key, 63);
    unsigned long long m = R < crev ? R : crev;
    #pragma unroll
    for (int j = 32; j >= 1; j >>= 1) {
      const unsigned long long o = __shfl_xor(m, j);
      const bool takeMin = ((lane & j) == 0);
      m = takeMin ? (m < o ? m : o) : (m > o ? m : o);
    }
    R = m;
  }
  knn[wid * 64 + lane] = (int)(R & 0xffffffffu);
}

// ---------------------------------------------------------------- weight transpose (w2 only)
__global__ __launch_bounds__(256) void transpose_kernel(const float* __restrict__ w,
                                                        float* __restrict__ wt, int O, int C) {
  const int i = blockIdx.x * 256 + threadIdx.x;
  if (i < O * C) { const int o = i / C, c = i - o * C; wt[c * O + o] = w[o * C + c]; }
}

// ---------------------------------------------------------------- stats reduction, stage A
__global__ __launch_bounds__(256) void reduce_rows_kernel(const float* __restrict__ partials,
                                                          int nb, float* __restrict__ out32) {
  const int r0 = blockIdx.x, j = threadIdx.x;
  const int chunk = (nb + 31) / 32;
  const int lo = r0 * chunk;
  const int hi = (lo + chunk < nb) ? lo + chunk : nb;
  float s = 0.f;
  for (int r = lo; r < hi; ++r) s += partials[(size_t)r * 256 + j];
  out32[r0 * 256 + j] = s;
}

// ---------------------------------------------------------------- BN finalize
__global__ __launch_bounds__(256) void finalize_kernel(const float* __restrict__ partials, int nb,
    const float* __restrict__ g, const float* __restrict__ be, float n,
    float* __restrict__ sc, float* __restrict__ sh, int CO) {
  __shared__ float tot[256];
  const int j = threadIdx.x;
  if (j < 2 * CO) {
    float s = 0.f;
    for (int r = 0; r < nb; ++r) s += partials[(size_t)r * 256 + j];
    tot[j] = s;
  }
  __syncthreads();
  if (j < CO) {
    const float m = tot[2 * j] / n;
    const float v = tot[2 * j + 1] / n - m * m;
    const float inv = 1.0f / sqrtf(v + 1e-5f);
    const float scv = g[j] * inv;
    sc[j] = scv;
    sh[j] = be[j] - m * scv;
  }
}

// ---------------------------------------------------------------- fused MLP pass
// L=0/1/2: forward up to layer L + (sum,sumsq) partials of pre-BN x_L.
// L==2 && XS: additionally store pre-BN x2 rows to x2buf as bf16.
// L=3 (fallback path only): full forward + BN + relu + max-over-K + store.
template<int K_, int C0, int C1, int C2, int L, int BOFF, int T, bool XS>
__global__ __launch_bounds__(T) void pass_kernel(
    const float* __restrict__ pts, const int* __restrict__ knnidx,
    const float* __restrict__ w0, const float* __restrict__ b0,
    const float* __restrict__ w1, const float* __restrict__ b1,
    const float* __restrict__ w2t, const float* __restrict__ b2,
    const float* __restrict__ scsh, float* __restrict__ partials,
    __hip_bfloat16* __restrict__ x2buf, float* __restrict__ out) {
  constexpr int RS = C1 + 1;
  constexpr int NAROW = (L >= 2) ? T * RS : 1;
  __shared__ __hip_bfloat16 arow[NAROW];
  __shared__ float spart[(T / 64) * 256];
  const int tid = threadIdx.x;
  const int lane = tid & 63;
  const int e = blockIdx.x * T + tid;
  const int b = e / (1024 * K_);
  const int rem = e - b * (1024 * K_);
  const int s = rem / K_;
  const int pidx = knnidx[(b * 1024 + s) * 64 + (rem - s * K_)];
  const float* pp = pts + ((size_t)b * 8192 + pidx) * 3;
  const float zx = pp[0], zy = pp[1], zz = pp[2];
  float* prow = partials + (size_t)blockIdx.x * 256;

  // layer 0 (3 -> C0)
  float a0[C0];
  #pragma unroll
  for (int o = 0; o < C0; ++o)
    a0[o] = b0[o] + zx * w0[3 * o] + zy * w0[3 * o + 1] + zz * w0[3 * o + 2];

  if constexpr (L == 0) {
    do_stats<(C0 > 32 ? 32 : C0), 0, C0, T>(a0, tid, spart, prow, 0);
    if constexpr (C0 > 32) do_stats<C0 - 32, 32, C0, T>(a0, tid, spart, prow, 64);
    return;
  }
  {
    const float* sc0 = scsh + 0;
    const float* sh0 = scsh + 128;
    #pragma unroll
    for (int o = 0; o < C0; ++o) a0[o] = fmaxf(0.f, a0[o] * sc0[o] + sh0[o]);
  }

  // layer 1 (C0 -> C1)
  if constexpr (L == 1) {
    float* swl = spart + (tid >> 6) * 256;
    for (int o = 0; o < C1; ++o) {
      float s0 = 0.f, s1 = 0.f, s2 = 0.f, s3 = 0.f;
      #pragma unroll
      for (int c = 0; c < C0; c += 4) {
        s0 += a0[c]     * w1[o * C0 + c];
        s1 += a0[c + 1] * w1[o * C0 + c + 1];
        s2 += a0[c + 2] * w1[o * C0 + c + 2];
        s3 += a0[c + 3] * w1[o * C0 + c + 3];
      }
      const float x = b1[o] + ((s0 + s1) + (s2 + s3));
      float sm = x, sq = x * x;
      #pragma unroll
      for (int m = 32; m >= 1; m >>= 1) { sm += __shfl_xor(sm, m); sq += __shfl_xor(sq, m); }
      if (lane == 0) { swl[2 * o] = sm; swl[2 * o + 1] = sq; }
    }
    __syncthreads();
    // Strided combine: 2*C1 can exceed T (branch 3: 192 > 128).
    for (int col = tid; col < 2 * C1; col += T) {
      float s2_ = 0.f;
      #pragma unroll
      for (int w = 0; w < T / 64; ++w) s2_ += spart[w * 256 + col];
      prow[col] = s2_;
    }
    return;
  }

  // L >= 2: act1 -> LDS (bf16)
  {
    const float* sc1 = scsh + 256;
    const float* sh1 = scsh + 384;
    for (int o = 0; o < C1; ++o) {
      float s0 = 0.f, s1 = 0.f, s2 = 0.f, s3 = 0.f;
      #pragma unroll
      for (int c = 0; c < C0; c += 4) {
        s0 += a0[c]     * w1[o * C0 + c];
        s1 += a0[c + 1] * w1[o * C0 + c + 1];
        s2 += a0[c + 2] * w1[o * C0 + c + 2];
        s3 += a0[c + 3] * w1[o * C0 + c + 3];
      }
      const float x = b1[o] + ((s0 + s1) + (s2 + s3));
      arow[tid * RS + o] = __float2bfloat16(fmaxf(0.f, x * sc1[o] + sh1[o]));
    }
  }

  // layer 2 (C1 -> C2), output chunks of 32
  const float* sc2 = scsh + 512;
  const float* sh2 = scsh + 640;
  const size_t orow = (size_t)(b * 1024 + s) * 320 + BOFF;
  __hip_bfloat162* x2p = (__hip_bfloat162*)(x2buf + (size_t)e * C2);
  #pragma unroll
  for (int CB = 0; CB < C2; CB += 32) {
    float acc[32];
    #pragma unroll
    for (int j = 0; j < 32; ++j) acc[j] = b2[CB + j];
    for (int c = 0; c < C1; ++c) {
      const float zc = __bfloat162float(arow[tid * RS + c]);
      #pragma unroll
      for (int j = 0; j < 32; ++j) acc[j] += zc * w2t[c * C2 + CB + j];
    }
    if constexpr (L == 2) {
      if constexpr (XS) {
        #pragma unroll
        for (int j = 0; j < 16; ++j) {
          __hip_bfloat162 pr;
          pr.x = __float2bfloat16(acc[2 * j]);
          pr.y = __float2bfloat16(acc[2 * j + 1]);
          x2p[CB / 2 + j] = pr;
        }
      }
      do_stats<32, 0, 32, T>(acc, tid, spart, prow, 2 * CB);
    } else {
      #pragma unroll
      for (int j = 0; j < 32; ++j) acc[j] = fmaxf(0.f, acc[j] * sc2[CB + j] + sh2[CB + j]);
      int base = 0;
      halve<32, (K_ >> 1), OpMax, 32>(acc, lane, base);
      constexpr int F = (32 / K_ > 0) ? (32 / K_) : 1;
      #pragma unroll
      for (int i = 0; i < F; ++i) out[orow + CB + base + i] = acc[i];
    }
  }
}

// ---------------------------------------------------------------- BN+relu+maxpool from stored x2
// wave = sample group, lane = channel pair -> fully coalesced row reads.
template<int K_, int C2, int BOFF>
__global__ __launch_bounds__(256) void pool_kernel(const unsigned int* __restrict__ x2u,
                                                   const float* __restrict__ scsh,
                                                   float* __restrict__ out) {
  constexpr int CP = C2 / 2;
  const int g = blockIdx.x * 256 + threadIdx.x;
  const int cp = g % CP;
  const int sample = g / CP;
  const float sca = scsh[512 + 2 * cp], scb = scsh[512 + 2 * cp + 1];
  const float sha = scsh[640 + 2 * cp], shb = scsh[640 + 2 * cp + 1];
  float m0 = 0.f, m1 = 0.f;   // relu outputs are >= 0
  const size_t base = (size_t)sample * K_ * CP + cp;
  #pragma unroll 4
  for (int k = 0; k < K_; ++k) {
    const unsigned v = x2u[base + (size_t)k * CP];
    const float x0 = __uint_as_float(v << 16);
    const float x1 = __uint_as_float(v & 0xFFFF0000u);
    m0 = fmaxf(m0, fmaxf(0.f, x0 * sca + sha));
    m1 = fmaxf(m1, fmaxf(0.f, x1 * scb + shb));
  }
  float2 r; r.x = m0; r.y = m1;
  *(float2*)&out[(size_t)sample * 320 + BOFF + 2 * cp] = r;
}

// ---------------------------------------------------------------- host side
template<int K_, int C0, int C1, int C2, int BOFF, bool XS>
static void run_branch(const float* pts, const int* knn_,
                       const float* const* W_, const float* const* B_,
                       const float* const* G_, const float* const* BE_,
                       float* scsh, float* partials, float* partials2, float* w2t,
                       __hip_bfloat16* x2buf, float* out, hipStream_t stream) {
  constexpr int T = 128;
  constexpr int NE = 8 * 1024 * K_;
  constexpr int NB = NE / T;
  transpose_kernel<<<(C1 * C2 + 255) / 256, 256, 0, stream>>>(W_[2], w2t, C2, C1);
  pass_kernel<K_, C0, C1, C2, 0, BOFF, T, XS><<<NB, T, 0, stream>>>(
      pts, knn_, W_[0], B_[0], W_[1], B_[1], w2t, B_[2], scsh, partials, x2buf, out);
  reduce_rows_kernel<<<32, 256, 0, stream>>>(partials, NB, partials2);
  finalize_kernel<<<1, 256, 0, stream>>>(partials2, 32, G_[0], BE_[0], (float)NE,
                                         scsh + 0, scsh + 128, C0);
  pass_kernel<K_, C0, C1, C2, 1, BOFF, T, XS><<<NB, T, 0, stream>>>(
      pts, knn_, W_[0], B_[0], W_[1], B_[1], w2t, B_[2], scsh, partials, x2buf, out);
  reduce_rows_kernel<<<32, 256, 0, stream>>>(partials, NB, partials2);
  finalize_kernel<<<1, 256, 0, stream>>>(partials2, 32, G_[1], BE_[1], (float)NE,
                                         scsh + 256, scsh + 384, C1);
  pass_kernel<K_, C0, C1, C2, 2, BOFF, T, XS><<<NB, T, 0, stream>>>(
      pts, knn_, W_[0], B_[0], W_[1], B_[1], w2t, B_[2], scsh, partials, x2buf, out);
  reduce_rows_kernel<<<32, 256, 0, stream>>>(partials, NB, partials2);
  finalize_kernel<<<1, 256, 0, stream>>>(partials2, 32, G_[2], BE_[2], (float)NE,
                                         scsh + 512, scsh + 640, C2);
  if constexpr (XS) {
    constexpr int NP = 8 * 1024 * (C2 / 2);
    pool_kernel<K_, C2, BOFF><<<NP / 256, 256, 0, stream>>>(
        (const unsigned int*)x2buf, scsh, out);
  } else {
    pass_kernel<K_, C0, C1, C2, 3, BOFF, T, XS><<<NB, T, 0, stream>>>(
        pts, knn_, W_[0], B_[0], W_[1], B_[1], w2t, B_[2], scsh, partials, x2buf, out);
  }
}

extern "C" void kernel_launch(void* const* d_in, const int* in_sizes, int n_in,
                              void* d_out, int out_size, void* d_ws, size_t ws_size,
                              hipStream_t stream) {
  (void)in_sizes; (void)n_in; (void)out_size;
  const float* pts = (const float*)d_in[0];
  const float* W_[9]; const float* B_[9]; const float* G_[9]; const float* BE_[9];
  for (int m = 0; m < 9; ++m) {
    W_[m]  = (const float*)d_in[1 + m * 4 + 0];
    B_[m]  = (const float*)d_in[1 + m * 4 + 1];
    G_[m]  = (const float*)d_in[1 + m * 4 + 2];
    BE_[m] = (const float*)d_in[1 + m * 4 + 3];
  }
  char* ws = (char*)d_ws;
  float4* cent      = (float4*)ws;                         // @0,       131072 B
  int*    knn_      = (int*)(ws + 131072);                 // @131072,  2 MB
  float*  partials  = (float*)(ws + 2228224);              // @2228224, 4 MB
  float*  scsh      = (float*)(ws + 6422528);              // 4 KB
  float*  w2t       = (float*)(ws + 6426624);              // 48 KB
  float*  partials2 = (float*)(ws + 6475776);              // 32 KB
  __hip_bfloat16* x2buf = (__hip_bfloat16*)(ws + 6508544); // up to 134217728 B
  float*  out       = (float*)d_out;
  const bool xs = ws_size >= (size_t)6508544 + 134217728ull;

  fps_kernel<<<8, 512, 0, stream>>>(pts, cent);
  knn_kernel<<<2048, 256, 0, stream>>>(pts, cent, knn_);

  if (xs) {
    run_branch<16, 32, 32, 64, 0, true>(pts, knn_, W_ + 0, B_ + 0, G_ + 0, BE_ + 0,
                                        scsh, partials, partials2, w2t, x2buf, out, stream);
    run_branch<32, 64, 64, 128, 64, true>(pts, knn_, W_ + 3, B_ + 3, G_ + 3, BE_ + 3,
                                          scsh, partials, partials2, w2t, x2buf, out, stream);
    run_branch<64, 64, 96, 128, 192, true>(pts, knn_, W_ + 6, B_ + 6, G_ + 6, BE_ + 6,
                                           scsh, partials, partials2, w2t, x2buf, out, stream);
  } else {
    run_branch<16, 32, 32, 64, 0, false>(pts, knn_, W_ + 0, B_ + 0, G_ + 0, BE_ + 0,
                                         scsh, partials, partials2, w2t, x2buf, out, stream);
    run_branch<32, 64, 64, 128, 64, false>(pts, knn_, W_ + 3, B_ + 3, G_ + 3, BE_ + 3,
                                           scsh, partials, partials2, w2t, x2buf, out, stream);
    run_branch<64, 64, 96, 128, 192, false>(pts, knn_, W_ + 6, B_ + 6, G_ + 6, BE_ + 6,
                                            scsh, partials, partials2, w2t, x2buf, out, stream);
  }
}

// Round 8
// 2814.974 us; speedup vs baseline: 3.1962x; 1.1004x over previous
//
#include <hip/hip_runtime.h>
#include <hip/hip_bf16.h>

#define DEVFN __device__ __forceinline__

// ---------------------------------------------------------------- utilities
struct OpSum { DEVFN float operator()(float a, float b) const { return a + b; } };
struct OpMax { DEVFN float operator()(float a, float b) const { return fmaxf(a, b); } };

template<int CH, int D, typename OP, int NV>
DEVFN void halve(float (&v)[NV], int lane, int& base) {
  if constexpr (D >= 1) {
    OP op;
    if constexpr (CH > 1) {
      constexpr int H = CH / 2;
      #pragma unroll
      for (int i = 0; i < H; ++i) {
        float send = (lane & D) ? v[i] : v[H + i];
        float r = __shfl_xor(send, D);
        float keep = (lane & D) ? v[H + i] : v[i];
        v[i] = op(keep, r);
      }
      if (lane & D) base += H;
      halve<H, (D >> 1), OP, NV>(v, lane, base);
    } else {
      v[0] = op(v[0], __shfl_xor(v[0], D));
      halve<CH, (D >> 1), OP, NV>(v, lane, base);
    }
  }
}

// Sum + sumsq of channels a[OFF..OFF+CC) across all T threads of the block.
// All uses here have 2*CC = 64 <= T.
template<int CC, int OFF, int NA, int T>
DEVFN void do_stats(const float (&a)[NA], int tid, float* spart, float* prow, int statoff) {
  float v[2 * CC];
  #pragma unroll
  for (int j = 0; j < CC; ++j) { float x = a[OFF + j]; v[2 * j] = x; v[2 * j + 1] = x * x; }
  int lane = tid & 63, base = 0;
  halve<2 * CC, 32, OpSum, 2 * CC>(v, lane, base);
  constexpr int F = (2 * CC) / 64 > 0 ? (2 * CC) / 64 : 1;
  int wv = tid >> 6;
  #pragma unroll
  for (int i = 0; i < F; ++i) spart[wv * 256 + base + i] = v[i];
  __syncthreads();
  constexpr int NW = T / 64;
  if (tid < 2 * CC) {
    float s2 = 0.f;
    #pragma unroll
    for (int w = 0; w < NW; ++w) s2 += spart[w * 256 + tid];
    prow[statoff + tid] = s2;
  }
  __syncthreads();
}

// ---------------------------------------------------------------- FPS
// 512 thr/batch, 16 pts/thread. j-loop tracks only (bd, bj); the unique
// winning lane per wave (key==k0 match-trick) recovers its coords via a
// one-lane 16-way switch. Key-only u64 butterfly; centroids buffered in LDS
// and flushed after the loop. Single barrier/iter, parity double-buffered.
__global__ __launch_bounds__(512) void fps_kernel(const float* __restrict__ pts,
                                                  float4* __restrict__ cent) {
  const int b = blockIdx.x, t = threadIdx.x;
  const int wv = t >> 6;
  __shared__ unsigned long long sk2[2][8];
  __shared__ float4 sc4[2][8];
  __shared__ float4 scent[1024];
  const float* p = pts + (size_t)b * 8192 * 3;
  float px[16], py[16], pz[16], dd[16];
  #pragma unroll
  for (int j = 0; j < 16; ++j) {
    const int i = t + j * 512;
    px[j] = p[i * 3]; py[j] = p[i * 3 + 1]; pz[j] = p[i * 3 + 2];
    dd[j] = 1e10f;
  }
  float cx = p[0], cy = p[1], cz = p[2];
  for (int it = 0; it < 1024; ++it) {
    if (t == 0) scent[it] = make_float4(cx, cy, cz, 0.f);
    const int par = it & 1;
    float bd = -1.f; int bj = 0;
    #pragma unroll
    for (int j = 0; j < 16; ++j) {
      const float dx = px[j] - cx, dy = py[j] - cy, dz = pz[j] - cz;
      float d = fminf(dd[j], dx * dx + dy * dy + dz * dz);
      dd[j] = d;
      if (d > bd) { bd = d; bj = j; }     // ascending j -> lowest idx on tie
    }
    const int bi = t + (bj << 9);
    // d >= 0 -> float bits order-preserving; ~idx -> lowest index wins ties.
    unsigned long long key = ((unsigned long long)__float_as_uint(bd) << 32)
                             | (0xFFFFFFFFu - (unsigned)bi);
    const unsigned long long k0 = key;
    #pragma unroll
    for (int m = 32; m >= 1; m >>= 1) {
      const unsigned long long ok = __shfl_xor(key, m);
      key = ok > key ? ok : key;
    }
    if (key == k0) {                      // unique winning lane of this wave
      float X, Y, Z;
      switch (bj) {
        case 0:  X = px[0];  Y = py[0];  Z = pz[0];  break;
        case 1:  X = px[1];  Y = py[1];  Z = pz[1];  break;
        case 2:  X = px[2];  Y = py[2];  Z = pz[2];  break;
        case 3:  X = px[3];  Y = py[3];  Z = pz[3];  break;
        case 4:  X = px[4];  Y = py[4];  Z = pz[4];  break;
        case 5:  X = px[5];  Y = py[5];  Z = pz[5];  break;
        case 6:  X = px[6];  Y = py[6];  Z = pz[6];  break;
        case 7:  X = px[7];  Y = py[7];  Z = pz[7];  break;
        case 8:  X = px[8];  Y = py[8];  Z = pz[8];  break;
        case 9:  X = px[9];  Y = py[9];  Z = pz[9];  break;
        case 10: X = px[10]; Y = py[10]; Z = pz[10]; break;
        case 11: X = px[11]; Y = py[11]; Z = pz[11]; break;
        case 12: X = px[12]; Y = py[12]; Z = pz[12]; break;
        case 13: X = px[13]; Y = py[13]; Z = pz[13]; break;
        default: X = px[14]; Y = py[14]; Z = pz[14];
                 if (bj == 15) { X = px[15]; Y = py[15]; Z = pz[15]; } break;
      }
      sk2[par][wv] = key;
      sc4[par][wv] = make_float4(X, Y, Z, 0.f);
    }
    __syncthreads();
    unsigned long long gk = sk2[par][0]; int gw = 0;
    #pragma unroll
    for (int w = 1; w < 8; ++w) {
      const unsigned long long k2 = sk2[par][w];
      if (k2 > gk) { gk = k2; gw = w; }
    }
    const float4 c4 = sc4[par][gw];
    cx = c4.x; cy = c4.y; cz = c4.z;
  }
  __syncthreads();
  #pragma unroll
  for (int i = t; i < 1024; i += 512) cent[(size_t)b * 1024 + i] = scent[i];
}

// ---------------------------------------------------------------- kNN
// One wave per query. Sorted top-64 (d2,idx) u64 keys maintained by
// sequential sorted-insertion (E[#inserts] ~ 64*ln(128) ~ 310 per query,
// far cheaper than per-chunk bitonic sort). Final set is order-independent;
// keys identical to the proven sort version -> identical results.
__global__ __launch_bounds__(256) void knn_kernel(const float* __restrict__ pts,
                                                  const float4* __restrict__ cent,
                                                  int* __restrict__ knn) {
  const int wid = (blockIdx.x * 256 + threadIdx.x) >> 6;
  const int lane = threadIdx.x & 63;
  const int b = wid >> 10;
  const float4 q = cent[wid];
  const float q2 = q.x * q.x + q.y * q.y + q.z * q.z;
  const float* p = pts + (size_t)b * 8192 * 3;
  unsigned long long R = ~0ull;
  for (int c0 = 0; c0 < 8192; c0 += 64) {
    const int i = c0 + lane;
    const float x = p[i * 3], y = p[i * 3 + 1], z = p[i * 3 + 2];
    const float p2 = x * x + y * y + z * z;
    const float dot = q.x * x + q.y * y + q.z * z;
    float d2 = q2 - 2.f * dot + p2;
    d2 = fmaxf(d2, 0.f);
    unsigned u = __float_as_uint(d2);
    u = (u & 0x80000000u) ? ~u : (u | 0x80000000u);
    const unsigned long long key = ((unsigned long long)u << 32) | (unsigned)i;
    const unsigned long long rmax = __shfl(R, 63);
    unsigned long long mask = __ballot(key < rmax);
    while (mask) {
      const int src = __ffsll(mask) - 1;
      mask &= mask - 1;
      const unsigned long long nk = __shfl(key, src);
      const int pos = __popcll(__ballot(R < nk));
      if (pos < 64) {                         // may be obsoleted by earlier inserts
        const unsigned long long Rm1 = __shfl_up(R, 1);
        R = (lane < pos) ? R : (lane == pos ? nk : Rm1);
      }
    }
  }
  knn[wid * 64 + lane] = (int)(R & 0xffffffffu);
}

// ---------------------------------------------------------------- weight transpose (w2 only)
__global__ __launch_bounds__(256) void transpose_kernel(const float* __restrict__ w,
                                                        float* __restrict__ wt, int O, int C) {
  const int i = blockIdx.x * 256 + threadIdx.x;
  if (i < O * C) { const int o = i / C, c = i - o * C; wt[c * O + o] = w[o * C + c]; }
}

// ---------------------------------------------------------------- stats reduction, stage A
__global__ __launch_bounds__(256) void reduce_rows_kernel(const float* __restrict__ partials,
                                                          int nb, float* __restrict__ out32) {
  const int r0 = blockIdx.x, j = threadIdx.x;
  const int chunk = (nb + 31) / 32;
  const int lo = r0 * chunk;
  const int hi = (lo + chunk < nb) ? lo + chunk : nb;
  float s = 0.f;
  for (int r = lo; r < hi; ++r) s += partials[(size_t)r * 256 + j];
  out32[r0 * 256 + j] = s;
}

// ---------------------------------------------------------------- BN finalize
__global__ __launch_bounds__(256) void finalize_kernel(const float* __restrict__ partials, int nb,
    const float* __restrict__ g, const float* __restrict__ be, float n,
    float* __restrict__ sc, float* __restrict__ sh, int CO) {
  __shared__ float tot[256];
  const int j = threadIdx.x;
  if (j < 2 * CO) {
    float s = 0.f;
    for (int r = 0; r < nb; ++r) s += partials[(size_t)r * 256 + j];
    tot[j] = s;
  }
  __syncthreads();
  if (j < CO) {
    const float m = tot[2 * j] / n;
    const float v = tot[2 * j + 1] / n - m * m;
    const float inv = 1.0f / sqrtf(v + 1e-5f);
    const float scv = g[j] * inv;
    sc[j] = scv;
    sh[j] = be[j] - m * scv;
  }
}

// ---------------------------------------------------------------- fused MLP pass
// L=0/1/2: forward up to layer L + (sum,sumsq) partials of pre-BN x_L.
// L==2 && XS: additionally store pre-BN x2 rows to x2buf as bf16.
// L=3 (fallback path only): full forward + BN + relu + max-over-K + store.
template<int K_, int C0, int C1, int C2, int L, int BOFF, int T, bool XS>
__global__ __launch_bounds__(T) void pass_kernel(
    const float* __restrict__ pts, const int* __restrict__ knnidx,
    const float* __restrict__ w0, const float* __restrict__ b0,
    const float* __restrict__ w1, const float* __restrict__ b1,
    const float* __restrict__ w2t, const float* __restrict__ b2,
    const float* __restrict__ scsh, float* __restrict__ partials,
    __hip_bfloat16* __restrict__ x2buf, float* __restrict__ out) {
  constexpr int RS = C1 + 1;
  constexpr int NAROW = (L >= 2) ? T * RS : 1;
  __shared__ __hip_bfloat16 arow[NAROW];
  __shared__ float spart[(T / 64) * 256];
  const int tid = threadIdx.x;
  const int lane = tid & 63;
  const int e = blockIdx.x * T + tid;
  const int b = e / (1024 * K_);
  const int rem = e - b * (1024 * K_);
  const int s = rem / K_;
  const int pidx = knnidx[(b * 1024 + s) * 64 + (rem - s * K_)];
  const float* pp = pts + ((size_t)b * 8192 + pidx) * 3;
  const float zx = pp[0], zy = pp[1], zz = pp[2];
  float* prow = partials + (size_t)blockIdx.x * 256;

  // layer 0 (3 -> C0)
  float a0[C0];
  #pragma unroll
  for (int o = 0; o < C0; ++o)
    a0[o] = b0[o] + zx * w0[3 * o] + zy * w0[3 * o + 1] + zz * w0[3 * o + 2];

  if constexpr (L == 0) {
    do_stats<(C0 > 32 ? 32 : C0), 0, C0, T>(a0, tid, spart, prow, 0);
    if constexpr (C0 > 32) do_stats<C0 - 32, 32, C0, T>(a0, tid, spart, prow, 64);
    return;
  }
  {
    const float* sc0 = scsh + 0;
    const float* sh0 = scsh + 128;
    #pragma unroll
    for (int o = 0; o < C0; ++o) a0[o] = fmaxf(0.f, a0[o] * sc0[o] + sh0[o]);
  }

  // layer 1 (C0 -> C1)
  if constexpr (L == 1) {
    float* swl = spart + (tid >> 6) * 256;
    for (int o = 0; o < C1; ++o) {
      float s0 = 0.f, s1 = 0.f, s2 = 0.f, s3 = 0.f;
      #pragma unroll
      for (int c = 0; c < C0; c += 4) {
        s0 += a0[c]     * w1[o * C0 + c];
        s1 += a0[c + 1] * w1[o * C0 + c + 1];
        s2 += a0[c + 2] * w1[o * C0 + c + 2];
        s3 += a0[c + 3] * w1[o * C0 + c + 3];
      }
      const float x = b1[o] + ((s0 + s1) + (s2 + s3));
      float sm = x, sq = x * x;
      #pragma unroll
      for (int m = 32; m >= 1; m >>= 1) { sm += __shfl_xor(sm, m); sq += __shfl_xor(sq, m); }
      if (lane == 0) { swl[2 * o] = sm; swl[2 * o + 1] = sq; }
    }
    __syncthreads();
    // Strided combine: 2*C1 can exceed T (branch 3: 192 > 128).
    for (int col = tid; col < 2 * C1; col += T) {
      float s2_ = 0.f;
      #pragma unroll
      for (int w = 0; w < T / 64; ++w) s2_ += spart[w * 256 + col];
      prow[col] = s2_;
    }
    return;
  }

  // L >= 2: act1 -> LDS (bf16)
  {
    const float* sc1 = scsh + 256;
    const float* sh1 = scsh + 384;
    for (int o = 0; o < C1; ++o) {
      float s0 = 0.f, s1 = 0.f, s2 = 0.f, s3 = 0.f;
      #pragma unroll
      for (int c = 0; c < C0; c += 4) {
        s0 += a0[c]     * w1[o * C0 + c];
        s1 += a0[c + 1] * w1[o * C0 + c + 1];
        s2 += a0[c + 2] * w1[o * C0 + c + 2];
        s3 += a0[c + 3] * w1[o * C0 + c + 3];
      }
      const float x = b1[o] + ((s0 + s1) + (s2 + s3));
      arow[tid * RS + o] = __float2bfloat16(fmaxf(0.f, x * sc1[o] + sh1[o]));
    }
  }

  // layer 2 (C1 -> C2), output chunks of 32
  const float* sc2 = scsh + 512;
  const float* sh2 = scsh + 640;
  const size_t orow = (size_t)(b * 1024 + s) * 320 + BOFF;
  __hip_bfloat162* x2p = (__hip_bfloat162*)(x2buf + (size_t)e * C2);
  #pragma unroll
  for (int CB = 0; CB < C2; CB += 32) {
    float acc[32];
    #pragma unroll
    for (int j = 0; j < 32; ++j) acc[j] = b2[CB + j];
    for (int c = 0; c < C1; ++c) {
      const float zc = __bfloat162float(arow[tid * RS + c]);
      #pragma unroll
      for (int j = 0; j < 32; ++j) acc[j] += zc * w2t[c * C2 + CB + j];
    }
    if constexpr (L == 2) {
      if constexpr (XS) {
        #pragma unroll
        for (int j = 0; j < 16; ++j) {
          __hip_bfloat162 pr;
          pr.x = __float2bfloat16(acc[2 * j]);
          pr.y = __float2bfloat16(acc[2 * j + 1]);
          x2p[CB / 2 + j] = pr;
        }
      }
      do_stats<32, 0, 32, T>(acc, tid, spart, prow, 2 * CB);
    } else {
      #pragma unroll
      for (int j = 0; j < 32; ++j) acc[j] = fmaxf(0.f, acc[j] * sc2[CB + j] + sh2[CB + j]);
      int base = 0;
      halve<32, (K_ >> 1), OpMax, 32>(acc, lane, base);
      constexpr int F = (32 / K_ > 0) ? (32 / K_) : 1;
      #pragma unroll
      for (int i = 0; i < F; ++i) out[orow + CB + base + i] = acc[i];
    }
  }
}

// ---------------------------------------------------------------- BN+relu+maxpool from stored x2
template<int K_, int C2, int BOFF>
__global__ __launch_bounds__(256) void pool_kernel(const unsigned int* __restrict__ x2u,
                                                   const float* __restrict__ scsh,
                                                   float* __restrict__ out) {
  constexpr int CP = C2 / 2;
  const int g = blockIdx.x * 256 + threadIdx.x;
  const int cp = g % CP;
  const int sample = g / CP;
  const float sca = scsh[512 + 2 * cp], scb = scsh[512 + 2 * cp + 1];
  const float sha = scsh[640 + 2 * cp], shb = scsh[640 + 2 * cp + 1];
  float m0 = 0.f, m1 = 0.f;   // relu outputs are >= 0
  const size_t base = (size_t)sample * K_ * CP + cp;
  #pragma unroll 4
  for (int k = 0; k < K_; ++k) {
    const unsigned v = x2u[base + (size_t)k * CP];
    const float x0 = __uint_as_float(v << 16);
    const float x1 = __uint_as_float(v & 0xFFFF0000u);
    m0 = fmaxf(m0, fmaxf(0.f, x0 * sca + sha));
    m1 = fmaxf(m1, fmaxf(0.f, x1 * scb + shb));
  }
  float2 r; r.x = m0; r.y = m1;
  *(float2*)&out[(size_t)sample * 320 + BOFF + 2 * cp] = r;
}

// ---------------------------------------------------------------- host side
template<int K_, int C0, int C1, int C2, int BOFF, bool XS>
static void run_branch(const float* pts, const int* knn_,
                       const float* const* W_, const float* const* B_,
                       const float* const* G_, const float* const* BE_,
                       float* scsh, float* partials, float* partials2, float* w2t,
                       __hip_bfloat16* x2buf, float* out, hipStream_t stream) {
  constexpr int T = 128;
  constexpr int NE = 8 * 1024 * K_;
  constexpr int NB = NE / T;
  transpose_kernel<<<(C1 * C2 + 255) / 256, 256, 0, stream>>>(W_[2], w2t, C2, C1);
  pass_kernel<K_, C0, C1, C2, 0, BOFF, T, XS><<<NB, T, 0, stream>>>(
      pts, knn_, W_[0], B_[0], W_[1], B_[1], w2t, B_[2], scsh, partials, x2buf, out);
  reduce_rows_kernel<<<32, 256, 0, stream>>>(partials, NB, partials2);
  finalize_kernel<<<1, 256, 0, stream>>>(partials2, 32, G_[0], BE_[0], (float)NE,
                                         scsh + 0, scsh + 128, C0);
  pass_kernel<K_, C0, C1, C2, 1, BOFF, T, XS><<<NB, T, 0, stream>>>(
      pts, knn_, W_[0], B_[0], W_[1], B_[1], w2t, B_[2], scsh, partials, x2buf, out);
  reduce_rows_kernel<<<32, 256, 0, stream>>>(partials, NB, partials2);
  finalize_kernel<<<1, 256, 0, stream>>>(partials2, 32, G_[1], BE_[1], (float)NE,
                                         scsh + 256, scsh + 384, C1);
  pass_kernel<K_, C0, C1, C2, 2, BOFF, T, XS><<<NB, T, 0, stream>>>(
      pts, knn_, W_[0], B_[0], W_[1], B_[1], w2t, B_[2], scsh, partials, x2buf, out);
  reduce_rows_kernel<<<32, 256, 0, stream>>>(partials, NB, partials2);
  finalize_kernel<<<1, 256, 0, stream>>>(partials2, 32, G_[2], BE_[2], (float)NE,
                                         scsh + 512, scsh + 640, C2);
  if constexpr (XS) {
    constexpr int NP = 8 * 1024 * (C2 / 2);
    pool_kernel<K_, C2, BOFF><<<NP / 256, 256, 0, stream>>>(
        (const unsigned int*)x2buf, scsh, out);
  } else {
    pass_kernel<K_, C0, C1, C2, 3, BOFF, T, XS><<<NB, T, 0, stream>>>(
        pts, knn_, W_[0], B_[0], W_[1], B_[1], w2t, B_[2], scsh, partials, x2buf, out);
  }
}

extern "C" void kernel_launch(void* const* d_in, const int* in_sizes, int n_in,
                              void* d_out, int out_size, void* d_ws, size_t ws_size,
                              hipStream_t stream) {
  (void)in_sizes; (void)n_in; (void)out_size;
  const float* pts = (const float*)d_in[0];
  const float* W_[9]; const float* B_[9]; const float* G_[9]; const float* BE_[9];
  for (int m = 0; m < 9; ++m) {
    W_[m]  = (const float*)d_in[1 + m * 4 + 0];
    B_[m]  = (const float*)d_in[1 + m * 4 + 1];
    G_[m]  = (const float*)d_in[1 + m * 4 + 2];
    BE_[m] = (const float*)d_in[1 + m * 4 + 3];
  }
  char* ws = (char*)d_ws;
  float4* cent      = (float4*)ws;                         // @0,       131072 B
  int*    knn_      = (int*)(ws + 131072);                 // @131072,  2 MB
  float*  partials  = (float*)(ws + 2228224);              // @2228224, 4 MB
  float*  scsh      = (float*)(ws + 6422528);              // 4 KB
  float*  w2t       = (float*)(ws + 6426624);              // 48 KB
  float*  partials2 = (float*)(ws + 6475776);              // 32 KB
  __hip_bfloat16* x2buf = (__hip_bfloat16*)(ws + 6508544); // up to 134217728 B
  float*  out       = (float*)d_out;
  const bool xs = ws_size >= (size_t)6508544 + 134217728ull;

  fps_kernel<<<8, 512, 0, stream>>>(pts, cent);
  knn_kernel<<<2048, 256, 0, stream>>>(pts, cent, knn_);

  if (xs) {
    run_branch<16, 32, 32, 64, 0, true>(pts, knn_, W_ + 0, B_ + 0, G_ + 0, BE_ + 0,
                                        scsh, partials, partials2, w2t, x2buf, out, stream);
    run_branch<32, 64, 64, 128, 64, true>(pts, knn_, W_ + 3, B_ + 3, G_ + 3, BE_ + 3,
                                          scsh, partials, partials2, w2t, x2buf, out, stream);
    run_branch<64, 64, 96, 128, 192, true>(pts, knn_, W_ + 6, B_ + 6, G_ + 6, BE_ + 6,
                                           scsh, partials, partials2, w2t, x2buf, out, stream);
  } else {
    run_branch<16, 32, 32, 64, 0, false>(pts, knn_, W_ + 0, B_ + 0, G_ + 0, BE_ + 0,
                                         scsh, partials, partials2, w2t, x2buf, out, stream);
    run_branch<32, 64, 64, 128, 64, false>(pts, knn_, W_ + 3, B_ + 3, G_ + 3, BE_ + 3,
                                           scsh, partials, partials2, w2t, x2buf, out, stream);
    run_branch<64, 64, 96, 128, 192, false>(pts, knn_, W_ + 6, B_ + 6, G_ + 6, BE_ + 6,
                                            scsh, partials, partials2, w2t, x2buf, out, stream);
  }
}

// Round 9
// 2669.046 us; speedup vs baseline: 3.3709x; 1.0547x over previous
//
#include <hip/hip_runtime.h>
#include <hip/hip_bf16.h>

#define DEVFN __device__ __forceinline__

// ---------------------------------------------------------------- utilities
struct OpSum { DEVFN float operator()(float a, float b) const { return a + b; } };
struct OpMax { DEVFN float operator()(float a, float b) const { return fmaxf(a, b); } };

template<int CH, int D, typename OP, int NV>
DEVFN void halve(float (&v)[NV], int lane, int& base) {
  if constexpr (D >= 1) {
    OP op;
    if constexpr (CH > 1) {
      constexpr int H = CH / 2;
      #pragma unroll
      for (int i = 0; i < H; ++i) {
        float send = (lane & D) ? v[i] : v[H + i];
        float r = __shfl_xor(send, D);
        float keep = (lane & D) ? v[H + i] : v[i];
        v[i] = op(keep, r);
      }
      if (lane & D) base += H;
      halve<H, (D >> 1), OP, NV>(v, lane, base);
    } else {
      v[0] = op(v[0], __shfl_xor(v[0], D));
      halve<CH, (D >> 1), OP, NV>(v, lane, base);
    }
  }
}

// Sum + sumsq of channels a[OFF..OFF+CC) across all T threads of the block.
template<int CC, int OFF, int NA, int T>
DEVFN void do_stats(const float (&a)[NA], int tid, float* spart, float* prow, int statoff) {
  float v[2 * CC];
  #pragma unroll
  for (int j = 0; j < CC; ++j) { float x = a[OFF + j]; v[2 * j] = x; v[2 * j + 1] = x * x; }
  int lane = tid & 63, base = 0;
  halve<2 * CC, 32, OpSum, 2 * CC>(v, lane, base);
  constexpr int F = (2 * CC) / 64 > 0 ? (2 * CC) / 64 : 1;
  int wv = tid >> 6;
  #pragma unroll
  for (int i = 0; i < F; ++i) spart[wv * 256 + base + i] = v[i];
  __syncthreads();
  constexpr int NW = T / 64;
  if (tid < 2 * CC) {
    float s2 = 0.f;
    #pragma unroll
    for (int w = 0; w < NW; ++w) s2 += spart[w * 256 + tid];
    prow[statoff + tid] = s2;
  }
  __syncthreads();
}

// ---------------------------------------------------------------- FPS
// 512 thr/batch, 16 pts/thread. j-loop carries (bd,bi,coords); key-only u64
// butterfly + match-trick write (unique winning lane). Final 8-slot scan
// carries coords via cndmask (no dependent LDS read). Centroids buffered in
// LDS, flushed after the loop. Single barrier/iter, parity double-buffered.
__global__ __launch_bounds__(512) void fps_kernel(const float* __restrict__ pts,
                                                  float4* __restrict__ cent) {
  const int b = blockIdx.x, t = threadIdx.x;
  const int wv = t >> 6;
  __shared__ unsigned long long sk2[2][8];
  __shared__ float4 sc4[2][8];
  __shared__ float4 scent[1024];
  const float* p = pts + (size_t)b * 8192 * 3;
  float px[16], py[16], pz[16], dd[16];
  #pragma unroll
  for (int j = 0; j < 16; ++j) {
    const int i = t + j * 512;
    px[j] = p[i * 3]; py[j] = p[i * 3 + 1]; pz[j] = p[i * 3 + 2];
    dd[j] = 1e10f;
  }
  float cx = p[0], cy = p[1], cz = p[2];
  for (int it = 0; it < 1024; ++it) {
    if (t == 0) scent[it] = make_float4(cx, cy, cz, 0.f);
    const int par = it & 1;
    float bd = -1.f, bx = 0.f, by = 0.f, bz = 0.f; int bi = 0;
    #pragma unroll
    for (int j = 0; j < 16; ++j) {
      const float dx = px[j] - cx, dy = py[j] - cy, dz = pz[j] - cz;
      float d = fminf(dd[j], dx * dx + dy * dy + dz * dz);
      dd[j] = d;
      if (d > bd) { bd = d; bi = t + j * 512; bx = px[j]; by = py[j]; bz = pz[j]; }
    }
    // d >= 0 -> float bits order-preserving; ~idx -> lowest index wins ties.
    unsigned long long key = ((unsigned long long)__float_as_uint(bd) << 32)
                             | (0xFFFFFFFFu - (unsigned)bi);
    const unsigned long long k0 = key;
    #pragma unroll
    for (int m = 32; m >= 1; m >>= 1) {
      const unsigned long long ok = __shfl_xor(key, m);
      key = ok > key ? ok : key;
    }
    if (key == k0) {                      // unique winning lane of this wave
      sk2[par][wv] = key;
      sc4[par][wv] = make_float4(bx, by, bz, 0.f);
    }
    __syncthreads();
    unsigned long long gk = sk2[par][0];
    float4 c4 = sc4[par][0];
    #pragma unroll
    for (int w = 1; w < 8; ++w) {
      const unsigned long long k2 = sk2[par][w];
      const float4 cc = sc4[par][w];
      if (k2 > gk) { gk = k2; c4 = cc; }
    }
    cx = c4.x; cy = c4.y; cz = c4.z;
  }
  __syncthreads();
  #pragma unroll
  for (int i = t; i < 1024; i += 512) cent[(size_t)b * 1024 + i] = scent[i];
}

// ---------------------------------------------------------------- kNN
// One wave per query; sorted top-64 via sequential sorted-insertion.
__global__ __launch_bounds__(256) void knn_kernel(const float* __restrict__ pts,
                                                  const float4* __restrict__ cent,
                                                  int* __restrict__ knn) {
  const int wid = (blockIdx.x * 256 + threadIdx.x) >> 6;
  const int lane = threadIdx.x & 63;
  const int b = wid >> 10;
  const float4 q = cent[wid];
  const float q2 = q.x * q.x + q.y * q.y + q.z * q.z;
  const float* p = pts + (size_t)b * 8192 * 3;
  unsigned long long R = ~0ull;
  for (int c0 = 0; c0 < 8192; c0 += 64) {
    const int i = c0 + lane;
    const float x = p[i * 3], y = p[i * 3 + 1], z = p[i * 3 + 2];
    const float p2 = x * x + y * y + z * z;
    const float dot = q.x * x + q.y * y + q.z * z;
    float d2 = q2 - 2.f * dot + p2;
    d2 = fmaxf(d2, 0.f);
    unsigned u = __float_as_uint(d2);
    u = (u & 0x80000000u) ? ~u : (u | 0x80000000u);
    const unsigned long long key = ((unsigned long long)u << 32) | (unsigned)i;
    const unsigned long long rmax = __shfl(R, 63);
    unsigned long long mask = __ballot(key < rmax);
    while (mask) {
      const int src = __ffsll(mask) - 1;
      mask &= mask - 1;
      const unsigned long long nk = __shfl(key, src);
      const int pos = __popcll(__ballot(R < nk));
      if (pos < 64) {
        const unsigned long long Rm1 = __shfl_up(R, 1);
        R = (lane < pos) ? R : (lane == pos ? nk : Rm1);
      }
    }
  }
  knn[wid * 64 + lane] = (int)(R & 0xffffffffu);
}

// ---------------------------------------------------------------- gather moments (BN0 stats)
// Wave = one sample: 64 neighbor points; prefix sums at 16/32/64 of
// (Sx,Sy,Sz, Mxx,Mxy,Mxz,Myy,Myz,Mzz) via group shuffles. knn lists are
// sorted -> k=16/32 gathers are prefixes of the k=64 list.
__global__ __launch_bounds__(256) void moments_kernel(const float* __restrict__ pts,
                                                      const int* __restrict__ knn_,
                                                      float* __restrict__ mpart) {
  __shared__ float smom[4][27];
  const int tid = threadIdx.x, lane = tid & 63, wv = tid >> 6;
  const int samp = blockIdx.x * 4 + wv;
  const int b = samp >> 10;
  const int pidx = knn_[samp * 64 + lane];
  const float* pp = pts + ((size_t)b * 8192 + pidx) * 3;
  const float x = pp[0], y = pp[1], z = pp[2];
  float g[9] = {x, y, z, x * x, x * y, x * z, y * y, y * z, z * z};
  #pragma unroll
  for (int m = 8; m >= 1; m >>= 1) {
    #pragma unroll
    for (int i = 0; i < 9; ++i) g[i] += __shfl_xor(g[i], m);
  }
  float h[9], tot[9];
  #pragma unroll
  for (int i = 0; i < 9; ++i) h[i] = g[i] + __shfl_xor(g[i], 16);
  #pragma unroll
  for (int i = 0; i < 9; ++i) tot[i] = h[i] + __shfl_xor(h[i], 32);
  if (lane == 0) {
    #pragma unroll
    for (int i = 0; i < 9; ++i) {
      smom[wv][i] = g[i]; smom[wv][9 + i] = h[i]; smom[wv][18 + i] = tot[i];
    }
  }
  __syncthreads();
  if (tid < 27) {
    mpart[blockIdx.x * 32 + tid] =
        smom[0][tid] + smom[1][tid] + smom[2][tid] + smom[3][tid];
  }
}

// ---------------------------------------------------------------- BN0 finalize (all 3 branches)
__global__ __launch_bounds__(256) void finalize0_kernel(const float* __restrict__ mpart,
    const float* __restrict__ w00, const float* __restrict__ b00,
    const float* __restrict__ g00, const float* __restrict__ be00,
    const float* __restrict__ w01, const float* __restrict__ b01,
    const float* __restrict__ g01, const float* __restrict__ be01,
    const float* __restrict__ w02, const float* __restrict__ b02,
    const float* __restrict__ g02, const float* __restrict__ be02,
    float* __restrict__ scsh) {
  __shared__ float fsum[8][32];
  __shared__ float mom[32];
  const int t = threadIdx.x;
  const int col = t & 31, chunk = t >> 5;
  float s = 0.f;
  for (int r = chunk * 256; r < chunk * 256 + 256; ++r) s += mpart[r * 32 + col];
  fsum[chunk][col] = s;
  __syncthreads();
  if (t < 32) {
    float s2 = 0.f;
    #pragma unroll
    for (int c = 0; c < 8; ++c) s2 += fsum[c][t];
    mom[t] = s2;
  }
  __syncthreads();
  int br, o; const float *w, *bb, *gg, *be; float E; int base;
  if (t < 32)       { br = 0; o = t;      w = w00; bb = b00; gg = g00; be = be00; E = 131072.f; base = 0; }
  else if (t < 96)  { br = 1; o = t - 32; w = w01; bb = b01; gg = g01; be = be01; E = 262144.f; base = 9; }
  else if (t < 160) { br = 2; o = t - 96; w = w02; bb = b02; gg = g02; be = be02; E = 524288.f; base = 18; }
  else return;
  const float Sx = mom[base], Sy = mom[base + 1], Sz = mom[base + 2];
  const float mxx = mom[base + 3], mxy = mom[base + 4], mxz = mom[base + 5];
  const float myy = mom[base + 6], myz = mom[base + 7], mzz = mom[base + 8];
  const float W0 = w[o * 3], W1 = w[o * 3 + 1], W2 = w[o * 3 + 2], bo = bb[o];
  const float wS = W0 * Sx + W1 * Sy + W2 * Sz;
  const float qf = W0 * W0 * mxx + 2.f * W0 * W1 * mxy + 2.f * W0 * W2 * mxz
                 + W1 * W1 * myy + 2.f * W1 * W2 * myz + W2 * W2 * mzz;
  const float mean = wS / E + bo;
  const float msq = (qf + 2.f * bo * wS) / E + bo * bo;
  const float var = msq - mean * mean;
  const float inv = 1.0f / sqrtf(var + 1e-5f);
  const float sc = gg[o] * inv;
  scsh[br * 768 + o] = sc;
  scsh[br * 768 + 128 + o] = be[o] - mean * sc;
}

// ---------------------------------------------------------------- weight transpose (w2 only)
__global__ __launch_bounds__(256) void transpose_kernel(const float* __restrict__ w,
                                                        float* __restrict__ wt, int O, int C) {
  const int i = blockIdx.x * 256 + threadIdx.x;
  if (i < O * C) { const int o = i / C, c = i - o * C; wt[c * O + o] = w[o * C + c]; }
}

// ---------------------------------------------------------------- stats reduction, stage A
__global__ __launch_bounds__(256) void reduce_rows_kernel(const float* __restrict__ partials,
                                                          int nb, float* __restrict__ out32) {
  const int r0 = blockIdx.x, j = threadIdx.x;
  const int chunk = (nb + 31) / 32;
  const int lo = r0 * chunk;
  const int hi = (lo + chunk < nb) ? lo + chunk : nb;
  float s = 0.f;
  for (int r = lo; r < hi; ++r) s += partials[(size_t)r * 256 + j];
  out32[r0 * 256 + j] = s;
}

// ---------------------------------------------------------------- BN finalize
__global__ __launch_bounds__(256) void finalize_kernel(const float* __restrict__ partials, int nb,
    const float* __restrict__ g, const float* __restrict__ be, float n,
    float* __restrict__ sc, float* __restrict__ sh, int CO) {
  __shared__ float tot[256];
  const int j = threadIdx.x;
  if (j < 2 * CO) {
    float s = 0.f;
    for (int r = 0; r < nb; ++r) s += partials[(size_t)r * 256 + j];
    tot[j] = s;
  }
  __syncthreads();
  if (j < CO) {
    const float m = tot[2 * j] / n;
    const float v = tot[2 * j + 1] / n - m * m;
    const float inv = 1.0f / sqrtf(v + 1e-5f);
    const float scv = g[j] * inv;
    sc[j] = scv;
    sh[j] = be[j] - m * scv;
  }
}

// ---------------------------------------------------------------- fused MLP pass
// L=1/2: forward up to layer L + (sum,sumsq) partials of pre-BN x_L.
// L==2 && XS: additionally store pre-BN x2 rows to x2buf as bf16.
// L=3 (fallback path only): full forward + BN + relu + max-over-K + store.
template<int K_, int C0, int C1, int C2, int L, int BOFF, int T, bool XS>
__global__ __launch_bounds__(T) void pass_kernel(
    const float* __restrict__ pts, const int* __restrict__ knnidx,
    const float* __restrict__ w0, const float* __restrict__ b0,
    const float* __restrict__ w1, const float* __restrict__ b1,
    const float* __restrict__ w2t, const float* __restrict__ b2,
    const float* __restrict__ scsh, float* __restrict__ partials,
    __hip_bfloat16* __restrict__ x2buf, float* __restrict__ out) {
  constexpr int RS = C1 + 1;
  constexpr int NAROW = (L >= 2) ? T * RS : 1;
  __shared__ __hip_bfloat16 arow[NAROW];
  __shared__ float spart[(T / 64) * 256];
  const int tid = threadIdx.x;
  const int lane = tid & 63;
  const int e = blockIdx.x * T + tid;
  const int b = e / (1024 * K_);
  const int rem = e - b * (1024 * K_);
  const int s = rem / K_;
  const int pidx = knnidx[(b * 1024 + s) * 64 + (rem - s * K_)];
  const float* pp = pts + ((size_t)b * 8192 + pidx) * 3;
  const float zx = pp[0], zy = pp[1], zz = pp[2];
  float* prow = partials + (size_t)blockIdx.x * 256;

  // layer 0 (3 -> C0) + BN0 + relu
  float a0[C0];
  #pragma unroll
  for (int o = 0; o < C0; ++o)
    a0[o] = b0[o] + zx * w0[3 * o] + zy * w0[3 * o + 1] + zz * w0[3 * o + 2];
  {
    const float* sc0 = scsh + 0;
    const float* sh0 = scsh + 128;
    #pragma unroll
    for (int o = 0; o < C0; ++o) a0[o] = fmaxf(0.f, a0[o] * sc0[o] + sh0[o]);
  }

  // layer 1 (C0 -> C1)
  if constexpr (L == 1) {
    float* swl = spart + (tid >> 6) * 256;
    for (int o = 0; o < C1; ++o) {
      float s0 = 0.f, s1 = 0.f, s2 = 0.f, s3 = 0.f;
      #pragma unroll
      for (int c = 0; c < C0; c += 4) {
        s0 += a0[c]     * w1[o * C0 + c];
        s1 += a0[c + 1] * w1[o * C0 + c + 1];
        s2 += a0[c + 2] * w1[o * C0 + c + 2];
        s3 += a0[c + 3] * w1[o * C0 + c + 3];
      }
      const float x = b1[o] + ((s0 + s1) + (s2 + s3));
      float sm = x, sq = x * x;
      #pragma unroll
      for (int m = 32; m >= 1; m >>= 1) { sm += __shfl_xor(sm, m); sq += __shfl_xor(sq, m); }
      if (lane == 0) { swl[2 * o] = sm; swl[2 * o + 1] = sq; }
    }
    __syncthreads();
    for (int col = tid; col < 2 * C1; col += T) {   // 2*C1 can exceed T
      float s2_ = 0.f;
      #pragma unroll
      for (int w = 0; w < T / 64; ++w) s2_ += spart[w * 256 + col];
      prow[col] = s2_;
    }
    return;
  }

  // L >= 2: act1 -> LDS (bf16)
  {
    const float* sc1 = scsh + 256;
    const float* sh1 = scsh + 384;
    for (int o = 0; o < C1; ++o) {
      float s0 = 0.f, s1 = 0.f, s2 = 0.f, s3 = 0.f;
      #pragma unroll
      for (int c = 0; c < C0; c += 4) {
        s0 += a0[c]     * w1[o * C0 + c];
        s1 += a0[c + 1] * w1[o * C0 + c + 1];
        s2 += a0[c + 2] * w1[o * C0 + c + 2];
        s3 += a0[c + 3] * w1[o * C0 + c + 3];
      }
      const float x = b1[o] + ((s0 + s1) + (s2 + s3));
      arow[tid * RS + o] = __float2bfloat16(fmaxf(0.f, x * sc1[o] + sh1[o]));
    }
  }

  // layer 2 (C1 -> C2), output chunks of 32
  const float* sc2 = scsh + 512;
  const float* sh2 = scsh + 640;
  const size_t orow = (size_t)(b * 1024 + s) * 320 + BOFF;
  __hip_bfloat162* x2p = (__hip_bfloat162*)(x2buf + (size_t)e * C2);
  #pragma unroll
  for (int CB = 0; CB < C2; CB += 32) {
    float acc[32];
    #pragma unroll
    for (int j = 0; j < 32; ++j) acc[j] = b2[CB + j];
    for (int c = 0; c < C1; ++c) {
      const float zc = __bfloat162float(arow[tid * RS + c]);
      #pragma unroll
      for (int j = 0; j < 32; ++j) acc[j] += zc * w2t[c * C2 + CB + j];
    }
    if constexpr (L == 2) {
      if constexpr (XS) {
        #pragma unroll
        for (int j = 0; j < 16; ++j) {
          __hip_bfloat162 pr;
          pr.x = __float2bfloat16(acc[2 * j]);
          pr.y = __float2bfloat16(acc[2 * j + 1]);
          x2p[CB / 2 + j] = pr;
        }
      }
      do_stats<32, 0, 32, T>(acc, tid, spart, prow, 2 * CB);
    } else {
      #pragma unroll
      for (int j = 0; j < 32; ++j) acc[j] = fmaxf(0.f, acc[j] * sc2[CB + j] + sh2[CB + j]);
      int base = 0;
      halve<32, (K_ >> 1), OpMax, 32>(acc, lane, base);
      constexpr int F = (32 / K_ > 0) ? (32 / K_) : 1;
      #pragma unroll
      for (int i = 0; i < F; ++i) out[orow + CB + base + i] = acc[i];
    }
  }
}

// ---------------------------------------------------------------- BN+relu+maxpool from stored x2
template<int K_, int C2, int BOFF>
__global__ __launch_bounds__(256) void pool_kernel(const unsigned int* __restrict__ x2u,
                                                   const float* __restrict__ scsh,
                                                   float* __restrict__ out) {
  constexpr int CP = C2 / 2;
  const int g = blockIdx.x * 256 + threadIdx.x;
  const int cp = g % CP;
  const int sample = g / CP;
  const float sca = scsh[512 + 2 * cp], scb = scsh[512 + 2 * cp + 1];
  const float sha = scsh[640 + 2 * cp], shb = scsh[640 + 2 * cp + 1];
  float m0 = 0.f, m1 = 0.f;
  const size_t base = (size_t)sample * K_ * CP + cp;
  #pragma unroll 4
  for (int k = 0; k < K_; ++k) {
    const unsigned v = x2u[base + (size_t)k * CP];
    const float x0 = __uint_as_float(v << 16);
    const float x1 = __uint_as_float(v & 0xFFFF0000u);
    m0 = fmaxf(m0, fmaxf(0.f, x0 * sca + sha));
    m1 = fmaxf(m1, fmaxf(0.f, x1 * scb + shb));
  }
  float2 r; r.x = m0; r.y = m1;
  *(float2*)&out[(size_t)sample * 320 + BOFF + 2 * cp] = r;
}

// ---------------------------------------------------------------- host side
template<int K_, int C0, int C1, int C2, int BOFF, bool XS>
static void run_branch(const float* pts, const int* knn_,
                       const float* const* W_, const float* const* B_,
                       const float* const* G_, const float* const* BE_,
                       float* scshb, float* partials, float* partials2, float* w2t,
                       __hip_bfloat16* x2buf, float* out, hipStream_t stream) {
  constexpr int T = 128;
  constexpr int NE = 8 * 1024 * K_;
  constexpr int NB = NE / T;
  transpose_kernel<<<(C1 * C2 + 255) / 256, 256, 0, stream>>>(W_[2], w2t, C2, C1);
  pass_kernel<K_, C0, C1, C2, 1, BOFF, T, XS><<<NB, T, 0, stream>>>(
      pts, knn_, W_[0], B_[0], W_[1], B_[1], w2t, B_[2], scshb, partials, x2buf, out);
  reduce_rows_kernel<<<32, 256, 0, stream>>>(partials, NB, partials2);
  finalize_kernel<<<1, 256, 0, stream>>>(partials2, 32, G_[1], BE_[1], (float)NE,
                                         scshb + 256, scshb + 384, C1);
  pass_kernel<K_, C0, C1, C2, 2, BOFF, T, XS><<<NB, T, 0, stream>>>(
      pts, knn_, W_[0], B_[0], W_[1], B_[1], w2t, B_[2], scshb, partials, x2buf, out);
  reduce_rows_kernel<<<32, 256, 0, stream>>>(partials, NB, partials2);
  finalize_kernel<<<1, 256, 0, stream>>>(partials2, 32, G_[2], BE_[2], (float)NE,
                                         scshb + 512, scshb + 640, C2);
  if constexpr (XS) {
    constexpr int NP = 8 * 1024 * (C2 / 2);
    pool_kernel<K_, C2, BOFF><<<NP / 256, 256, 0, stream>>>(
        (const unsigned int*)x2buf, scshb, out);
  } else {
    pass_kernel<K_, C0, C1, C2, 3, BOFF, T, XS><<<NB, T, 0, stream>>>(
        pts, knn_, W_[0], B_[0], W_[1], B_[1], w2t, B_[2], scshb, partials, x2buf, out);
  }
}

extern "C" void kernel_launch(void* const* d_in, const int* in_sizes, int n_in,
                              void* d_out, int out_size, void* d_ws, size_t ws_size,
                              hipStream_t stream) {
  (void)in_sizes; (void)n_in; (void)out_size;
  const float* pts = (const float*)d_in[0];
  const float* W_[9]; const float* B_[9]; const float* G_[9]; const float* BE_[9];
  for (int m = 0; m < 9; ++m) {
    W_[m]  = (const float*)d_in[1 + m * 4 + 0];
    B_[m]  = (const float*)d_in[1 + m * 4 + 1];
    G_[m]  = (const float*)d_in[1 + m * 4 + 2];
    BE_[m] = (const float*)d_in[1 + m * 4 + 3];
  }
  char* ws = (char*)d_ws;
  float4* cent      = (float4*)ws;                         // @0,       131072 B
  int*    knn_      = (int*)(ws + 131072);                 // @131072,  2 MB
  float*  partials  = (float*)(ws + 2228224);              // @2228224, 4 MB (also mpart)
  float*  scsh      = (float*)(ws + 6422528);              // 12 KB (3 branches x 768)
  float*  w2t       = (float*)(ws + 6434816);              // 48 KB
  float*  partials2 = (float*)(ws + 6483968);              // 32 KB
  __hip_bfloat16* x2buf = (__hip_bfloat16*)(ws + 6516736); // up to 134217728 B
  float*  out       = (float*)d_out;
  const bool xs = ws_size >= (size_t)6516736 + 134217728ull;

  fps_kernel<<<8, 512, 0, stream>>>(pts, cent);
  knn_kernel<<<2048, 256, 0, stream>>>(pts, cent, knn_);
  moments_kernel<<<2048, 256, 0, stream>>>(pts, knn_, partials);
  finalize0_kernel<<<1, 256, 0, stream>>>(partials,
      W_[0], B_[0], G_[0], BE_[0], W_[3], B_[3], G_[3], BE_[3],
      W_[6], B_[6], G_[6], BE_[6], scsh);

  if (xs) {
    run_branch<16, 32, 32, 64, 0, true>(pts, knn_, W_ + 0, B_ + 0, G_ + 0, BE_ + 0,
                                        scsh, partials, partials2, w2t, x2buf, out, stream);
    run_branch<32, 64, 64, 128, 64, true>(pts, knn_, W_ + 3, B_ + 3, G_ + 3, BE_ + 3,
                                          scsh + 768, partials, partials2, w2t, x2buf, out, stream);
    run_branch<64, 64, 96, 128, 192, true>(pts, knn_, W_ + 6, B_ + 6, G_ + 6, BE_ + 6,
                                           scsh + 1536, partials, partials2, w2t, x2buf, out, stream);
  } else {
    run_branch<16, 32, 32, 64, 0, false>(pts, knn_, W_ + 0, B_ + 0, G_ + 0, BE_ + 0,
                                         scsh, partials, partials2, w2t, x2buf, out, stream);
    run_branch<32, 64, 64, 128, 64, false>(pts, knn_, W_ + 3, B_ + 3, G_ + 3, BE_ + 3,
                                           scsh + 768, partials, partials2, w2t, x2buf, out, stream);
    run_branch<64, 64, 96, 128, 192, false>(pts, knn_, W_ + 6, B_ + 6, G_ + 6, BE_ + 6,
                                            scsh + 1536, partials, partials2, w2t, x2buf, out, stream);
  }
}

// Round 10
// 2397.849 us; speedup vs baseline: 3.7522x; 1.1131x over previous
//
#include <hip/hip_runtime.h>
#include <hip/hip_bf16.h>
#include <hip/hip_fp16.h>

#define DEVFN __device__ __forceinline__

// ---------------------------------------------------------------- utilities
struct OpSum { DEVFN float operator()(float a, float b) const { return a + b; } };
struct OpMax { DEVFN float operator()(float a, float b) const { return fmaxf(a, b); } };

template<int CH, int D, typename OP, int NV>
DEVFN void halve(float (&v)[NV], int lane, int& base) {
  if constexpr (D >= 1) {
    OP op;
    if constexpr (CH > 1) {
      constexpr int H = CH / 2;
      #pragma unroll
      for (int i = 0; i < H; ++i) {
        float send = (lane & D) ? v[i] : v[H + i];
        float r = __shfl_xor(send, D);
        float keep = (lane & D) ? v[H + i] : v[i];
        v[i] = op(keep, r);
      }
      if (lane & D) base += H;
      halve<H, (D >> 1), OP, NV>(v, lane, base);
    } else {
      v[0] = op(v[0], __shfl_xor(v[0], D));
      halve<CH, (D >> 1), OP, NV>(v, lane, base);
    }
  }
}

// Sum + sumsq of channels a[OFF..OFF+CC) across all T threads of the block.
template<int CC, int OFF, int NA, int T>
DEVFN void do_stats(const float (&a)[NA], int tid, float* spart, float* prow, int statoff) {
  float v[2 * CC];
  #pragma unroll
  for (int j = 0; j < CC; ++j) { float x = a[OFF + j]; v[2 * j] = x; v[2 * j + 1] = x * x; }
  int lane = tid & 63, base = 0;
  halve<2 * CC, 32, OpSum, 2 * CC>(v, lane, base);
  constexpr int F = (2 * CC) / 64 > 0 ? (2 * CC) / 64 : 1;
  int wv = tid >> 6;
  #pragma unroll
  for (int i = 0; i < F; ++i) spart[wv * 256 + base + i] = v[i];
  __syncthreads();
  constexpr int NW = T / 64;
  if (tid < 2 * CC) {
    float s2 = 0.f;
    #pragma unroll
    for (int w = 0; w < NW; ++w) s2 += spart[w * 256 + tid];
    prow[statoff + tid] = s2;
  }
  __syncthreads();
}

// ---------------------------------------------------------------- FPS (R9, at structural floor)
__global__ __launch_bounds__(512) void fps_kernel(const float* __restrict__ pts,
                                                  float4* __restrict__ cent) {
  const int b = blockIdx.x, t = threadIdx.x;
  const int wv = t >> 6;
  __shared__ unsigned long long sk2[2][8];
  __shared__ float4 sc4[2][8];
  __shared__ float4 scent[1024];
  const float* p = pts + (size_t)b * 8192 * 3;
  float px[16], py[16], pz[16], dd[16];
  #pragma unroll
  for (int j = 0; j < 16; ++j) {
    const int i = t + j * 512;
    px[j] = p[i * 3]; py[j] = p[i * 3 + 1]; pz[j] = p[i * 3 + 2];
    dd[j] = 1e10f;
  }
  float cx = p[0], cy = p[1], cz = p[2];
  for (int it = 0; it < 1024; ++it) {
    if (t == 0) scent[it] = make_float4(cx, cy, cz, 0.f);
    const int par = it & 1;
    float bd = -1.f, bx = 0.f, by = 0.f, bz = 0.f; int bi = 0;
    #pragma unroll
    for (int j = 0; j < 16; ++j) {
      const float dx = px[j] - cx, dy = py[j] - cy, dz = pz[j] - cz;
      float d = fminf(dd[j], dx * dx + dy * dy + dz * dz);
      dd[j] = d;
      if (d > bd) { bd = d; bi = t + j * 512; bx = px[j]; by = py[j]; bz = pz[j]; }
    }
    unsigned long long key = ((unsigned long long)__float_as_uint(bd) << 32)
                             | (0xFFFFFFFFu - (unsigned)bi);
    const unsigned long long k0 = key;
    #pragma unroll
    for (int m = 32; m >= 1; m >>= 1) {
      const unsigned long long ok = __shfl_xor(key, m);
      key = ok > key ? ok : key;
    }
    if (key == k0) {
      sk2[par][wv] = key;
      sc4[par][wv] = make_float4(bx, by, bz, 0.f);
    }
    __syncthreads();
    unsigned long long gk = sk2[par][0];
    float4 c4 = sc4[par][0];
    #pragma unroll
    for (int w = 1; w < 8; ++w) {
      const unsigned long long k2 = sk2[par][w];
      const float4 cc = sc4[par][w];
      if (k2 > gk) { gk = k2; c4 = cc; }
    }
    cx = c4.x; cy = c4.y; cz = c4.z;
  }
  __syncthreads();
  #pragma unroll
  for (int i = t; i < 1024; i += 512) cent[(size_t)b * 1024 + i] = scent[i];
}

// ---------------------------------------------------------------- kNN
__global__ __launch_bounds__(256) void knn_kernel(const float* __restrict__ pts,
                                                  const float4* __restrict__ cent,
                                                  int* __restrict__ knn) {
  const int wid = (blockIdx.x * 256 + threadIdx.x) >> 6;
  const int lane = threadIdx.x & 63;
  const int b = wid >> 10;
  const float4 q = cent[wid];
  const float q2 = q.x * q.x + q.y * q.y + q.z * q.z;
  const float* p = pts + (size_t)b * 8192 * 3;
  unsigned long long R = ~0ull;
  for (int c0 = 0; c0 < 8192; c0 += 64) {
    const int i = c0 + lane;
    const float x = p[i * 3], y = p[i * 3 + 1], z = p[i * 3 + 2];
    const float p2 = x * x + y * y + z * z;
    const float dot = q.x * x + q.y * y + q.z * z;
    float d2 = q2 - 2.f * dot + p2;
    d2 = fmaxf(d2, 0.f);
    unsigned u = __float_as_uint(d2);
    u = (u & 0x80000000u) ? ~u : (u | 0x80000000u);
    const unsigned long long key = ((unsigned long long)u << 32) | (unsigned)i;
    const unsigned long long rmax = __shfl(R, 63);
    unsigned long long mask = __ballot(key < rmax);
    while (mask) {
      const int src = __ffsll(mask) - 1;
      mask &= mask - 1;
      const unsigned long long nk = __shfl(key, src);
      const int pos = __popcll(__ballot(R < nk));
      if (pos < 64) {
        const unsigned long long Rm1 = __shfl_up(R, 1);
        R = (lane < pos) ? R : (lane == pos ? nk : Rm1);
      }
    }
  }
  knn[wid * 64 + lane] = (int)(R & 0xffffffffu);
}

// ---------------------------------------------------------------- gather moments (BN0 stats)
__global__ __launch_bounds__(256) void moments_kernel(const float* __restrict__ pts,
                                                      const int* __restrict__ knn_,
                                                      float* __restrict__ mpart) {
  __shared__ float smom[4][27];
  const int tid = threadIdx.x, lane = tid & 63, wv = tid >> 6;
  const int samp = blockIdx.x * 4 + wv;
  const int b = samp >> 10;
  const int pidx = knn_[samp * 64 + lane];
  const float* pp = pts + ((size_t)b * 8192 + pidx) * 3;
  const float x = pp[0], y = pp[1], z = pp[2];
  float g[9] = {x, y, z, x * x, x * y, x * z, y * y, y * z, z * z};
  #pragma unroll
  for (int m = 8; m >= 1; m >>= 1) {
    #pragma unroll
    for (int i = 0; i < 9; ++i) g[i] += __shfl_xor(g[i], m);
  }
  float h[9], tot[9];
  #pragma unroll
  for (int i = 0; i < 9; ++i) h[i] = g[i] + __shfl_xor(g[i], 16);
  #pragma unroll
  for (int i = 0; i < 9; ++i) tot[i] = h[i] + __shfl_xor(h[i], 32);
  if (lane == 0) {
    #pragma unroll
    for (int i = 0; i < 9; ++i) {
      smom[wv][i] = g[i]; smom[wv][9 + i] = h[i]; smom[wv][18 + i] = tot[i];
    }
  }
  __syncthreads();
  if (tid < 27) {
    mpart[blockIdx.x * 32 + tid] =
        smom[0][tid] + smom[1][tid] + smom[2][tid] + smom[3][tid];
  }
}

// ---------------------------------------------------------------- BN0 finalize (all 3 branches)
__global__ __launch_bounds__(256) void finalize0_kernel(const float* __restrict__ mpart,
    const float* __restrict__ w00, const float* __restrict__ b00,
    const float* __restrict__ g00, const float* __restrict__ be00,
    const float* __restrict__ w01, const float* __restrict__ b01,
    const float* __restrict__ g01, const float* __restrict__ be01,
    const float* __restrict__ w02, const float* __restrict__ b02,
    const float* __restrict__ g02, const float* __restrict__ be02,
    float* __restrict__ scsh) {
  __shared__ float fsum[8][32];
  __shared__ float mom[32];
  const int t = threadIdx.x;
  const int col = t & 31, chunk = t >> 5;
  float s = 0.f;
  for (int r = chunk * 256; r < chunk * 256 + 256; ++r) s += mpart[r * 32 + col];
  fsum[chunk][col] = s;
  __syncthreads();
  if (t < 32) {
    float s2 = 0.f;
    #pragma unroll
    for (int c = 0; c < 8; ++c) s2 += fsum[c][t];
    mom[t] = s2;
  }
  __syncthreads();
  int o; const float *w, *bb, *gg, *be; float E; int base, br;
  if (t < 32)       { br = 0; o = t;      w = w00; bb = b00; gg = g00; be = be00; E = 131072.f; base = 0; }
  else if (t < 96)  { br = 1; o = t - 32; w = w01; bb = b01; gg = g01; be = be01; E = 262144.f; base = 9; }
  else if (t < 160) { br = 2; o = t - 96; w = w02; bb = b02; gg = g02; be = be02; E = 524288.f; base = 18; }
  else return;
  const float Sx = mom[base], Sy = mom[base + 1], Sz = mom[base + 2];
  const float mxx = mom[base + 3], mxy = mom[base + 4], mxz = mom[base + 5];
  const float myy = mom[base + 6], myz = mom[base + 7], mzz = mom[base + 8];
  const float W0 = w[o * 3], W1 = w[o * 3 + 1], W2 = w[o * 3 + 2], bo = bb[o];
  const float wS = W0 * Sx + W1 * Sy + W2 * Sz;
  const float qf = W0 * W0 * mxx + 2.f * W0 * W1 * mxy + 2.f * W0 * W2 * mxz
                 + W1 * W1 * myy + 2.f * W1 * W2 * myz + W2 * W2 * mzz;
  const float mean = wS / E + bo;
  const float msq = (qf + 2.f * bo * wS) / E + bo * bo;
  const float var = msq - mean * mean;
  const float inv = 1.0f / sqrtf(var + 1e-5f);
  const float sc = gg[o] * inv;
  scsh[br * 768 + o] = sc;
  scsh[br * 768 + 128 + o] = be[o] - mean * sc;
}

// ---------------------------------------------------------------- transpose all three w2
__global__ __launch_bounds__(256) void transpose3_kernel(const float* __restrict__ wa,
                                                         const float* __restrict__ wb,
                                                         const float* __restrict__ wc,
                                                         float* __restrict__ wt) {
  const int i = blockIdx.x * 256 + threadIdx.x;
  if (i < 2048) {                                // b1: [64][32] -> wt[0..2048)
    const int o = i >> 5, c = i & 31; wt[c * 64 + o] = wa[i];
  } else if (i < 10240) {                        // b2: [128][64] -> wt[2048..10240)
    const int j = i - 2048, o = j >> 6, c = j & 63; wt[2048 + c * 128 + o] = wb[j];
  } else if (i < 22528) {                        // b3: [128][96] -> wt[10240..22528)
    const int j = i - 10240, o = j / 96, c = j - o * 96; wt[10240 + c * 128 + o] = wc[j];
  }
}

// ---------------------------------------------------------------- stats reduction, stage A
__global__ __launch_bounds__(256) void reduce_rows_kernel(const float* __restrict__ partials,
                                                          int nb, float* __restrict__ out32) {
  const int r0 = blockIdx.x, j = threadIdx.x;
  const int chunk = (nb + 31) / 32;
  const int lo = r0 * chunk;
  const int hi = (lo + chunk < nb) ? lo + chunk : nb;
  float s = 0.f;
  for (int r = lo; r < hi; ++r) s += partials[(size_t)r * 256 + j];
  out32[r0 * 256 + j] = s;
}

// ---------------------------------------------------------------- BN finalize
__global__ __launch_bounds__(256) void finalize_kernel(const float* __restrict__ partials, int nb,
    const float* __restrict__ g, const float* __restrict__ be, float n,
    float* __restrict__ sc, float* __restrict__ sh, int CO) {
  __shared__ float tot[256];
  const int j = threadIdx.x;
  if (j < 2 * CO) {
    float s = 0.f;
    for (int r = 0; r < nb; ++r) s += partials[(size_t)r * 256 + j];
    tot[j] = s;
  }
  __syncthreads();
  if (j < CO) {
    const float m = tot[2 * j] / n;
    const float v = tot[2 * j + 1] / n - m * m;
    const float inv = 1.0f / sqrtf(v + 1e-5f);
    const float scv = g[j] * inv;
    sc[j] = scv;
    sh[j] = be[j] - m * scv;
  }
}

// ---------------------------------------------------------------- fused MLP pass
// L=1: gather + L0 + BN0 + L1; store pre-BN x1 transposed (fp16, XS1) + stats.
// L=2: XS1: read x1t, BN1+relu -> arow; else recompute. Then L2 + stats (+x2 store if XS).
// L=3 (fallback, only when !XS): full forward + BN + relu + max-over-K + store.
template<int K_, int C0, int C1, int C2, int L, int BOFF, int T, bool XS, bool XS1>
__global__ __launch_bounds__(T) void pass_kernel(
    const float* __restrict__ pts, const int* __restrict__ knnidx,
    const float* __restrict__ w0, const float* __restrict__ b0,
    const float* __restrict__ w1, const float* __restrict__ b1,
    const float* __restrict__ w2t, const float* __restrict__ b2,
    const float* __restrict__ scsh, float* __restrict__ partials,
    __half* __restrict__ x1t, __half* __restrict__ x2buf, float* __restrict__ out) {
  constexpr int RS = C1 + 1;
  constexpr int NAROW = (L >= 2) ? T * RS : 1;
  constexpr size_t NE = (size_t)8 * 1024 * K_;
  __shared__ __half arow[NAROW];
  __shared__ float spart[(T / 64) * 256];
  const int tid = threadIdx.x;
  const int lane = tid & 63;
  const int e = blockIdx.x * T + tid;
  const int b = e / (1024 * K_);
  const int rem = e - b * (1024 * K_);
  const int s = rem / K_;
  float* prow = partials + (size_t)blockIdx.x * 256;

  float a0[C0];
  if constexpr (!(XS1 && L == 2)) {
    // gather + layer 0 (3 -> C0) + BN0 + relu
    const int pidx = knnidx[(b * 1024 + s) * 64 + (rem - s * K_)];
    const float* pp = pts + ((size_t)b * 8192 + pidx) * 3;
    const float zx = pp[0], zy = pp[1], zz = pp[2];
    #pragma unroll
    for (int o = 0; o < C0; ++o)
      a0[o] = b0[o] + zx * w0[3 * o] + zy * w0[3 * o + 1] + zz * w0[3 * o + 2];
    const float* sc0 = scsh + 0;
    const float* sh0 = scsh + 128;
    #pragma unroll
    for (int o = 0; o < C0; ++o) a0[o] = fmaxf(0.f, a0[o] * sc0[o] + sh0[o]);
  }

  // layer 1 (C0 -> C1)
  if constexpr (L == 1) {
    float* swl = spart + (tid >> 6) * 256;
    for (int o = 0; o < C1; ++o) {
      float s0 = 0.f, s1 = 0.f, s2 = 0.f, s3 = 0.f;
      #pragma unroll
      for (int c = 0; c < C0; c += 4) {
        s0 += a0[c]     * w1[o * C0 + c];
        s1 += a0[c + 1] * w1[o * C0 + c + 1];
        s2 += a0[c + 2] * w1[o * C0 + c + 2];
        s3 += a0[c + 3] * w1[o * C0 + c + 3];
      }
      const float x = b1[o] + ((s0 + s1) + (s2 + s3));
      if constexpr (XS1) x1t[(size_t)o * NE + e] = __float2half(x);
      float sm = x, sq = x * x;
      #pragma unroll
      for (int m = 32; m >= 1; m >>= 1) { sm += __shfl_xor(sm, m); sq += __shfl_xor(sq, m); }
      if (lane == 0) { swl[2 * o] = sm; swl[2 * o + 1] = sq; }
    }
    __syncthreads();
    for (int col = tid; col < 2 * C1; col += T) {   // 2*C1 can exceed T
      float s2_ = 0.f;
      #pragma unroll
      for (int w = 0; w < T / 64; ++w) s2_ += spart[w * 256 + col];
      prow[col] = s2_;
    }
    return;
  }

  // L >= 2: act1 -> LDS (fp16)
  {
    const float* sc1 = scsh + 256;
    const float* sh1 = scsh + 384;
    if constexpr (XS1 && L == 2) {
      for (int o = 0; o < C1; ++o) {
        const float xv = __half2float(x1t[(size_t)o * NE + e]);
        arow[tid * RS + o] = __float2half(fmaxf(0.f, xv * sc1[o] + sh1[o]));
      }
    } else {
      for (int o = 0; o < C1; ++o) {
        float s0 = 0.f, s1 = 0.f, s2 = 0.f, s3 = 0.f;
        #pragma unroll
        for (int c = 0; c < C0; c += 4) {
          s0 += a0[c]     * w1[o * C0 + c];
          s1 += a0[c + 1] * w1[o * C0 + c + 1];
          s2 += a0[c + 2] * w1[o * C0 + c + 2];
          s3 += a0[c + 3] * w1[o * C0 + c + 3];
        }
        const float x = b1[o] + ((s0 + s1) + (s2 + s3));
        arow[tid * RS + o] = __float2half(fmaxf(0.f, x * sc1[o] + sh1[o]));
      }
    }
  }

  // layer 2 (C1 -> C2), output chunks of 32
  const float* sc2 = scsh + 512;
  const float* sh2 = scsh + 640;
  const size_t orow = (size_t)(b * 1024 + s) * 320 + BOFF;
  __half2* x2p = (__half2*)(x2buf + (size_t)e * C2);
  #pragma unroll
  for (int CB = 0; CB < C2; CB += 32) {
    float acc[32];
    #pragma unroll
    for (int j = 0; j < 32; ++j) acc[j] = b2[CB + j];
    for (int c = 0; c < C1; ++c) {
      const float zc = __half2float(arow[tid * RS + c]);
      #pragma unroll
      for (int j = 0; j < 32; ++j) acc[j] += zc * w2t[c * C2 + CB + j];
    }
    if constexpr (L == 2) {
      if constexpr (XS) {
        #pragma unroll
        for (int j = 0; j < 16; ++j)
          x2p[CB / 2 + j] = __floats2half2_rn(acc[2 * j], acc[2 * j + 1]);
      }
      do_stats<32, 0, 32, T>(acc, tid, spart, prow, 2 * CB);
    } else {
      #pragma unroll
      for (int j = 0; j < 32; ++j) acc[j] = fmaxf(0.f, acc[j] * sc2[CB + j] + sh2[CB + j]);
      int base = 0;
      halve<32, (K_ >> 1), OpMax, 32>(acc, lane, base);
      constexpr int F = (32 / K_ > 0) ? (32 / K_) : 1;
      #pragma unroll
      for (int i = 0; i < F; ++i) out[orow + CB + base + i] = acc[i];
    }
  }
}

// ---------------------------------------------------------------- BN+relu+maxpool from stored x2
template<int K_, int C2, int BOFF>
__global__ __launch_bounds__(256) void pool_kernel(const __half2* __restrict__ x2h,
                                                   const float* __restrict__ scsh,
                                                   float* __restrict__ out) {
  constexpr int CP = C2 / 2;
  const int g = blockIdx.x * 256 + threadIdx.x;
  const int cp = g % CP;
  const int sample = g / CP;
  const float sca = scsh[512 + 2 * cp], scb = scsh[512 + 2 * cp + 1];
  const float sha = scsh[640 + 2 * cp], shb = scsh[640 + 2 * cp + 1];
  float m0 = 0.f, m1 = 0.f;
  const size_t base = (size_t)sample * K_ * CP + cp;
  #pragma unroll 4
  for (int k = 0; k < K_; ++k) {
    const float2 f = __half22float2(x2h[base + (size_t)k * CP]);
    m0 = fmaxf(m0, fmaxf(0.f, f.x * sca + sha));
    m1 = fmaxf(m1, fmaxf(0.f, f.y * scb + shb));
  }
  float2 r; r.x = m0; r.y = m1;
  *(float2*)&out[(size_t)sample * 320 + BOFF + 2 * cp] = r;
}

// ---------------------------------------------------------------- host side
template<int K_, int C0, int C1, int C2, int BOFF, bool XS, bool XS1>
static void run_branch(const float* pts, const int* knn_,
                       const float* const* W_, const float* const* B_,
                       const float* const* G_, const float* const* BE_,
                       float* scshb, float* partials, float* partials2, float* w2tb,
                       __half* x1t, __half* x2buf, float* out, hipStream_t stream) {
  constexpr int T = 128;
  constexpr int NE = 8 * 1024 * K_;
  constexpr int NB = NE / T;
  pass_kernel<K_, C0, C1, C2, 1, BOFF, T, XS, XS1><<<NB, T, 0, stream>>>(
      pts, knn_, W_[0], B_[0], W_[1], B_[1], w2tb, B_[2], scshb, partials, x1t, x2buf, out);
  reduce_rows_kernel<<<32, 256, 0, stream>>>(partials, NB, partials2);
  finalize_kernel<<<1, 256, 0, stream>>>(partials2, 32, G_[1], BE_[1], (float)NE,
                                         scshb + 256, scshb + 384, C1);
  pass_kernel<K_, C0, C1, C2, 2, BOFF, T, XS, XS1><<<NB, T, 0, stream>>>(
      pts, knn_, W_[0], B_[0], W_[1], B_[1], w2tb, B_[2], scshb, partials, x1t, x2buf, out);
  reduce_rows_kernel<<<32, 256, 0, stream>>>(partials, NB, partials2);
  finalize_kernel<<<1, 256, 0, stream>>>(partials2, 32, G_[2], BE_[2], (float)NE,
                                         scshb + 512, scshb + 640, C2);
  if constexpr (XS) {
    constexpr int NP = 8 * 1024 * (C2 / 2);
    pool_kernel<K_, C2, BOFF><<<NP / 256, 256, 0, stream>>>(
        (const __half2*)x2buf, scshb, out);
  } else {
    pass_kernel<K_, C0, C1, C2, 3, BOFF, T, XS, XS1><<<NB, T, 0, stream>>>(
        pts, knn_, W_[0], B_[0], W_[1], B_[1], w2tb, B_[2], scshb, partials, x1t, x2buf, out);
  }
}

template<bool XS, bool XS1>
static void run_all(const float* pts, const int* knn_,
                    const float* const* W_, const float* const* B_,
                    const float* const* G_, const float* const* BE_,
                    float* scsh, float* partials, float* partials2, float* w2t,
                    __half* x1t, __half* x2buf, float* out, hipStream_t stream) {
  run_branch<16, 32, 32, 64, 0, XS, XS1>(pts, knn_, W_ + 0, B_ + 0, G_ + 0, BE_ + 0,
      scsh, partials, partials2, w2t, x1t, x2buf, out, stream);
  run_branch<32, 64, 64, 128, 64, XS, XS1>(pts, knn_, W_ + 3, B_ + 3, G_ + 3, BE_ + 3,
      scsh + 768, partials, partials2, w2t + 2048, x1t, x2buf, out, stream);
  run_branch<64, 64, 96, 128, 192, XS, XS1>(pts, knn_, W_ + 6, B_ + 6, G_ + 6, BE_ + 6,
      scsh + 1536, partials, partials2, w2t + 10240, x1t, x2buf, out, stream);
}

extern "C" void kernel_launch(void* const* d_in, const int* in_sizes, int n_in,
                              void* d_out, int out_size, void* d_ws, size_t ws_size,
                              hipStream_t stream) {
  (void)in_sizes; (void)n_in; (void)out_size;
  const float* pts = (const float*)d_in[0];
  const float* W_[9]; const float* B_[9]; const float* G_[9]; const float* BE_[9];
  for (int m = 0; m < 9; ++m) {
    W_[m]  = (const float*)d_in[1 + m * 4 + 0];
    B_[m]  = (const float*)d_in[1 + m * 4 + 1];
    G_[m]  = (const float*)d_in[1 + m * 4 + 2];
    BE_[m] = (const float*)d_in[1 + m * 4 + 3];
  }
  char* ws = (char*)d_ws;
  float4* cent      = (float4*)ws;                          // @0,        131072 B
  int*    knn_      = (int*)(ws + 131072);                  // @131072,   2 MB
  float*  partials  = (float*)(ws + 2228224);               // @2228224,  4 MB (also mpart)
  float*  scsh      = (float*)(ws + 6422528);               // 12 KB (3 x 768 floats)
  float*  w2t       = (float*)(ws + 6434816);               // 96 KB (22528 floats, 3 branches)
  float*  partials2 = (float*)(ws + 6533120);               // 32 KB
  __half* x2buf     = (__half*)(ws + 6565888);              // 134217728 B max
  __half* x1t       = (__half*)(ws + 6565888 + 134217728ull); // 100663296 B max
  float*  out       = (float*)d_out;
  const bool xs  = ws_size >= 6565888ull + 134217728ull;
  const bool xs1 = ws_size >= 6565888ull + 134217728ull + 100663296ull;

  fps_kernel<<<8, 512, 0, stream>>>(pts, cent);
  knn_kernel<<<2048, 256, 0, stream>>>(pts, cent, knn_);
  moments_kernel<<<2048, 256, 0, stream>>>(pts, knn_, partials);
  finalize0_kernel<<<1, 256, 0, stream>>>(partials,
      W_[0], B_[0], G_[0], BE_[0], W_[3], B_[3], G_[3], BE_[3],
      W_[6], B_[6], G_[6], BE_[6], scsh);
  transpose3_kernel<<<88, 256, 0, stream>>>(W_[2], W_[5], W_[8], w2t);

  if (xs && xs1)
    run_all<true, true>(pts, knn_, W_, B_, G_, BE_, scsh, partials, partials2,
                        w2t, x1t, x2buf, out, stream);
  else if (xs)
    run_all<true, false>(pts, knn_, W_, B_, G_, BE_, scsh, partials, partials2,
                         w2t, x1t, x2buf, out, stream);
  else
    run_all<false, false>(pts, knn_, W_, B_, G_, BE_, scsh, partials, partials2,
                          w2t, x1t, x2buf, out, stream);
}

// Round 11
// 2349.268 us; speedup vs baseline: 3.8298x; 1.0207x over previous
//
#include <hip/hip_runtime.h>
#include <hip/hip_bf16.h>
#include <hip/hip_fp16.h>

#define DEVFN __device__ __forceinline__

typedef _Float16 v2h __attribute__((ext_vector_type(2)));

DEVFN float fdot2(v2h a, v2h b, float c) {
#if __has_builtin(__builtin_amdgcn_fdot2)
  return __builtin_amdgcn_fdot2(a, b, c, false);
#else
  return c + (float)a[0] * (float)b[0] + (float)a[1] * (float)b[1];
#endif
}

// ---------------------------------------------------------------- utilities
struct OpSum { DEVFN float operator()(float a, float b) const { return a + b; } };
struct OpMax { DEVFN float operator()(float a, float b) const { return fmaxf(a, b); } };

template<int CH, int D, typename OP, int NV>
DEVFN void halve(float (&v)[NV], int lane, int& base) {
  if constexpr (D >= 1) {
    OP op;
    if constexpr (CH > 1) {
      constexpr int H = CH / 2;
      #pragma unroll
      for (int i = 0; i < H; ++i) {
        float send = (lane & D) ? v[i] : v[H + i];
        float r = __shfl_xor(send, D);
        float keep = (lane & D) ? v[H + i] : v[i];
        v[i] = op(keep, r);
      }
      if (lane & D) base += H;
      halve<H, (D >> 1), OP, NV>(v, lane, base);
    } else {
      v[0] = op(v[0], __shfl_xor(v[0], D));
      halve<CH, (D >> 1), OP, NV>(v, lane, base);
    }
  }
}

// Sum + sumsq of channels a[OFF..OFF+CC) across all T threads of the block.
template<int CC, int OFF, int NA, int T>
DEVFN void do_stats(const float (&a)[NA], int tid, float* spart, float* prow, int statoff) {
  float v[2 * CC];
  #pragma unroll
  for (int j = 0; j < CC; ++j) { float x = a[OFF + j]; v[2 * j] = x; v[2 * j + 1] = x * x; }
  int lane = tid & 63, base = 0;
  halve<2 * CC, 32, OpSum, 2 * CC>(v, lane, base);
  constexpr int F = (2 * CC) / 64 > 0 ? (2 * CC) / 64 : 1;
  int wv = tid >> 6;
  #pragma unroll
  for (int i = 0; i < F; ++i) spart[wv * 256 + base + i] = v[i];
  __syncthreads();
  constexpr int NW = T / 64;
  if (tid < 2 * CC) {
    float s2 = 0.f;
    #pragma unroll
    for (int w = 0; w < NW; ++w) s2 += spart[w * 256 + tid];
    prow[statoff + tid] = s2;
  }
  __syncthreads();
}

// ---------------------------------------------------------------- FPS (structural floor)
__global__ __launch_bounds__(512) void fps_kernel(const float* __restrict__ pts,
                                                  float4* __restrict__ cent) {
  const int b = blockIdx.x, t = threadIdx.x;
  const int wv = t >> 6;
  __shared__ unsigned long long sk2[2][8];
  __shared__ float4 sc4[2][8];
  __shared__ float4 scent[1024];
  const float* p = pts + (size_t)b * 8192 * 3;
  float px[16], py[16], pz[16], dd[16];
  #pragma unroll
  for (int j = 0; j < 16; ++j) {
    const int i = t + j * 512;
    px[j] = p[i * 3]; py[j] = p[i * 3 + 1]; pz[j] = p[i * 3 + 2];
    dd[j] = 1e10f;
  }
  float cx = p[0], cy = p[1], cz = p[2];
  for (int it = 0; it < 1024; ++it) {
    if (t == 0) scent[it] = make_float4(cx, cy, cz, 0.f);
    const int par = it & 1;
    float bd = -1.f, bx = 0.f, by = 0.f, bz = 0.f; int bi = 0;
    #pragma unroll
    for (int j = 0; j < 16; ++j) {
      const float dx = px[j] - cx, dy = py[j] - cy, dz = pz[j] - cz;
      float d = fminf(dd[j], dx * dx + dy * dy + dz * dz);
      dd[j] = d;
      if (d > bd) { bd = d; bi = t + j * 512; bx = px[j]; by = py[j]; bz = pz[j]; }
    }
    unsigned long long key = ((unsigned long long)__float_as_uint(bd) << 32)
                             | (0xFFFFFFFFu - (unsigned)bi);
    const unsigned long long k0 = key;
    #pragma unroll
    for (int m = 32; m >= 1; m >>= 1) {
      const unsigned long long ok = __shfl_xor(key, m);
      key = ok > key ? ok : key;
    }
    if (key == k0) {
      sk2[par][wv] = key;
      sc4[par][wv] = make_float4(bx, by, bz, 0.f);
    }
    __syncthreads();
    unsigned long long gk = sk2[par][0];
    float4 c4 = sc4[par][0];
    #pragma unroll
    for (int w = 1; w < 8; ++w) {
      const unsigned long long k2 = sk2[par][w];
      const float4 cc = sc4[par][w];
      if (k2 > gk) { gk = k2; c4 = cc; }
    }
    cx = c4.x; cy = c4.y; cz = c4.z;
  }
  __syncthreads();
  #pragma unroll
  for (int i = t; i < 1024; i += 512) cent[(size_t)b * 1024 + i] = scent[i];
}

// ---------------------------------------------------------------- kNN
__global__ __launch_bounds__(256) void knn_kernel(const float* __restrict__ pts,
                                                  const float4* __restrict__ cent,
                                                  int* __restrict__ knn) {
  const int wid = (blockIdx.x * 256 + threadIdx.x) >> 6;
  const int lane = threadIdx.x & 63;
  const int b = wid >> 10;
  const float4 q = cent[wid];
  const float q2 = q.x * q.x + q.y * q.y + q.z * q.z;
  const float* p = pts + (size_t)b * 8192 * 3;
  unsigned long long R = ~0ull;
  for (int c0 = 0; c0 < 8192; c0 += 64) {
    const int i = c0 + lane;
    const float x = p[i * 3], y = p[i * 3 + 1], z = p[i * 3 + 2];
    const float p2 = x * x + y * y + z * z;
    const float dot = q.x * x + q.y * y + q.z * z;
    float d2 = q2 - 2.f * dot + p2;
    d2 = fmaxf(d2, 0.f);
    unsigned u = __float_as_uint(d2);
    u = (u & 0x80000000u) ? ~u : (u | 0x80000000u);
    const unsigned long long key = ((unsigned long long)u << 32) | (unsigned)i;
    const unsigned long long rmax = __shfl(R, 63);
    unsigned long long mask = __ballot(key < rmax);
    while (mask) {
      const int src = __ffsll(mask) - 1;
      mask &= mask - 1;
      const unsigned long long nk = __shfl(key, src);
      const int pos = __popcll(__ballot(R < nk));
      if (pos < 64) {
        const unsigned long long Rm1 = __shfl_up(R, 1);
        R = (lane < pos) ? R : (lane == pos ? nk : Rm1);
      }
    }
  }
  knn[wid * 64 + lane] = (int)(R & 0xffffffffu);
}

// ---------------------------------------------------------------- gather moments (BN0 stats)
__global__ __launch_bounds__(256) void moments_kernel(const float* __restrict__ pts,
                                                      const int* __restrict__ knn_,
                                                      float* __restrict__ mpart) {
  __shared__ float smom[4][27];
  const int tid = threadIdx.x, lane = tid & 63, wv = tid >> 6;
  const int samp = blockIdx.x * 4 + wv;
  const int b = samp >> 10;
  const int pidx = knn_[samp * 64 + lane];
  const float* pp = pts + ((size_t)b * 8192 + pidx) * 3;
  const float x = pp[0], y = pp[1], z = pp[2];
  float g[9] = {x, y, z, x * x, x * y, x * z, y * y, y * z, z * z};
  #pragma unroll
  for (int m = 8; m >= 1; m >>= 1) {
    #pragma unroll
    for (int i = 0; i < 9; ++i) g[i] += __shfl_xor(g[i], m);
  }
  float h[9], tot[9];
  #pragma unroll
  for (int i = 0; i < 9; ++i) h[i] = g[i] + __shfl_xor(g[i], 16);
  #pragma unroll
  for (int i = 0; i < 9; ++i) tot[i] = h[i] + __shfl_xor(h[i], 32);
  if (lane == 0) {
    #pragma unroll
    for (int i = 0; i < 9; ++i) {
      smom[wv][i] = g[i]; smom[wv][9 + i] = h[i]; smom[wv][18 + i] = tot[i];
    }
  }
  __syncthreads();
  if (tid < 27) {
    mpart[blockIdx.x * 32 + tid] =
        smom[0][tid] + smom[1][tid] + smom[2][tid] + smom[3][tid];
  }
}

// ---------------------------------------------------------------- BN0 finalize (all 3 branches)
__global__ __launch_bounds__(256) void finalize0_kernel(const float* __restrict__ mpart,
    const float* __restrict__ w00, const float* __restrict__ b00,
    const float* __restrict__ g00, const float* __restrict__ be00,
    const float* __restrict__ w01, const float* __restrict__ b01,
    const float* __restrict__ g01, const float* __restrict__ be01,
    const float* __restrict__ w02, const float* __restrict__ b02,
    const float* __restrict__ g02, const float* __restrict__ be02,
    float* __restrict__ scsh) {
  __shared__ float fsum[8][32];
  __shared__ float mom[32];
  const int t = threadIdx.x;
  const int col = t & 31, chunk = t >> 5;
  float s = 0.f;
  for (int r = chunk * 256; r < chunk * 256 + 256; ++r) s += mpart[r * 32 + col];
  fsum[chunk][col] = s;
  __syncthreads();
  if (t < 32) {
    float s2 = 0.f;
    #pragma unroll
    for (int c = 0; c < 8; ++c) s2 += fsum[c][t];
    mom[t] = s2;
  }
  __syncthreads();
  int o; const float *w, *bb, *gg, *be; float E; int base, br;
  if (t < 32)       { br = 0; o = t;      w = w00; bb = b00; gg = g00; be = be00; E = 131072.f; base = 0; }
  else if (t < 96)  { br = 1; o = t - 32; w = w01; bb = b01; gg = g01; be = be01; E = 262144.f; base = 9; }
  else if (t < 160) { br = 2; o = t - 96; w = w02; bb = b02; gg = g02; be = be02; E = 524288.f; base = 18; }
  else return;
  const float Sx = mom[base], Sy = mom[base + 1], Sz = mom[base + 2];
  const float mxx = mom[base + 3], mxy = mom[base + 4], mxz = mom[base + 5];
  const float myy = mom[base + 6], myz = mom[base + 7], mzz = mom[base + 8];
  const float W0 = w[o * 3], W1 = w[o * 3 + 1], W2 = w[o * 3 + 2], bo = bb[o];
  const float wS = W0 * Sx + W1 * Sy + W2 * Sz;
  const float qf = W0 * W0 * mxx + 2.f * W0 * W1 * mxy + 2.f * W0 * W2 * mxz
                 + W1 * W1 * myy + 2.f * W1 * W2 * myz + W2 * W2 * mzz;
  const float mean = wS / E + bo;
  const float msq = (qf + 2.f * bo * wS) / E + bo * bo;
  const float var = msq - mean * mean;
  const float inv = 1.0f / sqrtf(var + 1e-5f);
  const float sc = gg[o] * inv;
  scsh[br * 768 + o] = sc;
  scsh[br * 768 + 128 + o] = be[o] - mean * sc;
}

// ---------------------------------------------------------------- pack w1/w2 as half2 pairs
// w1h2[o*(C0/2)+c2] = (w1[o][2c2], w1[o][2c2+1]); regions b1@0, b2@512, b3@2560.
// w2h2[c2*C2+j] = (w2[j][2c2], w2[j][2c2+1]);   regions b1@0, b2@1024, b3@5120.
__global__ __launch_bounds__(256) void pack_kernel(
    const float* __restrict__ w1a, const float* __restrict__ w1b, const float* __restrict__ w1c,
    const float* __restrict__ w2a, const float* __restrict__ w2b, const float* __restrict__ w2c,
    v2h* __restrict__ w1h2, v2h* __restrict__ w2h2) {
  const int i = blockIdx.x * 256 + threadIdx.x;
  if (i < 512) {                                   // b1 w1: C0=32 (C02=16), C1=32
    const int o = i >> 4, c2 = i & 15;
    w1h2[i] = v2h{(_Float16)w1a[o * 32 + 2 * c2], (_Float16)w1a[o * 32 + 2 * c2 + 1]};
  } else if (i < 2560) {                           // b2 w1: C0=64 (C02=32), C1=64
    const int j = i - 512, o = j >> 5, c2 = j & 31;
    w1h2[i] = v2h{(_Float16)w1b[o * 64 + 2 * c2], (_Float16)w1b[o * 64 + 2 * c2 + 1]};
  } else if (i < 5632) {                           // b3 w1: C0=64 (C02=32), C1=96
    const int j = i - 2560, o = j >> 5, c2 = j & 31;
    w1h2[i] = v2h{(_Float16)w1c[o * 64 + 2 * c2], (_Float16)w1c[o * 64 + 2 * c2 + 1]};
  } else if (i < 6656) {                           // b1 w2: C1=32 (C12=16), C2=64
    const int j = i - 5632, c2 = j >> 6, jj = j & 63;
    w2h2[j] = v2h{(_Float16)w2a[jj * 32 + 2 * c2], (_Float16)w2a[jj * 32 + 2 * c2 + 1]};
  } else if (i < 10752) {                          // b2 w2: C1=64 (C12=32), C2=128
    const int j = i - 6656, c2 = j >> 7, jj = j & 127;
    w2h2[1024 + j] = v2h{(_Float16)w2b[jj * 64 + 2 * c2], (_Float16)w2b[jj * 64 + 2 * c2 + 1]};
  } else if (i < 16896) {                          // b3 w2: C1=96 (C12=48), C2=128
    const int j = i - 10752, c2 = j >> 7, jj = j & 127;
    w2h2[5120 + j] = v2h{(_Float16)w2c[jj * 96 + 2 * c2], (_Float16)w2c[jj * 96 + 2 * c2 + 1]};
  }
}

// ---------------------------------------------------------------- stats reduction, stage A
__global__ __launch_bounds__(256) void reduce_rows_kernel(const float* __restrict__ partials,
                                                          int nb, float* __restrict__ out32) {
  const int r0 = blockIdx.x, j = threadIdx.x;
  const int chunk = (nb + 31) / 32;
  const int lo = r0 * chunk;
  const int hi = (lo + chunk < nb) ? lo + chunk : nb;
  float s = 0.f;
  for (int r = lo; r < hi; ++r) s += partials[(size_t)r * 256 + j];
  out32[r0 * 256 + j] = s;
}

// ---------------------------------------------------------------- BN finalize
__global__ __launch_bounds__(256) void finalize_kernel(const float* __restrict__ partials, int nb,
    const float* __restrict__ g, const float* __restrict__ be, float n,
    float* __restrict__ sc, float* __restrict__ sh, int CO) {
  __shared__ float tot[256];
  const int j = threadIdx.x;
  if (j < 2 * CO) {
    float s = 0.f;
    for (int r = 0; r < nb; ++r) s += partials[(size_t)r * 256 + j];
    tot[j] = s;
  }
  __syncthreads();
  if (j < CO) {
    const float m = tot[2 * j] / n;
    const float v = tot[2 * j + 1] / n - m * m;
    const float inv = 1.0f / sqrtf(v + 1e-5f);
    const float scv = g[j] * inv;
    sc[j] = scv;
    sh[j] = be[j] - m * scv;
  }
}

// ---------------------------------------------------------------- fused MLP pass (dot2)
// L=1: gather + L0 + BN0 + L1 (fdot2); store pre-BN x1 (fp16, XS1) + stats.
// L=2: XS1: read x1t, BN1+relu -> arowv; else recompute. L2 via fdot2 + stats (+x2 store).
// L=3 (fallback, !XS): full forward + BN2 + relu + max-over-K + store.
template<int K_, int C0, int C1, int C2, int L, int BOFF, int T, bool XS, bool XS1>
__global__ __launch_bounds__(T) void pass_kernel(
    const float* __restrict__ pts, const int* __restrict__ knnidx,
    const float* __restrict__ w0, const float* __restrict__ b0,
    const v2h* __restrict__ w1p, const float* __restrict__ b1,
    const v2h* __restrict__ w2p, const float* __restrict__ b2,
    const float* __restrict__ scsh, float* __restrict__ partials,
    __half* __restrict__ x1t, __half* __restrict__ x2buf, float* __restrict__ out) {
  constexpr int C02 = C0 / 2;
  constexpr int C12 = C1 / 2;
  constexpr int RSv = C12 + 1;                       // odd dword stride -> conflict-free
  constexpr int NAROW = (L >= 2) ? T * RSv : 1;
  constexpr size_t NE = (size_t)8 * 1024 * K_;
  __shared__ v2h arowv[NAROW];
  __shared__ float spart[(T / 64) * 256];
  const int tid = threadIdx.x;
  const int lane = tid & 63;
  const int e = blockIdx.x * T + tid;
  const int b = e / (1024 * K_);
  const int rem = e - b * (1024 * K_);
  const int s = rem / K_;
  float* prow = partials + (size_t)blockIdx.x * 256;

  v2h a0p[C02];
  if constexpr (!(XS1 && L == 2)) {
    // gather + layer 0 (3 -> C0) + BN0 + relu, packed to half2
    const int pidx = knnidx[(b * 1024 + s) * 64 + (rem - s * K_)];
    const float* pp = pts + ((size_t)b * 8192 + pidx) * 3;
    const float zx = pp[0], zy = pp[1], zz = pp[2];
    const float* sc0 = scsh + 0;
    const float* sh0 = scsh + 128;
    #pragma unroll
    for (int c2 = 0; c2 < C02; ++c2) {
      float va = b0[2 * c2]     + zx * w0[6 * c2]     + zy * w0[6 * c2 + 1] + zz * w0[6 * c2 + 2];
      float vb = b0[2 * c2 + 1] + zx * w0[6 * c2 + 3] + zy * w0[6 * c2 + 4] + zz * w0[6 * c2 + 5];
      va = fmaxf(0.f, va * sc0[2 * c2] + sh0[2 * c2]);
      vb = fmaxf(0.f, vb * sc0[2 * c2 + 1] + sh0[2 * c2 + 1]);
      a0p[c2] = v2h{(_Float16)va, (_Float16)vb};
    }
  }

  // layer 1 (C0 -> C1)
  if constexpr (L == 1) {
    float* swl = spart + (tid >> 6) * 256;
    for (int o = 0; o < C1; ++o) {
      float s0 = 0.f, s1 = 0.f;
      #pragma unroll
      for (int c2 = 0; c2 < C02; c2 += 2) {
        s0 = fdot2(a0p[c2],     w1p[o * C02 + c2],     s0);
        s1 = fdot2(a0p[c2 + 1], w1p[o * C02 + c2 + 1], s1);
      }
      const float x = b1[o] + (s0 + s1);
      if constexpr (XS1) x1t[(size_t)o * NE + e] = __float2half(x);
      float sm = x, sq = x * x;
      #pragma unroll
      for (int m = 32; m >= 1; m >>= 1) { sm += __shfl_xor(sm, m); sq += __shfl_xor(sq, m); }
      if (lane == 0) { swl[2 * o] = sm; swl[2 * o + 1] = sq; }
    }
    __syncthreads();
    for (int col = tid; col < 2 * C1; col += T) {   // 2*C1 can exceed T
      float s2_ = 0.f;
      #pragma unroll
      for (int w = 0; w < T / 64; ++w) s2_ += spart[w * 256 + col];
      prow[col] = s2_;
    }
    return;
  }

  // L >= 2: act1 -> LDS (half2)
  {
    const float* sc1 = scsh + 256;
    const float* sh1 = scsh + 384;
    if constexpr (XS1 && L == 2) {
      for (int o2 = 0; o2 < C12; ++o2) {
        float xa = __half2float(x1t[(size_t)(2 * o2) * NE + e]);
        float xb = __half2float(x1t[(size_t)(2 * o2 + 1) * NE + e]);
        xa = fmaxf(0.f, xa * sc1[2 * o2] + sh1[2 * o2]);
        xb = fmaxf(0.f, xb * sc1[2 * o2 + 1] + sh1[2 * o2 + 1]);
        arowv[tid * RSv + o2] = v2h{(_Float16)xa, (_Float16)xb};
      }
    } else {
      for (int o2 = 0; o2 < C12; ++o2) {
        float xv[2];
        #pragma unroll
        for (int tt = 0; tt < 2; ++tt) {
          const int o = 2 * o2 + tt;
          float s0 = 0.f, s1 = 0.f;
          #pragma unroll
          for (int c2 = 0; c2 < C02; c2 += 2) {
            s0 = fdot2(a0p[c2],     w1p[o * C02 + c2],     s0);
            s1 = fdot2(a0p[c2 + 1], w1p[o * C02 + c2 + 1], s1);
          }
          const float x = b1[o] + (s0 + s1);
          xv[tt] = fmaxf(0.f, x * sc1[o] + sh1[o]);
        }
        arowv[tid * RSv + o2] = v2h{(_Float16)xv[0], (_Float16)xv[1]};
      }
    }
  }

  // layer 2 (C1 -> C2), output chunks of 32, fdot2 over c-pairs
  const float* sc2 = scsh + 512;
  const float* sh2 = scsh + 640;
  const size_t orow = (size_t)(b * 1024 + s) * 320 + BOFF;
  __half2* x2p = (__half2*)(x2buf + (size_t)e * C2);
  #pragma unroll
  for (int CB = 0; CB < C2; CB += 32) {
    float acc[32];
    #pragma unroll
    for (int j = 0; j < 32; ++j) acc[j] = b2[CB + j];
    for (int c2 = 0; c2 < C12; ++c2) {
      const v2h az = arowv[tid * RSv + c2];
      const v2h* wrow = w2p + c2 * C2 + CB;
      #pragma unroll
      for (int j = 0; j < 32; ++j) acc[j] = fdot2(az, wrow[j], acc[j]);
    }
    if constexpr (L == 2) {
      if constexpr (XS) {
        #pragma unroll
        for (int j = 0; j < 16; ++j)
          x2p[CB / 2 + j] = __floats2half2_rn(acc[2 * j], acc[2 * j + 1]);
      }
      do_stats<32, 0, 32, T>(acc, tid, spart, prow, 2 * CB);
    } else {
      #pragma unroll
      for (int j = 0; j < 32; ++j) acc[j] = fmaxf(0.f, acc[j] * sc2[CB + j] + sh2[CB + j]);
      int base = 0;
      halve<32, (K_ >> 1), OpMax, 32>(acc, lane, base);
      constexpr int F = (32 / K_ > 0) ? (32 / K_) : 1;
      #pragma unroll
      for (int i = 0; i < F; ++i) out[orow + CB + base + i] = acc[i];
    }
  }
}

// ---------------------------------------------------------------- BN+relu+maxpool from stored x2
template<int K_, int C2, int BOFF>
__global__ __launch_bounds__(256) void pool_kernel(const __half2* __restrict__ x2h,
                                                   const float* __restrict__ scsh,
                                                   float* __restrict__ out) {
  constexpr int CP = C2 / 2;
  const int g = blockIdx.x * 256 + threadIdx.x;
  const int cp = g % CP;
  const int sample = g / CP;
  const float sca = scsh[512 + 2 * cp], scb = scsh[512 + 2 * cp + 1];
  const float sha = scsh[640 + 2 * cp], shb = scsh[640 + 2 * cp + 1];
  float m0 = 0.f, m1 = 0.f;
  const size_t base = (size_t)sample * K_ * CP + cp;
  #pragma unroll 4
  for (int k = 0; k < K_; ++k) {
    const float2 f = __half22float2(x2h[base + (size_t)k * CP]);
    m0 = fmaxf(m0, fmaxf(0.f, f.x * sca + sha));
    m1 = fmaxf(m1, fmaxf(0.f, f.y * scb + shb));
  }
  float2 r; r.x = m0; r.y = m1;
  *(float2*)&out[(size_t)sample * 320 + BOFF + 2 * cp] = r;
}

// ---------------------------------------------------------------- host side
template<int K_, int C0, int C1, int C2, int BOFF, bool XS, bool XS1>
static void run_branch(const float* pts, const int* knn_,
                       const float* const* W_, const float* const* B_,
                       const float* const* G_, const float* const* BE_,
                       float* scshb, float* partials, float* partials2,
                       const v2h* w1pb, const v2h* w2pb,
                       __half* x1t, __half* x2buf, float* out, hipStream_t stream) {
  constexpr int T = 128;
  constexpr int NE = 8 * 1024 * K_;
  constexpr int NB = NE / T;
  pass_kernel<K_, C0, C1, C2, 1, BOFF, T, XS, XS1><<<NB, T, 0, stream>>>(
      pts, knn_, W_[0], B_[0], w1pb, B_[1], w2pb, B_[2], scshb, partials, x1t, x2buf, out);
  reduce_rows_kernel<<<32, 256, 0, stream>>>(partials, NB, partials2);
  finalize_kernel<<<1, 256, 0, stream>>>(partials2, 32, G_[1], BE_[1], (float)NE,
                                         scshb + 256, scshb + 384, C1);
  pass_kernel<K_, C0, C1, C2, 2, BOFF, T, XS, XS1><<<NB, T, 0, stream>>>(
      pts, knn_, W_[0], B_[0], w1pb, B_[1], w2pb, B_[2], scshb, partials, x1t, x2buf, out);
  reduce_rows_kernel<<<32, 256, 0, stream>>>(partials, NB, partials2);
  finalize_kernel<<<1, 256, 0, stream>>>(partials2, 32, G_[2], BE_[2], (float)NE,
                                         scshb + 512, scshb + 640, C2);
  if constexpr (XS) {
    constexpr int NP = 8 * 1024 * (C2 / 2);
    pool_kernel<K_, C2, BOFF><<<NP / 256, 256, 0, stream>>>(
        (const __half2*)x2buf, scshb, out);
  } else {
    pass_kernel<K_, C0, C1, C2, 3, BOFF, T, XS, XS1><<<NB, T, 0, stream>>>(
        pts, knn_, W_[0], B_[0], w1pb, B_[1], w2pb, B_[2], scshb, partials, x1t, x2buf, out);
  }
}

template<bool XS, bool XS1>
static void run_all(const float* pts, const int* knn_,
                    const float* const* W_, const float* const* B_,
                    const float* const* G_, const float* const* BE_,
                    float* scsh, float* partials, float* partials2,
                    const v2h* w1h2, const v2h* w2h2,
                    __half* x1t, __half* x2buf, float* out, hipStream_t stream) {
  run_branch<16, 32, 32, 64, 0, XS, XS1>(pts, knn_, W_ + 0, B_ + 0, G_ + 0, BE_ + 0,
      scsh, partials, partials2, w1h2, w2h2, x1t, x2buf, out, stream);
  run_branch<32, 64, 64, 128, 64, XS, XS1>(pts, knn_, W_ + 3, B_ + 3, G_ + 3, BE_ + 3,
      scsh + 768, partials, partials2, w1h2 + 512, w2h2 + 1024, x1t, x2buf, out, stream);
  run_branch<64, 64, 96, 128, 192, XS, XS1>(pts, knn_, W_ + 6, B_ + 6, G_ + 6, BE_ + 6,
      scsh + 1536, partials, partials2, w1h2 + 2560, w2h2 + 5120, x1t, x2buf, out, stream);
}

extern "C" void kernel_launch(void* const* d_in, const int* in_sizes, int n_in,
                              void* d_out, int out_size, void* d_ws, size_t ws_size,
                              hipStream_t stream) {
  (void)in_sizes; (void)n_in; (void)out_size;
  const float* pts = (const float*)d_in[0];
  const float* W_[9]; const float* B_[9]; const float* G_[9]; const float* BE_[9];
  for (int m = 0; m < 9; ++m) {
    W_[m]  = (const float*)d_in[1 + m * 4 + 0];
    B_[m]  = (const float*)d_in[1 + m * 4 + 1];
    G_[m]  = (const float*)d_in[1 + m * 4 + 2];
    BE_[m] = (const float*)d_in[1 + m * 4 + 3];
  }
  char* ws = (char*)d_ws;
  float4* cent      = (float4*)ws;                          // @0,        131072 B
  int*    knn_      = (int*)(ws + 131072);                  // 2 MB
  float*  partials  = (float*)(ws + 2228224);               // 4 MB (also mpart)
  float*  scsh      = (float*)(ws + 6422528);               // 12 KB
  v2h*    w1h2      = (v2h*)(ws + 6434816);                 // 22528 B (5632 v2h)
  v2h*    w2h2      = (v2h*)(ws + 6457344);                 // 45056 B (11264 v2h)
  float*  partials2 = (float*)(ws + 6502400);               // 32 KB
  __half* x2buf     = (__half*)(ws + 6535168);              // 134217728 B max
  __half* x1t       = (__half*)(ws + 6535168 + 134217728ull); // 100663296 B max
  float*  out       = (float*)d_out;
  const bool xs  = ws_size >= 6535168ull + 134217728ull;
  const bool xs1 = ws_size >= 6535168ull + 134217728ull + 100663296ull;

  fps_kernel<<<8, 512, 0, stream>>>(pts, cent);
  knn_kernel<<<2048, 256, 0, stream>>>(pts, cent, knn_);
  moments_kernel<<<2048, 256, 0, stream>>>(pts, knn_, partials);
  finalize0_kernel<<<1, 256, 0, stream>>>(partials,
      W_[0], B_[0], G_[0], BE_[0], W_[3], B_[3], G_[3], BE_[3],
      W_[6], B_[6], G_[6], BE_[6], scsh);
  pack_kernel<<<66, 256, 0, stream>>>(W_[1], W_[4], W_[7], W_[2], W_[5], W_[8], w1h2, w2h2);

  if (xs && xs1)
    run_all<true, true>(pts, knn_, W_, B_, G_, BE_, scsh, partials, partials2,
                        w1h2, w2h2, x1t, x2buf, out, stream);
  else if (xs)
    run_all<true, false>(pts, knn_, W_, B_, G_, BE_, scsh, partials, partials2,
                         w1h2, w2h2, x1t, x2buf, out, stream);
  else
    run_all<false, false>(pts, knn_, W_, B_, G_, BE_, scsh, partials, partials2,
                          w1h2, w2h2, x1t, x2buf, out, stream);
}

// Round 12
// 2217.175 us; speedup vs baseline: 4.0579x; 1.0596x over previous
//
#include <hip/hip_runtime.h>
#include <hip/hip_fp16.h>

#define DEVFN __device__ __forceinline__

typedef _Float16 v2h __attribute__((ext_vector_type(2)));

DEVFN float fdot2(v2h a, v2h b, float c) {
#if __has_builtin(__builtin_amdgcn_fdot2)
  return __builtin_amdgcn_fdot2(a, b, c, false);
#else
  return c + (float)a[0] * (float)b[0] + (float)a[1] * (float)b[1];
#endif
}

// ---------------------------------------------------------------- utilities
struct OpSum { DEVFN float operator()(float a, float b) const { return a + b; } };
struct OpMax { DEVFN float operator()(float a, float b) const { return fmaxf(a, b); } };
struct OpMin { DEVFN float operator()(float a, float b) const { return fminf(a, b); } };

template<int CH, int D, typename OP, int NV>
DEVFN void halve(float (&v)[NV], int lane, int& base) {
  if constexpr (D >= 1) {
    OP op;
    if constexpr (CH > 1) {
      constexpr int H = CH / 2;
      #pragma unroll
      for (int i = 0; i < H; ++i) {
        float send = (lane & D) ? v[i] : v[H + i];
        float r = __shfl_xor(send, D);
        float keep = (lane & D) ? v[H + i] : v[i];
        v[i] = op(keep, r);
      }
      if (lane & D) base += H;
      halve<H, (D >> 1), OP, NV>(v, lane, base);
    } else {
      v[0] = op(v[0], __shfl_xor(v[0], D));
      halve<CH, (D >> 1), OP, NV>(v, lane, base);
    }
  }
}

// Sum + sumsq of channels a[OFF..OFF+CC) across all T threads of the block.
template<int CC, int OFF, int NA, int T>
DEVFN void do_stats(const float (&a)[NA], int tid, float* spart, float* prow, int statoff) {
  float v[2 * CC];
  #pragma unroll
  for (int j = 0; j < CC; ++j) { float x = a[OFF + j]; v[2 * j] = x; v[2 * j + 1] = x * x; }
  int lane = tid & 63, base = 0;
  halve<2 * CC, 32, OpSum, 2 * CC>(v, lane, base);
  constexpr int F = (2 * CC) / 64 > 0 ? (2 * CC) / 64 : 1;
  int wv = tid >> 6;
  #pragma unroll
  for (int i = 0; i < F; ++i) spart[wv * 256 + base + i] = v[i];
  __syncthreads();
  constexpr int NW = T / 64;
  if (tid < 2 * CC) {
    float s2 = 0.f;
    #pragma unroll
    for (int w = 0; w < NW; ++w) s2 += spart[w * 256 + tid];
    prow[statoff + tid] = s2;
  }
  __syncthreads();
}

// ---------------------------------------------------------------- FPS (structural floor)
__global__ __launch_bounds__(512) void fps_kernel(const float* __restrict__ pts,
                                                  float4* __restrict__ cent) {
  const int b = blockIdx.x, t = threadIdx.x;
  const int wv = t >> 6;
  __shared__ unsigned long long sk2[2][8];
  __shared__ float4 sc4[2][8];
  __shared__ float4 scent[1024];
  const float* p = pts + (size_t)b * 8192 * 3;
  float px[16], py[16], pz[16], dd[16];
  #pragma unroll
  for (int j = 0; j < 16; ++j) {
    const int i = t + j * 512;
    px[j] = p[i * 3]; py[j] = p[i * 3 + 1]; pz[j] = p[i * 3 + 2];
    dd[j] = 1e10f;
  }
  float cx = p[0], cy = p[1], cz = p[2];
  for (int it = 0; it < 1024; ++it) {
    if (t == 0) scent[it] = make_float4(cx, cy, cz, 0.f);
    const int par = it & 1;
    float bd = -1.f, bx = 0.f, by = 0.f, bz = 0.f; int bi = 0;
    #pragma unroll
    for (int j = 0; j < 16; ++j) {
      const float dx = px[j] - cx, dy = py[j] - cy, dz = pz[j] - cz;
      float d = fminf(dd[j], dx * dx + dy * dy + dz * dz);
      dd[j] = d;
      if (d > bd) { bd = d; bi = t + j * 512; bx = px[j]; by = py[j]; bz = pz[j]; }
    }
    unsigned long long key = ((unsigned long long)__float_as_uint(bd) << 32)
                             | (0xFFFFFFFFu - (unsigned)bi);
    const unsigned long long k0 = key;
    #pragma unroll
    for (int m = 32; m >= 1; m >>= 1) {
      const unsigned long long ok = __shfl_xor(key, m);
      key = ok > key ? ok : key;
    }
    if (key == k0) {
      sk2[par][wv] = key;
      sc4[par][wv] = make_float4(bx, by, bz, 0.f);
    }
    __syncthreads();
    unsigned long long gk = sk2[par][0];
    float4 c4 = sc4[par][0];
    #pragma unroll
    for (int w = 1; w < 8; ++w) {
      const unsigned long long k2 = sk2[par][w];
      const float4 cc = sc4[par][w];
      if (k2 > gk) { gk = k2; c4 = cc; }
    }
    cx = c4.x; cy = c4.y; cz = c4.z;
  }
  __syncthreads();
  #pragma unroll
  for (int i = t; i < 1024; i += 512) cent[(size_t)b * 1024 + i] = scent[i];
}

// ---------------------------------------------------------------- kNN
__global__ __launch_bounds__(256) void knn_kernel(const float* __restrict__ pts,
                                                  const float4* __restrict__ cent,
                                                  int* __restrict__ knn) {
  const int wid = (blockIdx.x * 256 + threadIdx.x) >> 6;
  const int lane = threadIdx.x & 63;
  const int b = wid >> 10;
  const float4 q = cent[wid];
  const float q2 = q.x * q.x + q.y * q.y + q.z * q.z;
  const float* p = pts + (size_t)b * 8192 * 3;
  unsigned long long R = ~0ull;
  for (int c0 = 0; c0 < 8192; c0 += 64) {
    const int i = c0 + lane;
    const float x = p[i * 3], y = p[i * 3 + 1], z = p[i * 3 + 2];
    const float p2 = x * x + y * y + z * z;
    const float dot = q.x * x + q.y * y + q.z * z;
    float d2 = q2 - 2.f * dot + p2;
    d2 = fmaxf(d2, 0.f);
    unsigned u = __float_as_uint(d2);
    u = (u & 0x80000000u) ? ~u : (u | 0x80000000u);
    const unsigned long long key = ((unsigned long long)u << 32) | (unsigned)i;
    const unsigned long long rmax = __shfl(R, 63);
    unsigned long long mask = __ballot(key < rmax);
    while (mask) {
      const int src = __ffsll(mask) - 1;
      mask &= mask - 1;
      const unsigned long long nk = __shfl(key, src);
      const int pos = __popcll(__ballot(R < nk));
      if (pos < 64) {
        const unsigned long long Rm1 = __shfl_up(R, 1);
        R = (lane < pos) ? R : (lane == pos ? nk : Rm1);
      }
    }
  }
  knn[wid * 64 + lane] = (int)(R & 0xffffffffu);
}

// ---------------------------------------------------------------- gather moments (BN0 stats)
__global__ __launch_bounds__(256) void moments_kernel(const float* __restrict__ pts,
                                                      const int* __restrict__ knn_,
                                                      float* __restrict__ mpart) {
  __shared__ float smom[4][27];
  const int tid = threadIdx.x, lane = tid & 63, wv = tid >> 6;
  const int samp = blockIdx.x * 4 + wv;
  const int b = samp >> 10;
  const int pidx = knn_[samp * 64 + lane];
  const float* pp = pts + ((size_t)b * 8192 + pidx) * 3;
  const float x = pp[0], y = pp[1], z = pp[2];
  float g[9] = {x, y, z, x * x, x * y, x * z, y * y, y * z, z * z};
  #pragma unroll
  for (int m = 8; m >= 1; m >>= 1) {
    #pragma unroll
    for (int i = 0; i < 9; ++i) g[i] += __shfl_xor(g[i], m);
  }
  float h[9], tot[9];
  #pragma unroll
  for (int i = 0; i < 9; ++i) h[i] = g[i] + __shfl_xor(g[i], 16);
  #pragma unroll
  for (int i = 0; i < 9; ++i) tot[i] = h[i] + __shfl_xor(h[i], 32);
  if (lane == 0) {
    #pragma unroll
    for (int i = 0; i < 9; ++i) {
      smom[wv][i] = g[i]; smom[wv][9 + i] = h[i]; smom[wv][18 + i] = tot[i];
    }
  }
  __syncthreads();
  if (tid < 27) {
    mpart[blockIdx.x * 32 + tid] =
        smom[0][tid] + smom[1][tid] + smom[2][tid] + smom[3][tid];
  }
}

// ---------------------------------------------------------------- BN0 finalize (all 3 branches)
__global__ __launch_bounds__(256) void finalize0_kernel(const float* __restrict__ mpart,
    const float* __restrict__ w00, const float* __restrict__ b00,
    const float* __restrict__ g00, const float* __restrict__ be00,
    const float* __restrict__ w01, const float* __restrict__ b01,
    const float* __restrict__ g01, const float* __restrict__ be01,
    const float* __restrict__ w02, const float* __restrict__ b02,
    const float* __restrict__ g02, const float* __restrict__ be02,
    float* __restrict__ scsh) {
  __shared__ float fsum[8][32];
  __shared__ float mom[32];
  const int t = threadIdx.x;
  const int col = t & 31, chunk = t >> 5;
  float s = 0.f;
  for (int r = chunk * 256; r < chunk * 256 + 256; ++r) s += mpart[r * 32 + col];
  fsum[chunk][col] = s;
  __syncthreads();
  if (t < 32) {
    float s2 = 0.f;
    #pragma unroll
    for (int c = 0; c < 8; ++c) s2 += fsum[c][t];
    mom[t] = s2;
  }
  __syncthreads();
  int o; const float *w, *bb, *gg, *be; float E; int base, br;
  if (t < 32)       { br = 0; o = t;      w = w00; bb = b00; gg = g00; be = be00; E = 131072.f; base = 0; }
  else if (t < 96)  { br = 1; o = t - 32; w = w01; bb = b01; gg = g01; be = be01; E = 262144.f; base = 9; }
  else if (t < 160) { br = 2; o = t - 96; w = w02; bb = b02; gg = g02; be = be02; E = 524288.f; base = 18; }
  else return;
  const float Sx = mom[base], Sy = mom[base + 1], Sz = mom[base + 2];
  const float mxx = mom[base + 3], mxy = mom[base + 4], mxz = mom[base + 5];
  const float myy = mom[base + 6], myz = mom[base + 7], mzz = mom[base + 8];
  const float W0 = w[o * 3], W1 = w[o * 3 + 1], W2 = w[o * 3 + 2], bo = bb[o];
  const float wS = W0 * Sx + W1 * Sy + W2 * Sz;
  const float qf = W0 * W0 * mxx + 2.f * W0 * W1 * mxy + 2.f * W0 * W2 * mxz
                 + W1 * W1 * myy + 2.f * W1 * W2 * myz + W2 * W2 * mzz;
  const float mean = wS / E + bo;
  const float msq = (qf + 2.f * bo * wS) / E + bo * bo;
  const float var = msq - mean * mean;
  const float inv = 1.0f / sqrtf(var + 1e-5f);
  const float sc = gg[o] * inv;
  scsh[br * 768 + o] = sc;
  scsh[br * 768 + 128 + o] = be[o] - mean * sc;
}

// ---------------------------------------------------------------- pack w1/w2 as half2 pairs
__global__ __launch_bounds__(256) void pack_kernel(
    const float* __restrict__ w1a, const float* __restrict__ w1b, const float* __restrict__ w1c,
    const float* __restrict__ w2a, const float* __restrict__ w2b, const float* __restrict__ w2c,
    v2h* __restrict__ w1h2, v2h* __restrict__ w2h2) {
  const int i = blockIdx.x * 256 + threadIdx.x;
  if (i < 512) {                                   // b1 w1: C0=32, C1=32
    const int o = i >> 4, c2 = i & 15;
    w1h2[i] = v2h{(_Float16)w1a[o * 32 + 2 * c2], (_Float16)w1a[o * 32 + 2 * c2 + 1]};
  } else if (i < 2560) {                           // b2 w1: C0=64, C1=64
    const int j = i - 512, o = j >> 5, c2 = j & 31;
    w1h2[i] = v2h{(_Float16)w1b[o * 64 + 2 * c2], (_Float16)w1b[o * 64 + 2 * c2 + 1]};
  } else if (i < 5632) {                           // b3 w1: C0=64, C1=96
    const int j = i - 2560, o = j >> 5, c2 = j & 31;
    w1h2[i] = v2h{(_Float16)w1c[o * 64 + 2 * c2], (_Float16)w1c[o * 64 + 2 * c2 + 1]};
  } else if (i < 6656) {                           // b1 w2: C1=32, C2=64
    const int j = i - 5632, c2 = j >> 6, jj = j & 63;
    w2h2[j] = v2h{(_Float16)w2a[jj * 32 + 2 * c2], (_Float16)w2a[jj * 32 + 2 * c2 + 1]};
  } else if (i < 10752) {                          // b2 w2: C1=64, C2=128
    const int j = i - 6656, c2 = j >> 7, jj = j & 127;
    w2h2[1024 + j] = v2h{(_Float16)w2b[jj * 64 + 2 * c2], (_Float16)w2b[jj * 64 + 2 * c2 + 1]};
  } else if (i < 16896) {                          // b3 w2: C1=96, C2=128
    const int j = i - 10752, c2 = j >> 7, jj = j & 127;
    w2h2[5120 + j] = v2h{(_Float16)w2c[jj * 96 + 2 * c2], (_Float16)w2c[jj * 96 + 2 * c2 + 1]};
  }
}

// ---------------------------------------------------------------- stats reduction, stage A
__global__ __launch_bounds__(256) void reduce_rows_kernel(const float* __restrict__ partials,
                                                          int nb, float* __restrict__ out32) {
  const int r0 = blockIdx.x, j = threadIdx.x;
  const int chunk = (nb + 31) / 32;
  const int lo = r0 * chunk;
  const int hi = (lo + chunk < nb) ? lo + chunk : nb;
  float s = 0.f;
  for (int r = lo; r < hi; ++r) s += partials[(size_t)r * 256 + j];
  out32[r0 * 256 + j] = s;
}

// ---------------------------------------------------------------- BN finalize
__global__ __launch_bounds__(256) void finalize_kernel(const float* __restrict__ partials, int nb,
    const float* __restrict__ g, const float* __restrict__ be, float n,
    float* __restrict__ sc, float* __restrict__ sh, int CO) {
  __shared__ float tot[256];
  const int j = threadIdx.x;
  if (j < 2 * CO) {
    float s = 0.f;
    for (int r = 0; r < nb; ++r) s += partials[(size_t)r * 256 + j];
    tot[j] = s;
  }
  __syncthreads();
  if (j < CO) {
    const float m = tot[2 * j] / n;
    const float v = tot[2 * j + 1] / n - m * m;
    const float inv = 1.0f / sqrtf(v + 1e-5f);
    const float scv = g[j] * inv;
    sc[j] = scv;
    sh[j] = be[j] - m * scv;
  }
}

// ---------------------------------------------------------------- fused MLP pass (dot2)
// L=1: gather + L0 + BN0 + L1 (fdot2); chunked do_stats; x1 store (fp16, XS1).
// L=2: XS1: read x1t, BN1+relu -> arowv; else recompute. L2 + stats + pre-BN
//      max/min pool over K -> pmax/pmin (exact fp32).
template<int K_, int C0, int C1, int C2, int L, int T, bool XS1>
__global__ __launch_bounds__(T) void pass_kernel(
    const float* __restrict__ pts, const int* __restrict__ knnidx,
    const float* __restrict__ w0, const float* __restrict__ b0,
    const v2h* __restrict__ w1p, const float* __restrict__ b1,
    const v2h* __restrict__ w2p, const float* __restrict__ b2,
    const float* __restrict__ scsh, float* __restrict__ partials,
    __half* __restrict__ x1t, float* __restrict__ pmax, float* __restrict__ pmin) {
  constexpr int C02 = C0 / 2;
  constexpr int C12 = C1 / 2;
  constexpr int RSv = C12 + 1;                       // odd dword stride -> conflict-free
  constexpr int NAROW = (L >= 2) ? T * RSv : 1;
  constexpr size_t NE = (size_t)8 * 1024 * K_;
  __shared__ v2h arowv[NAROW];
  __shared__ float spart[(T / 64) * 256];
  const int tid = threadIdx.x;
  const int lane = tid & 63;
  const int e = blockIdx.x * T + tid;
  const int b = e / (1024 * K_);
  const int rem = e - b * (1024 * K_);
  const int s = rem / K_;
  float* prow = partials + (size_t)blockIdx.x * 256;

  v2h a0p[C02];
  if constexpr (!(XS1 && L == 2)) {
    const int pidx = knnidx[(b * 1024 + s) * 64 + (rem - s * K_)];
    const float* pp = pts + ((size_t)b * 8192 + pidx) * 3;
    const float zx = pp[0], zy = pp[1], zz = pp[2];
    const float* sc0 = scsh + 0;
    const float* sh0 = scsh + 128;
    #pragma unroll
    for (int c2 = 0; c2 < C02; ++c2) {
      float va = b0[2 * c2]     + zx * w0[6 * c2]     + zy * w0[6 * c2 + 1] + zz * w0[6 * c2 + 2];
      float vb = b0[2 * c2 + 1] + zx * w0[6 * c2 + 3] + zy * w0[6 * c2 + 4] + zz * w0[6 * c2 + 5];
      va = fmaxf(0.f, va * sc0[2 * c2] + sh0[2 * c2]);
      vb = fmaxf(0.f, vb * sc0[2 * c2 + 1] + sh0[2 * c2 + 1]);
      a0p[c2] = v2h{(_Float16)va, (_Float16)vb};
    }
  }

  // layer 1 (C0 -> C1), chunked stats
  if constexpr (L == 1) {
    #pragma unroll
    for (int CB = 0; CB < C1; CB += 32) {
      float arr[32];
      #pragma unroll
      for (int oo = 0; oo < 32; ++oo) {
        const int o = CB + oo;
        float s0 = 0.f, s1 = 0.f;
        #pragma unroll
        for (int c2 = 0; c2 < C02; c2 += 2) {
          s0 = fdot2(a0p[c2],     w1p[o * C02 + c2],     s0);
          s1 = fdot2(a0p[c2 + 1], w1p[o * C02 + c2 + 1], s1);
        }
        const float x = b1[o] + (s0 + s1);
        if constexpr (XS1) x1t[(size_t)o * NE + e] = __float2half(x);
        arr[oo] = x;
      }
      do_stats<32, 0, 32, T>(arr, tid, spart, prow, 2 * CB);
    }
    return;
  }

  // L == 2: act1 -> LDS (half2)
  {
    const float* sc1 = scsh + 256;
    const float* sh1 = scsh + 384;
    if constexpr (XS1) {
      for (int o2 = 0; o2 < C12; ++o2) {
        float xa = __half2float(x1t[(size_t)(2 * o2) * NE + e]);
        float xb = __half2float(x1t[(size_t)(2 * o2 + 1) * NE + e]);
        xa = fmaxf(0.f, xa * sc1[2 * o2] + sh1[2 * o2]);
        xb = fmaxf(0.f, xb * sc1[2 * o2 + 1] + sh1[2 * o2 + 1]);
        arowv[tid * RSv + o2] = v2h{(_Float16)xa, (_Float16)xb};
      }
    } else {
      for (int o2 = 0; o2 < C12; ++o2) {
        float xv[2];
        #pragma unroll
        for (int tt = 0; tt < 2; ++tt) {
          const int o = 2 * o2 + tt;
          float s0 = 0.f, s1 = 0.f;
          #pragma unroll
          for (int c2 = 0; c2 < C02; c2 += 2) {
            s0 = fdot2(a0p[c2],     w1p[o * C02 + c2],     s0);
            s1 = fdot2(a0p[c2 + 1], w1p[o * C02 + c2 + 1], s1);
          }
          const float x = b1[o] + (s0 + s1);
          xv[tt] = fmaxf(0.f, x * sc1[o] + sh1[o]);
        }
        arowv[tid * RSv + o2] = v2h{(_Float16)xv[0], (_Float16)xv[1]};
      }
    }
  }

  // layer 2 (C1 -> C2): stats + pre-BN max/min pool over K
  const size_t srow = (size_t)(b * 1024 + s) * C2;
  #pragma unroll
  for (int CB = 0; CB < C2; CB += 32) {
    float acc[32];
    #pragma unroll
    for (int j = 0; j < 32; ++j) acc[j] = b2[CB + j];
    for (int c2 = 0; c2 < C12; ++c2) {
      const v2h az = arowv[tid * RSv + c2];
      const v2h* wrow = w2p + c2 * C2 + CB;
      #pragma unroll
      for (int j = 0; j < 32; ++j) acc[j] = fdot2(az, wrow[j], acc[j]);
    }
    do_stats<32, 0, 32, T>(acc, tid, spart, prow, 2 * CB);
    float tmn[32];
    #pragma unroll
    for (int j = 0; j < 32; ++j) tmn[j] = acc[j];
    int base = 0;
    halve<32, (K_ >> 1), OpMax, 32>(acc, lane, base);
    int base2 = 0;
    halve<32, (K_ >> 1), OpMin, 32>(tmn, lane, base2);
    constexpr int F = (32 / K_ > 0) ? (32 / K_) : 1;  // K=64: lane pairs dup-write
    #pragma unroll
    for (int i = 0; i < F; ++i) {
      pmax[srow + CB + base + i] = acc[i];
      pmin[srow + CB + base2 + i] = tmn[i];
    }
  }
}

// ---------------------------------------------------------------- BN2+relu on pooled pre-BN max/min
template<int C2, int BOFF>
__global__ __launch_bounds__(256) void outbn_kernel(const float* __restrict__ pmax,
                                                    const float* __restrict__ pmin,
                                                    const float* __restrict__ scsh,
                                                    float* __restrict__ out) {
  const int g = blockIdx.x * 256 + threadIdx.x;     // g < 8192 * C2
  const int c = g & (C2 - 1);
  const int sample = g / C2;
  const float sc = scsh[512 + c], sh = scsh[640 + c];
  const float xv = (sc >= 0.f) ? pmax[g] : pmin[g]; // max/BN commutation, exact
  out[(size_t)sample * 320 + BOFF + c] = fmaxf(0.f, sc * xv + sh);
}

// ---------------------------------------------------------------- host side
template<int K_, int C0, int C1, int C2, int BOFF, bool XS1>
static void run_branch(const float* pts, const int* knn_,
                       const float* const* W_, const float* const* B_,
                       const float* const* G_, const float* const* BE_,
                       float* scshb, float* partials, float* partials2,
                       const v2h* w1pb, const v2h* w2pb,
                       __half* x1t, float* pmax, float* pmin,
                       float* out, hipStream_t stream) {
  constexpr int T = 128;
  constexpr int NE = 8 * 1024 * K_;
  constexpr int NB = NE / T;
  pass_kernel<K_, C0, C1, C2, 1, T, XS1><<<NB, T, 0, stream>>>(
      pts, knn_, W_[0], B_[0], w1pb, B_[1], w2pb, B_[2], scshb, partials, x1t, pmax, pmin);
  reduce_rows_kernel<<<32, 256, 0, stream>>>(partials, NB, partials2);
  finalize_kernel<<<1, 256, 0, stream>>>(partials2, 32, G_[1], BE_[1], (float)NE,
                                         scshb + 256, scshb + 384, C1);
  pass_kernel<K_, C0, C1, C2, 2, T, XS1><<<NB, T, 0, stream>>>(
      pts, knn_, W_[0], B_[0], w1pb, B_[1], w2pb, B_[2], scshb, partials, x1t, pmax, pmin);
  reduce_rows_kernel<<<32, 256, 0, stream>>>(partials, NB, partials2);
  finalize_kernel<<<1, 256, 0, stream>>>(partials2, 32, G_[2], BE_[2], (float)NE,
                                         scshb + 512, scshb + 640, C2);
  outbn_kernel<C2, BOFF><<<8192 * C2 / 256, 256, 0, stream>>>(pmax, pmin, scshb, out);
}

template<bool XS1>
static void run_all(const float* pts, const int* knn_,
                    const float* const* W_, const float* const* B_,
                    const float* const* G_, const float* const* BE_,
                    float* scsh, float* partials, float* partials2,
                    const v2h* w1h2, const v2h* w2h2,
                    __half* x1t, float* pmax, float* pmin,
                    float* out, hipStream_t stream) {
  run_branch<16, 32, 32, 64, 0, XS1>(pts, knn_, W_ + 0, B_ + 0, G_ + 0, BE_ + 0,
      scsh, partials, partials2, w1h2, w2h2, x1t, pmax, pmin, out, stream);
  run_branch<32, 64, 64, 128, 64, XS1>(pts, knn_, W_ + 3, B_ + 3, G_ + 3, BE_ + 3,
      scsh + 768, partials, partials2, w1h2 + 512, w2h2 + 1024, x1t, pmax, pmin, out, stream);
  run_branch<64, 64, 96, 128, 192, XS1>(pts, knn_, W_ + 6, B_ + 6, G_ + 6, BE_ + 6,
      scsh + 1536, partials, partials2, w1h2 + 2560, w2h2 + 5120, x1t, pmax, pmin, out, stream);
}

extern "C" void kernel_launch(void* const* d_in, const int* in_sizes, int n_in,
                              void* d_out, int out_size, void* d_ws, size_t ws_size,
                              hipStream_t stream) {
  (void)in_sizes; (void)n_in; (void)out_size;
  const float* pts = (const float*)d_in[0];
  const float* W_[9]; const float* B_[9]; const float* G_[9]; const float* BE_[9];
  for (int m = 0; m < 9; ++m) {
    W_[m]  = (const float*)d_in[1 + m * 4 + 0];
    B_[m]  = (const float*)d_in[1 + m * 4 + 1];
    G_[m]  = (const float*)d_in[1 + m * 4 + 2];
    BE_[m] = (const float*)d_in[1 + m * 4 + 3];
  }
  char* ws = (char*)d_ws;
  float4* cent      = (float4*)ws;                          // @0,        131072 B
  int*    knn_      = (int*)(ws + 131072);                  // 2 MB
  float*  partials  = (float*)(ws + 2228224);               // 4 MB (also mpart)
  float*  scsh      = (float*)(ws + 6422528);               // 12 KB
  v2h*    w1h2      = (v2h*)(ws + 6434816);                 // 22528 B
  v2h*    w2h2      = (v2h*)(ws + 6457344);                 // 45056 B
  float*  partials2 = (float*)(ws + 6502400);               // 32 KB
  float*  pmax      = (float*)(ws + 6535168);               // 4 MB (8192*128*4)
  float*  pmin      = (float*)(ws + 6535168 + 4194304);     // 4 MB
  __half* x1t       = (__half*)(ws + 6535168 + 8388608);    // 100663296 B max
  float*  out       = (float*)d_out;
  const bool xs1 = ws_size >= 6535168ull + 8388608ull + 100663296ull;  // ~110 MB

  fps_kernel<<<8, 512, 0, stream>>>(pts, cent);
  knn_kernel<<<2048, 256, 0, stream>>>(pts, cent, knn_);
  moments_kernel<<<2048, 256, 0, stream>>>(pts, knn_, partials);
  finalize0_kernel<<<1, 256, 0, stream>>>(partials,
      W_[0], B_[0], G_[0], BE_[0], W_[3], B_[3], G_[3], BE_[3],
      W_[6], B_[6], G_[6], BE_[6], scsh);
  pack_kernel<<<66, 256, 0, stream>>>(W_[1], W_[4], W_[7], W_[2], W_[5], W_[8], w1h2, w2h2);

  if (xs1)
    run_all<true>(pts, knn_, W_, B_, G_, BE_, scsh, partials, partials2,
                  w1h2, w2h2, x1t, pmax, pmin, out, stream);
  else
    run_all<false>(pts, knn_, W_, B_, G_, BE_, scsh, partials, partials2,
                   w1h2, w2h2, x1t, pmax, pmin, out, stream);
}

// Round 13
// 2062.936 us; speedup vs baseline: 4.3613x; 1.0748x over previous
//
#include <hip/hip_runtime.h>
#include <hip/hip_fp16.h>

#define DEVFN __device__ __forceinline__

typedef _Float16 v2h __attribute__((ext_vector_type(2)));

DEVFN float fdot2(v2h a, v2h b, float c) {
#if __has_builtin(__builtin_amdgcn_fdot2)
  return __builtin_amdgcn_fdot2(a, b, c, false);
#else
  return c + (float)a[0] * (float)b[0] + (float)a[1] * (float)b[1];
#endif
}

// ---------------------------------------------------------------- utilities
struct OpSum { DEVFN float operator()(float a, float b) const { return a + b; } };
struct OpMax { DEVFN float operator()(float a, float b) const { return fmaxf(a, b); } };
struct OpMin { DEVFN float operator()(float a, float b) const { return fminf(a, b); } };

template<int CH, int D, typename OP, int NV>
DEVFN void halve(float (&v)[NV], int lane, int& base) {
  if constexpr (D >= 1) {
    OP op;
    if constexpr (CH > 1) {
      constexpr int H = CH / 2;
      #pragma unroll
      for (int i = 0; i < H; ++i) {
        float send = (lane & D) ? v[i] : v[H + i];
        float r = __shfl_xor(send, D);
        float keep = (lane & D) ? v[H + i] : v[i];
        v[i] = op(keep, r);
      }
      if (lane & D) base += H;
      halve<H, (D >> 1), OP, NV>(v, lane, base);
    } else {
      v[0] = op(v[0], __shfl_xor(v[0], D));
      halve<CH, (D >> 1), OP, NV>(v, lane, base);
    }
  }
}

// Sum + sumsq of channels a[OFF..OFF+CC) across all T threads of the block.
template<int CC, int OFF, int NA, int T>
DEVFN void do_stats(const float (&a)[NA], int tid, float* spart, float* prow, int statoff) {
  float v[2 * CC];
  #pragma unroll
  for (int j = 0; j < CC; ++j) { float x = a[OFF + j]; v[2 * j] = x; v[2 * j + 1] = x * x; }
  int lane = tid & 63, base = 0;
  halve<2 * CC, 32, OpSum, 2 * CC>(v, lane, base);
  constexpr int F = (2 * CC) / 64 > 0 ? (2 * CC) / 64 : 1;
  int wv = tid >> 6;
  #pragma unroll
  for (int i = 0; i < F; ++i) spart[wv * 256 + base + i] = v[i];
  __syncthreads();
  constexpr int NW = T / 64;
  if (tid < 2 * CC) {
    float s2 = 0.f;
    #pragma unroll
    for (int w = 0; w < NW; ++w) s2 += spart[w * 256 + tid];
    prow[statoff + tid] = s2;
  }
  __syncthreads();
}

// ---------------------------------------------------------------- FPS
// f32-only max butterfly (1 shuffle/level — halves the LDS-pipe traffic of
// the u64 version) + ballot winner select. Exact tie across lanes (rare,
// wave-uniform branch) falls back to min-index reduce. Selection semantics
// identical to the proven u64-key butterfly.
__global__ __launch_bounds__(512) void fps_kernel(const float* __restrict__ pts,
                                                  float4* __restrict__ cent) {
  const int b = blockIdx.x, t = threadIdx.x;
  const int wv = t >> 6;
  __shared__ unsigned long long sk2[2][8];
  __shared__ float4 sc4[2][8];
  __shared__ float4 scent[1024];
  const float* p = pts + (size_t)b * 8192 * 3;
  float px[16], py[16], pz[16], dd[16];
  #pragma unroll
  for (int j = 0; j < 16; ++j) {
    const int i = t + j * 512;
    px[j] = p[i * 3]; py[j] = p[i * 3 + 1]; pz[j] = p[i * 3 + 2];
    dd[j] = 1e10f;
  }
  float cx = p[0], cy = p[1], cz = p[2];
  for (int it = 0; it < 1024; ++it) {
    if (t == 0) scent[it] = make_float4(cx, cy, cz, 0.f);
    const int par = it & 1;
    float bd = -1.f, bx = 0.f, by = 0.f, bz = 0.f; int bi = 0;
    #pragma unroll
    for (int j = 0; j < 16; ++j) {
      const float dx = px[j] - cx, dy = py[j] - cy, dz = pz[j] - cz;
      float d = fminf(dd[j], dx * dx + dy * dy + dz * dz);
      dd[j] = d;
      if (d > bd) { bd = d; bi = t + j * 512; bx = px[j]; by = py[j]; bz = pz[j]; }
    }
    float wmax = bd;
    #pragma unroll
    for (int m = 32; m >= 1; m >>= 1) wmax = fmaxf(wmax, __shfl_xor(wmax, m));
    const unsigned long long am = __ballot(bd == wmax);
    bool iswin;
    if (__popcll(am) == 1) {
      iswin = (bd == wmax);
    } else {                               // exact fp tie across lanes: min idx wins
      int cand = (bd == wmax) ? bi : 0x7FFFFFFF;
      #pragma unroll
      for (int m = 32; m >= 1; m >>= 1) cand = min(cand, __shfl_xor(cand, m));
      iswin = (bd == wmax) && (bi == cand);
    }
    if (iswin) {                           // unique winning lane of this wave
      sk2[par][wv] = ((unsigned long long)__float_as_uint(bd) << 32)
                     | (0xFFFFFFFFu - (unsigned)bi);
      sc4[par][wv] = make_float4(bx, by, bz, 0.f);
    }
    __syncthreads();
    unsigned long long gk = sk2[par][0];
    float4 c4 = sc4[par][0];
    #pragma unroll
    for (int w = 1; w < 8; ++w) {
      const unsigned long long k2 = sk2[par][w];
      const float4 cc = sc4[par][w];
      if (k2 > gk) { gk = k2; c4 = cc; }
    }
    cx = c4.x; cy = c4.y; cz = c4.z;
  }
  __syncthreads();
  #pragma unroll
  for (int i = t; i < 1024; i += 512) cent[(size_t)b * 1024 + i] = scent[i];
}

// ---------------------------------------------------------------- kNN
__global__ __launch_bounds__(256) void knn_kernel(const float* __restrict__ pts,
                                                  const float4* __restrict__ cent,
                                                  int* __restrict__ knn) {
  const int wid = (blockIdx.x * 256 + threadIdx.x) >> 6;
  const int lane = threadIdx.x & 63;
  const int b = wid >> 10;
  const float4 q = cent[wid];
  const float q2 = q.x * q.x + q.y * q.y + q.z * q.z;
  const float* p = pts + (size_t)b * 8192 * 3;
  unsigned long long R = ~0ull;
  for (int c0 = 0; c0 < 8192; c0 += 64) {
    const int i = c0 + lane;
    const float x = p[i * 3], y = p[i * 3 + 1], z = p[i * 3 + 2];
    const float p2 = x * x + y * y + z * z;
    const float dot = q.x * x + q.y * y + q.z * z;
    float d2 = q2 - 2.f * dot + p2;
    d2 = fmaxf(d2, 0.f);
    unsigned u = __float_as_uint(d2);
    u = (u & 0x80000000u) ? ~u : (u | 0x80000000u);
    const unsigned long long key = ((unsigned long long)u << 32) | (unsigned)i;
    const unsigned long long rmax = __shfl(R, 63);
    unsigned long long mask = __ballot(key < rmax);
    while (mask) {
      const int src = __ffsll(mask) - 1;
      mask &= mask - 1;
      const unsigned long long nk = __shfl(key, src);
      const int pos = __popcll(__ballot(R < nk));
      if (pos < 64) {
        const unsigned long long Rm1 = __shfl_up(R, 1);
        R = (lane < pos) ? R : (lane == pos ? nk : Rm1);
      }
    }
  }
  knn[wid * 64 + lane] = (int)(R & 0xffffffffu);
}

// ---------------------------------------------------------------- gather moments (BN0 stats)
__global__ __launch_bounds__(256) void moments_kernel(const float* __restrict__ pts,
                                                      const int* __restrict__ knn_,
                                                      float* __restrict__ mpart) {
  __shared__ float smom[4][27];
  const int tid = threadIdx.x, lane = tid & 63, wv = tid >> 6;
  const int samp = blockIdx.x * 4 + wv;
  const int b = samp >> 10;
  const int pidx = knn_[samp * 64 + lane];
  const float* pp = pts + ((size_t)b * 8192 + pidx) * 3;
  const float x = pp[0], y = pp[1], z = pp[2];
  float g[9] = {x, y, z, x * x, x * y, x * z, y * y, y * z, z * z};
  #pragma unroll
  for (int m = 8; m >= 1; m >>= 1) {
    #pragma unroll
    for (int i = 0; i < 9; ++i) g[i] += __shfl_xor(g[i], m);
  }
  float h[9], tot[9];
  #pragma unroll
  for (int i = 0; i < 9; ++i) h[i] = g[i] + __shfl_xor(g[i], 16);
  #pragma unroll
  for (int i = 0; i < 9; ++i) tot[i] = h[i] + __shfl_xor(h[i], 32);
  if (lane == 0) {
    #pragma unroll
    for (int i = 0; i < 9; ++i) {
      smom[wv][i] = g[i]; smom[wv][9 + i] = h[i]; smom[wv][18 + i] = tot[i];
    }
  }
  __syncthreads();
  if (tid < 27) {
    mpart[blockIdx.x * 32 + tid] =
        smom[0][tid] + smom[1][tid] + smom[2][tid] + smom[3][tid];
  }
}

// ---------------------------------------------------------------- BN0 finalize (all 3 branches)
__global__ __launch_bounds__(256) void finalize0_kernel(const float* __restrict__ mpart,
    const float* __restrict__ w00, const float* __restrict__ b00,
    const float* __restrict__ g00, const float* __restrict__ be00,
    const float* __restrict__ w01, const float* __restrict__ b01,
    const float* __restrict__ g01, const float* __restrict__ be01,
    const float* __restrict__ w02, const float* __restrict__ b02,
    const float* __restrict__ g02, const float* __restrict__ be02,
    float* __restrict__ scsh) {
  __shared__ float fsum[8][32];
  __shared__ float mom[32];
  const int t = threadIdx.x;
  const int col = t & 31, chunk = t >> 5;
  float s = 0.f;
  for (int r = chunk * 256; r < chunk * 256 + 256; ++r) s += mpart[r * 32 + col];
  fsum[chunk][col] = s;
  __syncthreads();
  if (t < 32) {
    float s2 = 0.f;
    #pragma unroll
    for (int c = 0; c < 8; ++c) s2 += fsum[c][t];
    mom[t] = s2;
  }
  __syncthreads();
  int o; const float *w, *bb, *gg, *be; float E; int base, br;
  if (t < 32)       { br = 0; o = t;      w = w00; bb = b00; gg = g00; be = be00; E = 131072.f; base = 0; }
  else if (t < 96)  { br = 1; o = t - 32; w = w01; bb = b01; gg = g01; be = be01; E = 262144.f; base = 9; }
  else if (t < 160) { br = 2; o = t - 96; w = w02; bb = b02; gg = g02; be = be02; E = 524288.f; base = 18; }
  else return;
  const float Sx = mom[base], Sy = mom[base + 1], Sz = mom[base + 2];
  const float mxx = mom[base + 3], mxy = mom[base + 4], mxz = mom[base + 5];
  const float myy = mom[base + 6], myz = mom[base + 7], mzz = mom[base + 8];
  const float W0 = w[o * 3], W1 = w[o * 3 + 1], W2 = w[o * 3 + 2], bo = bb[o];
  const float wS = W0 * Sx + W1 * Sy + W2 * Sz;
  const float qf = W0 * W0 * mxx + 2.f * W0 * W1 * mxy + 2.f * W0 * W2 * mxz
                 + W1 * W1 * myy + 2.f * W1 * W2 * myz + W2 * W2 * mzz;
  const float mean = wS / E + bo;
  const float msq = (qf + 2.f * bo * wS) / E + bo * bo;
  const float var = msq - mean * mean;
  const float inv = 1.0f / sqrtf(var + 1e-5f);
  const float sc = gg[o] * inv;
  scsh[br * 768 + o] = sc;
  scsh[br * 768 + 128 + o] = be[o] - mean * sc;
}

// ---------------------------------------------------------------- pack w1/w2 as half2 pairs
__global__ __launch_bounds__(256) void pack_kernel(
    const float* __restrict__ w1a, const float* __restrict__ w1b, const float* __restrict__ w1c,
    const float* __restrict__ w2a, const float* __restrict__ w2b, const float* __restrict__ w2c,
    v2h* __restrict__ w1h2, v2h* __restrict__ w2h2) {
  const int i = blockIdx.x * 256 + threadIdx.x;
  if (i < 512) {                                   // b1 w1: C0=32, C1=32
    const int o = i >> 4, c2 = i & 15;
    w1h2[i] = v2h{(_Float16)w1a[o * 32 + 2 * c2], (_Float16)w1a[o * 32 + 2 * c2 + 1]};
  } else if (i < 2560) {                           // b2 w1: C0=64, C1=64
    const int j = i - 512, o = j >> 5, c2 = j & 31;
    w1h2[i] = v2h{(_Float16)w1b[o * 64 + 2 * c2], (_Float16)w1b[o * 64 + 2 * c2 + 1]};
  } else if (i < 5632) {                           // b3 w1: C0=64, C1=96
    const int j = i - 2560, o = j >> 5, c2 = j & 31;
    w1h2[i] = v2h{(_Float16)w1c[o * 64 + 2 * c2], (_Float16)w1c[o * 64 + 2 * c2 + 1]};
  } else if (i < 6656) {                           // b1 w2: C1=32, C2=64
    const int j = i - 5632, c2 = j >> 6, jj = j & 63;
    w2h2[j] = v2h{(_Float16)w2a[jj * 32 + 2 * c2], (_Float16)w2a[jj * 32 + 2 * c2 + 1]};
  } else if (i < 10752) {                          // b2 w2: C1=64, C2=128
    const int j = i - 6656, c2 = j >> 7, jj = j & 127;
    w2h2[1024 + j] = v2h{(_Float16)w2b[jj * 64 + 2 * c2], (_Float16)w2b[jj * 64 + 2 * c2 + 1]};
  } else if (i < 16896) {                          // b3 w2: C1=96, C2=128
    const int j = i - 10752, c2 = j >> 7, jj = j & 127;
    w2h2[5120 + j] = v2h{(_Float16)w2c[jj * 96 + 2 * c2], (_Float16)w2c[jj * 96 + 2 * c2 + 1]};
  }
}

// ---------------------------------------------------------------- x1 stats (streaming, from fp16 x1t)
// Block (o, slice): per-channel sum/sumsq over NE/16 contiguous elements.
// Writes finalize_kernel-compatible rows: out32[slice*256 + 2o{,+1}], nb=16.
__global__ __launch_bounds__(256) void x1stats_kernel(const __half2* __restrict__ x1t2,
                                                      int NE2, float* __restrict__ out32) {
  const int o = blockIdx.x >> 4, sl = blockIdx.x & 15;
  const int tid = threadIdx.x, lane = tid & 63, wv = tid >> 6;
  const int chunk = NE2 >> 4;
  const __half2* base = x1t2 + (size_t)o * NE2 + (size_t)sl * chunk;
  float sum = 0.f, sq = 0.f;
  for (int i = tid; i < chunk; i += 256) {
    const float2 f = __half22float2(base[i]);
    sum += f.x + f.y;
    sq = fmaf(f.x, f.x, sq);
    sq = fmaf(f.y, f.y, sq);
  }
  #pragma unroll
  for (int m = 32; m >= 1; m >>= 1) { sum += __shfl_xor(sum, m); sq += __shfl_xor(sq, m); }
  __shared__ float ss[4][2];
  if (lane == 0) { ss[wv][0] = sum; ss[wv][1] = sq; }
  __syncthreads();
  if (tid == 0) {
    out32[sl * 256 + 2 * o]     = ss[0][0] + ss[1][0] + ss[2][0] + ss[3][0];
    out32[sl * 256 + 2 * o + 1] = ss[0][1] + ss[1][1] + ss[2][1] + ss[3][1];
  }
}

// ---------------------------------------------------------------- stats reduction, stage A
__global__ __launch_bounds__(256) void reduce_rows_kernel(const float* __restrict__ partials,
                                                          int nb, float* __restrict__ out32) {
  const int r0 = blockIdx.x, j = threadIdx.x;
  const int chunk = (nb + 31) / 32;
  const int lo = r0 * chunk;
  const int hi = (lo + chunk < nb) ? lo + chunk : nb;
  float s = 0.f;
  for (int r = lo; r < hi; ++r) s += partials[(size_t)r * 256 + j];
  out32[r0 * 256 + j] = s;
}

// ---------------------------------------------------------------- BN finalize
__global__ __launch_bounds__(256) void finalize_kernel(const float* __restrict__ partials, int nb,
    const float* __restrict__ g, const float* __restrict__ be, float n,
    float* __restrict__ sc, float* __restrict__ sh, int CO) {
  __shared__ float tot[256];
  const int j = threadIdx.x;
  if (j < 2 * CO) {
    float s = 0.f;
    for (int r = 0; r < nb; ++r) s += partials[(size_t)r * 256 + j];
    tot[j] = s;
  }
  __syncthreads();
  if (j < CO) {
    const float m = tot[2 * j] / n;
    const float v = tot[2 * j + 1] / n - m * m;
    const float inv = 1.0f / sqrtf(v + 1e-5f);
    const float scv = g[j] * inv;
    sc[j] = scv;
    sh[j] = be[j] - m * scv;
  }
}

// ---------------------------------------------------------------- fused MLP pass (dot2)
// L=1, XS1: gather + L0 + BN0 + L1 -> store x1t only (stats done by x1stats).
// L=1, !XS1: as before with in-pass chunked stats.
// L=2: XS1: read x1t, BN1+relu -> arowv; else recompute. L2 + stats + pre-BN
//      max/min pool over K -> pmax/pmin (exact fp32).
template<int K_, int C0, int C1, int C2, int L, int T, bool XS1>
__global__ __launch_bounds__(T) void pass_kernel(
    const float* __restrict__ pts, const int* __restrict__ knnidx,
    const float* __restrict__ w0, const float* __restrict__ b0,
    const v2h* __restrict__ w1p, const float* __restrict__ b1,
    const v2h* __restrict__ w2p, const float* __restrict__ b2,
    const float* __restrict__ scsh, float* __restrict__ partials,
    __half* __restrict__ x1t, float* __restrict__ pmax, float* __restrict__ pmin) {
  constexpr int C02 = C0 / 2;
  constexpr int C12 = C1 / 2;
  constexpr int RSv = C12 + 1;                       // odd dword stride -> conflict-free
  constexpr int NAROW = (L >= 2) ? T * RSv : 1;
  constexpr size_t NE = (size_t)8 * 1024 * K_;
  __shared__ v2h arowv[NAROW];
  __shared__ float spart[(T / 64) * 256];
  const int tid = threadIdx.x;
  const int lane = tid & 63;
  const int e = blockIdx.x * T + tid;
  const int b = e / (1024 * K_);
  const int rem = e - b * (1024 * K_);
  const int s = rem / K_;
  float* prow = partials + (size_t)blockIdx.x * 256;

  v2h a0p[C02];
  if constexpr (!(XS1 && L == 2)) {
    const int pidx = knnidx[(b * 1024 + s) * 64 + (rem - s * K_)];
    const float* pp = pts + ((size_t)b * 8192 + pidx) * 3;
    const float zx = pp[0], zy = pp[1], zz = pp[2];
    const float* sc0 = scsh + 0;
    const float* sh0 = scsh + 128;
    #pragma unroll
    for (int c2 = 0; c2 < C02; ++c2) {
      float va = b0[2 * c2]     + zx * w0[6 * c2]     + zy * w0[6 * c2 + 1] + zz * w0[6 * c2 + 2];
      float vb = b0[2 * c2 + 1] + zx * w0[6 * c2 + 3] + zy * w0[6 * c2 + 4] + zz * w0[6 * c2 + 5];
      va = fmaxf(0.f, va * sc0[2 * c2] + sh0[2 * c2]);
      vb = fmaxf(0.f, vb * sc0[2 * c2 + 1] + sh0[2 * c2 + 1]);
      a0p[c2] = v2h{(_Float16)va, (_Float16)vb};
    }
  }

  // layer 1 (C0 -> C1)
  if constexpr (L == 1) {
    if constexpr (XS1) {
      // store-only: stats computed from x1t by x1stats_kernel
      #pragma unroll
      for (int o = 0; o < C1; ++o) {
        float s0 = 0.f, s1 = 0.f;
        #pragma unroll
        for (int c2 = 0; c2 < C02; c2 += 2) {
          s0 = fdot2(a0p[c2],     w1p[o * C02 + c2],     s0);
          s1 = fdot2(a0p[c2 + 1], w1p[o * C02 + c2 + 1], s1);
        }
        x1t[(size_t)o * NE + e] = __float2half(b1[o] + (s0 + s1));
      }
    } else {
      #pragma unroll
      for (int CB = 0; CB < C1; CB += 32) {
        float arr[32];
        #pragma unroll
        for (int oo = 0; oo < 32; ++oo) {
          const int o = CB + oo;
          float s0 = 0.f, s1 = 0.f;
          #pragma unroll
          for (int c2 = 0; c2 < C02; c2 += 2) {
            s0 = fdot2(a0p[c2],     w1p[o * C02 + c2],     s0);
            s1 = fdot2(a0p[c2 + 1], w1p[o * C02 + c2 + 1], s1);
          }
          arr[oo] = b1[o] + (s0 + s1);
        }
        do_stats<32, 0, 32, T>(arr, tid, spart, prow, 2 * CB);
      }
    }
    return;
  }

  // L == 2: act1 -> LDS (half2)
  {
    const float* sc1 = scsh + 256;
    const float* sh1 = scsh + 384;
    if constexpr (XS1) {
      for (int o2 = 0; o2 < C12; ++o2) {
        float xa = __half2float(x1t[(size_t)(2 * o2) * NE + e]);
        float xb = __half2float(x1t[(size_t)(2 * o2 + 1) * NE + e]);
        xa = fmaxf(0.f, xa * sc1[2 * o2] + sh1[2 * o2]);
        xb = fmaxf(0.f, xb * sc1[2 * o2 + 1] + sh1[2 * o2 + 1]);
        arowv[tid * RSv + o2] = v2h{(_Float16)xa, (_Float16)xb};
      }
    } else {
      for (int o2 = 0; o2 < C12; ++o2) {
        float xv[2];
        #pragma unroll
        for (int tt = 0; tt < 2; ++tt) {
          const int o = 2 * o2 + tt;
          float s0 = 0.f, s1 = 0.f;
          #pragma unroll
          for (int c2 = 0; c2 < C02; c2 += 2) {
            s0 = fdot2(a0p[c2],     w1p[o * C02 + c2],     s0);
            s1 = fdot2(a0p[c2 + 1], w1p[o * C02 + c2 + 1], s1);
          }
          const float x = b1[o] + (s0 + s1);
          xv[tt] = fmaxf(0.f, x * sc1[o] + sh1[o]);
        }
        arowv[tid * RSv + o2] = v2h{(_Float16)xv[0], (_Float16)xv[1]};
      }
    }
  }

  // layer 2 (C1 -> C2): stats + pre-BN max/min pool over K
  const size_t srow = (size_t)(b * 1024 + s) * C2;
  #pragma unroll
  for (int CB = 0; CB < C2; CB += 32) {
    float acc[32];
    #pragma unroll
    for (int j = 0; j < 32; ++j) acc[j] = b2[CB + j];
    for (int c2 = 0; c2 < C12; ++c2) {
      const v2h az = arowv[tid * RSv + c2];
      const v2h* wrow = w2p + c2 * C2 + CB;
      #pragma unroll
      for (int j = 0; j < 32; ++j) acc[j] = fdot2(az, wrow[j], acc[j]);
    }
    do_stats<32, 0, 32, T>(acc, tid, spart, prow, 2 * CB);
    float tmn[32];
    #pragma unroll
    for (int j = 0; j < 32; ++j) tmn[j] = acc[j];
    int base = 0;
    halve<32, (K_ >> 1), OpMax, 32>(acc, lane, base);
    int base2 = 0;
    halve<32, (K_ >> 1), OpMin, 32>(tmn, lane, base2);
    constexpr int F = (32 / K_ > 0) ? (32 / K_) : 1;  // K=64: lane pairs dup-write
    #pragma unroll
    for (int i = 0; i < F; ++i) {
      pmax[srow + CB + base + i] = acc[i];
      pmin[srow + CB + base2 + i] = tmn[i];
    }
  }
}

// ---------------------------------------------------------------- BN2+relu on pooled pre-BN max/min
template<int C2, int BOFF>
__global__ __launch_bounds__(256) void outbn_kernel(const float* __restrict__ pmax,
                                                    const float* __restrict__ pmin,
                                                    const float* __restrict__ scsh,
                                                    float* __restrict__ out) {
  const int g = blockIdx.x * 256 + threadIdx.x;     // g < 8192 * C2
  const int c = g & (C2 - 1);
  const int sample = g / C2;
  const float sc = scsh[512 + c], sh = scsh[640 + c];
  const float xv = (sc >= 0.f) ? pmax[g] : pmin[g]; // max/BN commutation, exact
  out[(size_t)sample * 320 + BOFF + c] = fmaxf(0.f, sc * xv + sh);
}

// ---------------------------------------------------------------- host side
template<int K_, int C0, int C1, int C2, int BOFF, bool XS1>
static void run_branch(const float* pts, const int* knn_,
                       const float* const* W_, const float* const* B_,
                       const float* const* G_, const float* const* BE_,
                       float* scshb, float* partials, float* partials2,
                       const v2h* w1pb, const v2h* w2pb,
                       __half* x1t, float* pmax, float* pmin,
                       float* out, hipStream_t stream) {
  constexpr int T = 128;
  constexpr int NE = 8 * 1024 * K_;
  constexpr int NB = NE / T;
  pass_kernel<K_, C0, C1, C2, 1, T, XS1><<<NB, T, 0, stream>>>(
      pts, knn_, W_[0], B_[0], w1pb, B_[1], w2pb, B_[2], scshb, partials, x1t, pmax, pmin);
  if constexpr (XS1) {
    x1stats_kernel<<<C1 * 16, 256, 0, stream>>>((const __half2*)x1t, NE / 2, partials2);
    finalize_kernel<<<1, 256, 0, stream>>>(partials2, 16, G_[1], BE_[1], (float)NE,
                                           scshb + 256, scshb + 384, C1);
  } else {
    reduce_rows_kernel<<<32, 256, 0, stream>>>(partials, NB, partials2);
    finalize_kernel<<<1, 256, 0, stream>>>(partials2, 32, G_[1], BE_[1], (float)NE,
                                           scshb + 256, scshb + 384, C1);
  }
  pass_kernel<K_, C0, C1, C2, 2, T, XS1><<<NB, T, 0, stream>>>(
      pts, knn_, W_[0], B_[0], w1pb, B_[1], w2pb, B_[2], scshb, partials, x1t, pmax, pmin);
  reduce_rows_kernel<<<32, 256, 0, stream>>>(partials, NB, partials2);
  finalize_kernel<<<1, 256, 0, stream>>>(partials2, 32, G_[2], BE_[2], (float)NE,
                                         scshb + 512, scshb + 640, C2);
  outbn_kernel<C2, BOFF><<<8192 * C2 / 256, 256, 0, stream>>>(pmax, pmin, scshb, out);
}

template<bool XS1>
static void run_all(const float* pts, const int* knn_,
                    const float* const* W_, const float* const* B_,
                    const float* const* G_, const float* const* BE_,
                    float* scsh, float* partials, float* partials2,
                    const v2h* w1h2, const v2h* w2h2,
                    __half* x1t, float* pmax, float* pmin,
                    float* out, hipStream_t stream) {
  run_branch<16, 32, 32, 64, 0, XS1>(pts, knn_, W_ + 0, B_ + 0, G_ + 0, BE_ + 0,
      scsh, partials, partials2, w1h2, w2h2, x1t, pmax, pmin, out, stream);
  run_branch<32, 64, 64, 128, 64, XS1>(pts, knn_, W_ + 3, B_ + 3, G_ + 3, BE_ + 3,
      scsh + 768, partials, partials2, w1h2 + 512, w2h2 + 1024, x1t, pmax, pmin, out, stream);
  run_branch<64, 64, 96, 128, 192, XS1>(pts, knn_, W_ + 6, B_ + 6, G_ + 6, BE_ + 6,
      scsh + 1536, partials, partials2, w1h2 + 2560, w2h2 + 5120, x1t, pmax, pmin, out, stream);
}

extern "C" void kernel_launch(void* const* d_in, const int* in_sizes, int n_in,
                              void* d_out, int out_size, void* d_ws, size_t ws_size,
                              hipStream_t stream) {
  (void)in_sizes; (void)n_in; (void)out_size;
  const float* pts = (const float*)d_in[0];
  const float* W_[9]; const float* B_[9]; const float* G_[9]; const float* BE_[9];
  for (int m = 0; m < 9; ++m) {
    W_[m]  = (const float*)d_in[1 + m * 4 + 0];
    B_[m]  = (const float*)d_in[1 + m * 4 + 1];
    G_[m]  = (const float*)d_in[1 + m * 4 + 2];
    BE_[m] = (const float*)d_in[1 + m * 4 + 3];
  }
  char* ws = (char*)d_ws;
  float4* cent      = (float4*)ws;                          // @0,        131072 B
  int*    knn_      = (int*)(ws + 131072);                  // 2 MB
  float*  partials  = (float*)(ws + 2228224);               // 4 MB (also mpart)
  float*  scsh      = (float*)(ws + 6422528);               // 12 KB
  v2h*    w1h2      = (v2h*)(ws + 6434816);                 // 22528 B
  v2h*    w2h2      = (v2h*)(ws + 6457344);                 // 45056 B
  float*  partials2 = (float*)(ws + 6502400);               // 32 KB
  float*  pmax      = (float*)(ws + 6535168);               // 4 MB (8192*128*4)
  float*  pmin      = (float*)(ws + 6535168 + 4194304);     // 4 MB
  __half* x1t       = (__half*)(ws + 6535168 + 8388608);    // 100663296 B max
  float*  out       = (float*)d_out;
  const bool xs1 = ws_size >= 6535168ull + 8388608ull + 100663296ull;  // ~110 MB

  fps_kernel<<<8, 512, 0, stream>>>(pts, cent);
  knn_kernel<<<2048, 256, 0, stream>>>(pts, cent, knn_);
  moments_kernel<<<2048, 256, 0, stream>>>(pts, knn_, partials);
  finalize0_kernel<<<1, 256, 0, stream>>>(partials,
      W_[0], B_[0], G_[0], BE_[0], W_[3], B_[3], G_[3], BE_[3],
      W_[6], B_[6], G_[6], BE_[6], scsh);
  pack_kernel<<<66, 256, 0, stream>>>(W_[1], W_[4], W_[7], W_[2], W_[5], W_[8], w1h2, w2h2);

  if (xs1)
    run_all<true>(pts, knn_, W_, B_, G_, BE_, scsh, partials, partials2,
                  w1h2, w2h2, x1t, pmax, pmin, out, stream);
  else
    run_all<false>(pts, knn_, W_, B_, G_, BE_, scsh, partials, partials2,
                   w1h2, w2h2, x1t, pmax, pmin, out, stream);
}

// Round 14
// 1887.419 us; speedup vs baseline: 4.7669x; 1.0930x over previous
//
#include <hip/hip_runtime.h>
#include <hip/hip_fp16.h>

#define DEVFN __device__ __forceinline__

typedef _Float16 v2h __attribute__((ext_vector_type(2)));

DEVFN float fdot2(v2h a, v2h b, float c) {
#if __has_builtin(__builtin_amdgcn_fdot2)
  return __builtin_amdgcn_fdot2(a, b, c, false);
#else
  return c + (float)a[0] * (float)b[0] + (float)a[1] * (float)b[1];
#endif
}

// ---------------------------------------------------------------- utilities
struct OpSum { DEVFN float operator()(float a, float b) const { return a + b; } };

template<int CH, int D, typename OP, int NV>
DEVFN void halve(float (&v)[NV], int lane, int& base) {
  if constexpr (D >= 1) {
    OP op;
    if constexpr (CH > 1) {
      constexpr int H = CH / 2;
      #pragma unroll
      for (int i = 0; i < H; ++i) {
        float send = (lane & D) ? v[i] : v[H + i];
        float r = __shfl_xor(send, D);
        float keep = (lane & D) ? v[H + i] : v[i];
        v[i] = op(keep, r);
      }
      if (lane & D) base += H;
      halve<H, (D >> 1), OP, NV>(v, lane, base);
    } else {
      v[0] = op(v[0], __shfl_xor(v[0], D));
      halve<CH, (D >> 1), OP, NV>(v, lane, base);
    }
  }
}

// Multiplicity-weighted sum + sumsq of a[0..CC) across T threads.
// v_sum = m*x, v_sq = m*x*x -> exactly the gathered-multiset stats.
template<int CC, int NA, int T>
DEVFN void do_stats_w(const float (&a)[NA], float m, int tid, float* spart,
                      float* prow, int statoff) {
  float v[2 * CC];
  #pragma unroll
  for (int j = 0; j < CC; ++j) { float x = a[j]; v[2 * j] = m * x; v[2 * j + 1] = m * x * x; }
  int lane = tid & 63, base = 0;
  halve<2 * CC, 32, OpSum, 2 * CC>(v, lane, base);
  int wv = tid >> 6;
  spart[wv * 256 + base] = v[0];
  __syncthreads();
  constexpr int NW = T / 64;
  if (tid < 2 * CC) {
    float s2 = 0.f;
    #pragma unroll
    for (int w = 0; w < NW; ++w) s2 += spart[w * 256 + tid];
    prow[statoff + tid] = s2;
  }
  __syncthreads();
}

// ---------------------------------------------------------------- FPS (structural floor)
__global__ __launch_bounds__(512) void fps_kernel(const float* __restrict__ pts,
                                                  float4* __restrict__ cent) {
  const int b = blockIdx.x, t = threadIdx.x;
  const int wv = t >> 6;
  __shared__ unsigned long long sk2[2][8];
  __shared__ float4 sc4[2][8];
  __shared__ float4 scent[1024];
  const float* p = pts + (size_t)b * 8192 * 3;
  float px[16], py[16], pz[16], dd[16];
  #pragma unroll
  for (int j = 0; j < 16; ++j) {
    const int i = t + j * 512;
    px[j] = p[i * 3]; py[j] = p[i * 3 + 1]; pz[j] = p[i * 3 + 2];
    dd[j] = 1e10f;
  }
  float cx = p[0], cy = p[1], cz = p[2];
  for (int it = 0; it < 1024; ++it) {
    if (t == 0) scent[it] = make_float4(cx, cy, cz, 0.f);
    const int par = it & 1;
    float bd = -1.f, bx = 0.f, by = 0.f, bz = 0.f; int bi = 0;
    #pragma unroll
    for (int j = 0; j < 16; ++j) {
      const float dx = px[j] - cx, dy = py[j] - cy, dz = pz[j] - cz;
      float d = fminf(dd[j], dx * dx + dy * dy + dz * dz);
      dd[j] = d;
      if (d > bd) { bd = d; bi = t + j * 512; bx = px[j]; by = py[j]; bz = pz[j]; }
    }
    float wmax = bd;
    #pragma unroll
    for (int m = 32; m >= 1; m >>= 1) wmax = fmaxf(wmax, __shfl_xor(wmax, m));
    const unsigned long long am = __ballot(bd == wmax);
    bool iswin;
    if (__popcll(am) == 1) {
      iswin = (bd == wmax);
    } else {
      int cand = (bd == wmax) ? bi : 0x7FFFFFFF;
      #pragma unroll
      for (int m = 32; m >= 1; m >>= 1) cand = min(cand, __shfl_xor(cand, m));
      iswin = (bd == wmax) && (bi == cand);
    }
    if (iswin) {
      sk2[par][wv] = ((unsigned long long)__float_as_uint(bd) << 32)
                     | (0xFFFFFFFFu - (unsigned)bi);
      sc4[par][wv] = make_float4(bx, by, bz, 0.f);
    }
    __syncthreads();
    unsigned long long gk = sk2[par][0];
    float4 c4 = sc4[par][0];
    #pragma unroll
    for (int w = 1; w < 8; ++w) {
      const unsigned long long k2 = sk2[par][w];
      const float4 cc = sc4[par][w];
      if (k2 > gk) { gk = k2; c4 = cc; }
    }
    cx = c4.x; cy = c4.y; cz = c4.z;
  }
  __syncthreads();
  #pragma unroll
  for (int i = t; i < 1024; i += 512) cent[(size_t)b * 1024 + i] = scent[i];
}

// ---------------------------------------------------------------- kNN
__global__ __launch_bounds__(256) void knn_kernel(const float* __restrict__ pts,
                                                  const float4* __restrict__ cent,
                                                  int* __restrict__ knn) {
  const int wid = (blockIdx.x * 256 + threadIdx.x) >> 6;
  const int lane = threadIdx.x & 63;
  const int b = wid >> 10;
  const float4 q = cent[wid];
  const float q2 = q.x * q.x + q.y * q.y + q.z * q.z;
  const float* p = pts + (size_t)b * 8192 * 3;
  unsigned long long R = ~0ull;
  for (int c0 = 0; c0 < 8192; c0 += 64) {
    const int i = c0 + lane;
    const float x = p[i * 3], y = p[i * 3 + 1], z = p[i * 3 + 2];
    const float p2 = x * x + y * y + z * z;
    const float dot = q.x * x + q.y * y + q.z * z;
    float d2 = q2 - 2.f * dot + p2;
    d2 = fmaxf(d2, 0.f);
    unsigned u = __float_as_uint(d2);
    u = (u & 0x80000000u) ? ~u : (u | 0x80000000u);
    const unsigned long long key = ((unsigned long long)u << 32) | (unsigned)i;
    const unsigned long long rmax = __shfl(R, 63);
    unsigned long long mask = __ballot(key < rmax);
    while (mask) {
      const int src = __ffsll(mask) - 1;
      mask &= mask - 1;
      const unsigned long long nk = __shfl(key, src);
      const int pos = __popcll(__ballot(R < nk));
      if (pos < 64) {
        const unsigned long long Rm1 = __shfl_up(R, 1);
        R = (lane < pos) ? R : (lane == pos ? nk : Rm1);
      }
    }
  }
  knn[wid * 64 + lane] = (int)(R & 0xffffffffu);
}

// ---------------------------------------------------------------- gather moments (BN0 stats)
__global__ __launch_bounds__(256) void moments_kernel(const float* __restrict__ pts,
                                                      const int* __restrict__ knn_,
                                                      float* __restrict__ mpart) {
  __shared__ float smom[4][27];
  const int tid = threadIdx.x, lane = tid & 63, wv = tid >> 6;
  const int samp = blockIdx.x * 4 + wv;
  const int b = samp >> 10;
  const int pidx = knn_[samp * 64 + lane];
  const float* pp = pts + ((size_t)b * 8192 + pidx) * 3;
  const float x = pp[0], y = pp[1], z = pp[2];
  float g[9] = {x, y, z, x * x, x * y, x * z, y * y, y * z, z * z};
  #pragma unroll
  for (int m = 8; m >= 1; m >>= 1) {
    #pragma unroll
    for (int i = 0; i < 9; ++i) g[i] += __shfl_xor(g[i], m);
  }
  float h[9], tot[9];
  #pragma unroll
  for (int i = 0; i < 9; ++i) h[i] = g[i] + __shfl_xor(g[i], 16);
  #pragma unroll
  for (int i = 0; i < 9; ++i) tot[i] = h[i] + __shfl_xor(h[i], 32);
  if (lane == 0) {
    #pragma unroll
    for (int i = 0; i < 9; ++i) {
      smom[wv][i] = g[i]; smom[wv][9 + i] = h[i]; smom[wv][18 + i] = tot[i];
    }
  }
  __syncthreads();
  if (tid < 27) {
    mpart[blockIdx.x * 32 + tid] =
        smom[0][tid] + smom[1][tid] + smom[2][tid] + smom[3][tid];
  }
}

// ---------------------------------------------------------------- BN0 finalize (all 3 branches)
__global__ __launch_bounds__(256) void finalize0_kernel(const float* __restrict__ mpart,
    const float* __restrict__ w00, const float* __restrict__ b00,
    const float* __restrict__ g00, const float* __restrict__ be00,
    const float* __restrict__ w01, const float* __restrict__ b01,
    const float* __restrict__ g01, const float* __restrict__ be01,
    const float* __restrict__ w02, const float* __restrict__ b02,
    const float* __restrict__ g02, const float* __restrict__ be02,
    float* __restrict__ scsh) {
  __shared__ float fsum[8][32];
  __shared__ float mom[32];
  const int t = threadIdx.x;
  const int col = t & 31, chunk = t >> 5;
  float s = 0.f;
  for (int r = chunk * 256; r < chunk * 256 + 256; ++r) s += mpart[r * 32 + col];
  fsum[chunk][col] = s;
  __syncthreads();
  if (t < 32) {
    float s2 = 0.f;
    #pragma unroll
    for (int c = 0; c < 8; ++c) s2 += fsum[c][t];
    mom[t] = s2;
  }
  __syncthreads();
  int o; const float *w, *bb, *gg, *be; float E; int base, br;
  if (t < 32)       { br = 0; o = t;      w = w00; bb = b00; gg = g00; be = be00; E = 131072.f; base = 0; }
  else if (t < 96)  { br = 1; o = t - 32; w = w01; bb = b01; gg = g01; be = be01; E = 262144.f; base = 9; }
  else if (t < 160) { br = 2; o = t - 96; w = w02; bb = b02; gg = g02; be = be02; E = 524288.f; base = 18; }
  else return;
  const float Sx = mom[base], Sy = mom[base + 1], Sz = mom[base + 2];
  const float mxx = mom[base + 3], mxy = mom[base + 4], mxz = mom[base + 5];
  const float myy = mom[base + 6], myz = mom[base + 7], mzz = mom[base + 8];
  const float W0 = w[o * 3], W1 = w[o * 3 + 1], W2 = w[o * 3 + 2], bo = bb[o];
  const float wS = W0 * Sx + W1 * Sy + W2 * Sz;
  const float qf = W0 * W0 * mxx + 2.f * W0 * W1 * mxy + 2.f * W0 * W2 * mxz
                 + W1 * W1 * myy + 2.f * W1 * W2 * myz + W2 * W2 * mzz;
  const float mean = wS / E + bo;
  const float msq = (qf + 2.f * bo * wS) / E + bo * bo;
  const float var = msq - mean * mean;
  const float inv = 1.0f / sqrtf(var + 1e-5f);
  const float sc = gg[o] * inv;
  scsh[br * 768 + o] = sc;
  scsh[br * 768 + 128 + o] = be[o] - mean * sc;
}

// ---------------------------------------------------------------- pack w1/w2 as half2 pairs
__global__ __launch_bounds__(256) void pack_kernel(
    const float* __restrict__ w1a, const float* __restrict__ w1b, const float* __restrict__ w1c,
    const float* __restrict__ w2a, const float* __restrict__ w2b, const float* __restrict__ w2c,
    v2h* __restrict__ w1h2, v2h* __restrict__ w2h2) {
  const int i = blockIdx.x * 256 + threadIdx.x;
  if (i < 512) {                                   // b1 w1: C0=32, C1=32
    const int o = i >> 4, c2 = i & 15;
    w1h2[i] = v2h{(_Float16)w1a[o * 32 + 2 * c2], (_Float16)w1a[o * 32 + 2 * c2 + 1]};
  } else if (i < 2560) {                           // b2 w1: C0=64, C1=64
    const int j = i - 512, o = j >> 5, c2 = j & 31;
    w1h2[i] = v2h{(_Float16)w1b[o * 64 + 2 * c2], (_Float16)w1b[o * 64 + 2 * c2 + 1]};
  } else if (i < 5632) {                           // b3 w1: C0=64, C1=96
    const int j = i - 2560, o = j >> 5, c2 = j & 31;
    w1h2[i] = v2h{(_Float16)w1c[o * 64 + 2 * c2], (_Float16)w1c[o * 64 + 2 * c2 + 1]};
  } else if (i < 6656) {                           // b1 w2: C1=32, C2=64
    const int j = i - 5632, c2 = j >> 6, jj = j & 63;
    w2h2[j] = v2h{(_Float16)w2a[jj * 32 + 2 * c2], (_Float16)w2a[jj * 32 + 2 * c2 + 1]};
  } else if (i < 10752) {                          // b2 w2: C1=64, C2=128
    const int j = i - 6656, c2 = j >> 7, jj = j & 127;
    w2h2[1024 + j] = v2h{(_Float16)w2b[jj * 64 + 2 * c2], (_Float16)w2b[jj * 64 + 2 * c2 + 1]};
  } else if (i < 16896) {                          // b3 w2: C1=96, C2=128
    const int j = i - 10752, c2 = j >> 7, jj = j & 127;
    w2h2[5120 + j] = v2h{(_Float16)w2c[jj * 96 + 2 * c2], (_Float16)w2c[jj * 96 + 2 * c2 + 1]};
  }
}

// ---------------------------------------------------------------- zero + histogram (multiplicities)
__global__ __launch_bounds__(256) void zero_kernel(int* __restrict__ p, int n) {
  const int i = blockIdx.x * 256 + threadIdx.x;
  if (i < n) p[i] = 0;
}

// cnt layout: [0,65536)=K16, [65536,131072)=K32, [131072,196608)=K64.
__global__ __launch_bounds__(256) void hist_kernel(const int* __restrict__ knn_,
                                                   int* __restrict__ cnt) {
  const int e = blockIdx.x * 256 + threadIdx.x;    // 524288 entries
  const int s = e >> 6, k = e & 63;
  const int b = s >> 10;
  const int idx = b * 8192 + knn_[e];
  atomicAdd(&cnt[131072 + idx], 1);
  if (k < 32) atomicAdd(&cnt[65536 + idx], 1);
  if (k < 16) atomicAdd(&cnt[idx], 1);
}

// ---------------------------------------------------------------- stats reduction, stage A
__global__ __launch_bounds__(256) void reduce_rows_kernel(const float* __restrict__ partials,
                                                          int nb, float* __restrict__ out32) {
  const int r0 = blockIdx.x, j = threadIdx.x;
  const int chunk = (nb + 31) / 32;
  const int lo = r0 * chunk;
  const int hi = (lo + chunk < nb) ? lo + chunk : nb;
  float s = 0.f;
  for (int r = lo; r < hi; ++r) s += partials[(size_t)r * 256 + j];
  out32[r0 * 256 + j] = s;
}

// ---------------------------------------------------------------- BN finalize
__global__ __launch_bounds__(256) void finalize_kernel(const float* __restrict__ partials, int nb,
    const float* __restrict__ g, const float* __restrict__ be, float n,
    float* __restrict__ sc, float* __restrict__ sh, int CO) {
  __shared__ float tot[256];
  const int j = threadIdx.x;
  if (j < 2 * CO) {
    float s = 0.f;
    for (int r = 0; r < nb; ++r) s += partials[(size_t)r * 256 + j];
    tot[j] = s;
  }
  __syncthreads();
  if (j < CO) {
    const float m = tot[2 * j] / n;
    const float v = tot[2 * j + 1] / n - m * m;
    const float inv = 1.0f / sqrtf(v + 1e-5f);
    const float scv = g[j] * inv;
    sc[j] = scv;
    sh[j] = be[j] - m * scv;
  }
}

// ---------------------------------------------------------------- pass1: distinct points, L0+BN0+L1
// Thread = one of 65536 distinct points. Stores pre-BN x1 (fp16, channel-major)
// + multiplicity-weighted stats (exact gathered-multiset sums).
template<int C0, int C1, int T>
__global__ __launch_bounds__(T) void pass1_kernel(
    const float* __restrict__ pts, const int* __restrict__ cnt,
    const float* __restrict__ w0, const float* __restrict__ b0,
    const v2h* __restrict__ w1p, const float* __restrict__ b1,
    const float* __restrict__ scshb, float* __restrict__ partials,
    __half* __restrict__ x1pts) {
  constexpr int C02 = C0 / 2;
  __shared__ float spart[(T / 64) * 256];
  const int tid = threadIdx.x;
  const int pt = blockIdx.x * T + tid;
  const float m = (float)cnt[pt];
  const float* pp = pts + (size_t)pt * 3;
  float* prow = partials + (size_t)blockIdx.x * 256;
  const float zx = pp[0], zy = pp[1], zz = pp[2];
  const float* sc0 = scshb;
  const float* sh0 = scshb + 128;
  v2h a0p[C02];
  #pragma unroll
  for (int c2 = 0; c2 < C02; ++c2) {
    float va = b0[2 * c2]     + zx * w0[6 * c2]     + zy * w0[6 * c2 + 1] + zz * w0[6 * c2 + 2];
    float vb = b0[2 * c2 + 1] + zx * w0[6 * c2 + 3] + zy * w0[6 * c2 + 4] + zz * w0[6 * c2 + 5];
    va = fmaxf(0.f, va * sc0[2 * c2] + sh0[2 * c2]);
    vb = fmaxf(0.f, vb * sc0[2 * c2 + 1] + sh0[2 * c2 + 1]);
    a0p[c2] = v2h{(_Float16)va, (_Float16)vb};
  }
  for (int CB = 0; CB < C1; CB += 32) {
    float arr[32];
    #pragma unroll
    for (int oo = 0; oo < 32; ++oo) {
      const int o = CB + oo;
      float s0 = 0.f, s1 = 0.f;
      #pragma unroll
      for (int c2 = 0; c2 < C02; c2 += 2) {
        s0 = fdot2(a0p[c2],     w1p[o * C02 + c2],     s0);
        s1 = fdot2(a0p[c2 + 1], w1p[o * C02 + c2 + 1], s1);
      }
      const float x = b1[o] + (s0 + s1);
      x1pts[(size_t)o * 65536 + pt] = __float2half(x);
      arr[oo] = x;
    }
    do_stats_w<32, 32, T>(arr, m, tid, spart, prow, 2 * CB);
  }
}

// ---------------------------------------------------------------- pass2: BN1+relu+L2 on distinct points
// Stores pre-BN x2 rows (fp32, row-major) + weighted stats.
template<int C1, int C2, int T>
__global__ __launch_bounds__(T) void pass2_kernel(
    const __half* __restrict__ x1pts, const int* __restrict__ cnt,
    const v2h* __restrict__ w2p, const float* __restrict__ b2,
    const float* __restrict__ scshb, float* __restrict__ partials,
    float* __restrict__ x2pts) {
  constexpr int C12 = C1 / 2;
  constexpr int RSv = C12 + 1;                   // odd dword stride -> conflict-free
  __shared__ v2h arowv[T * RSv];
  __shared__ float spart[(T / 64) * 256];
  const int tid = threadIdx.x;
  const int pt = blockIdx.x * T + tid;
  const float m = (float)cnt[pt];
  float* prow = partials + (size_t)blockIdx.x * 256;
  const float* sc1 = scshb + 256;
  const float* sh1 = scshb + 384;
  for (int o2 = 0; o2 < C12; ++o2) {
    float xa = __half2float(x1pts[(size_t)(2 * o2) * 65536 + pt]);
    float xb = __half2float(x1pts[(size_t)(2 * o2 + 1) * 65536 + pt]);
    xa = fmaxf(0.f, xa * sc1[2 * o2] + sh1[2 * o2]);
    xb = fmaxf(0.f, xb * sc1[2 * o2 + 1] + sh1[2 * o2 + 1]);
    arowv[tid * RSv + o2] = v2h{(_Float16)xa, (_Float16)xb};
  }
  for (int CB = 0; CB < C2; CB += 32) {
    float acc[32];
    #pragma unroll
    for (int j = 0; j < 32; ++j) acc[j] = b2[CB + j];
    for (int c2 = 0; c2 < C12; ++c2) {
      const v2h az = arowv[tid * RSv + c2];
      const v2h* wrow = w2p + c2 * C2 + CB;
      #pragma unroll
      for (int j = 0; j < 32; ++j) acc[j] = fdot2(az, wrow[j], acc[j]);
    }
    #pragma unroll
    for (int j = 0; j < 32; ++j) x2pts[(size_t)pt * C2 + CB + j] = acc[j];
    do_stats_w<32, 32, T>(acc, m, tid, spart, prow, 2 * CB);
  }
}

// ---------------------------------------------------------------- pool: gather-max + BN2 + relu
// Block per sample, thread per channel; k-loop row reads are coalesced.
template<int K_, int C2, int BOFF>
__global__ __launch_bounds__(C2) void pool_kernel(const float* __restrict__ x2pts,
                                                  const int* __restrict__ knn_,
                                                  const float* __restrict__ scshb,
                                                  float* __restrict__ out) {
  const int s = blockIdx.x;                      // 0..8191
  const int c = threadIdx.x;                     // 0..C2-1
  const int b = s >> 10;
  const float sc = scshb[512 + c], sh = scshb[640 + c];
  const int* kn = knn_ + s * 64;
  float mx = -1e30f, mn = 1e30f;
  for (int k = 0; k < K_; ++k) {
    const int idx = kn[k];                       // wave-uniform
    const float x = x2pts[((size_t)(b * 8192 + idx)) * C2 + c];
    mx = fmaxf(mx, x); mn = fminf(mn, x);
  }
  const float xv = (sc >= 0.f) ? mx : mn;        // max/BN commutation, exact
  out[(size_t)s * 320 + BOFF + c] = fmaxf(0.f, fmaf(sc, xv, sh));
}

// ---------------------------------------------------------------- host side
template<int K_, int C0, int C1, int C2, int BOFF>
static void run_branch(const float* pts, const int* knn_, const int* cntb,
                       const float* const* W_, const float* const* B_,
                       const float* const* G_, const float* const* BE_,
                       float* scshb, float* partials, float* partials2,
                       const v2h* w1pb, const v2h* w2pb,
                       __half* x1pts, float* x2pts, float* out, hipStream_t stream) {
  constexpr int T = 128;
  constexpr int NB = 65536 / T;                  // 512
  const float NEf = (float)(8 * 1024 * K_);
  pass1_kernel<C0, C1, T><<<NB, T, 0, stream>>>(
      pts, cntb, W_[0], B_[0], w1pb, B_[1], scshb, partials, x1pts);
  reduce_rows_kernel<<<32, 256, 0, stream>>>(partials, NB, partials2);
  finalize_kernel<<<1, 256, 0, stream>>>(partials2, 32, G_[1], BE_[1], NEf,
                                         scshb + 256, scshb + 384, C1);
  pass2_kernel<C1, C2, T><<<NB, T, 0, stream>>>(
      x1pts, cntb, w2pb, B_[2], scshb, partials, x2pts);
  reduce_rows_kernel<<<32, 256, 0, stream>>>(partials, NB, partials2);
  finalize_kernel<<<1, 256, 0, stream>>>(partials2, 32, G_[2], BE_[2], NEf,
                                         scshb + 512, scshb + 640, C2);
  pool_kernel<K_, C2, BOFF><<<8192, C2, 0, stream>>>(x2pts, knn_, scshb, out);
}

extern "C" void kernel_launch(void* const* d_in, const int* in_sizes, int n_in,
                              void* d_out, int out_size, void* d_ws, size_t ws_size,
                              hipStream_t stream) {
  (void)in_sizes; (void)n_in; (void)out_size; (void)ws_size;
  const float* pts = (const float*)d_in[0];
  const float* W_[9]; const float* B_[9]; const float* G_[9]; const float* BE_[9];
  for (int m = 0; m < 9; ++m) {
    W_[m]  = (const float*)d_in[1 + m * 4 + 0];
    B_[m]  = (const float*)d_in[1 + m * 4 + 1];
    G_[m]  = (const float*)d_in[1 + m * 4 + 2];
    BE_[m] = (const float*)d_in[1 + m * 4 + 3];
  }
  char* ws = (char*)d_ws;
  float4* cent      = (float4*)ws;                          // @0,        131072 B
  int*    knn_      = (int*)(ws + 131072);                  // 2 MB
  float*  partials  = (float*)(ws + 2228224);               // 4 MB (also mpart)
  float*  scsh      = (float*)(ws + 6422528);               // 12 KB
  v2h*    w1h2      = (v2h*)(ws + 6434816);                 // 22528 B
  v2h*    w2h2      = (v2h*)(ws + 6457344);                 // 45056 B
  float*  partials2 = (float*)(ws + 6502400);               // 32 KB
  int*    cnt       = (int*)(ws + 6535168);                 // 786432 B (3 x 65536)
  __half* x1pts     = (__half*)(ws + 7321600);              // 12582912 B (96 x 65536 x 2)
  float*  x2pts     = (float*)(ws + 19904512);              // 33554432 B (65536 x 128 x 4)
  float*  out       = (float*)d_out;

  fps_kernel<<<8, 512, 0, stream>>>(pts, cent);
  knn_kernel<<<2048, 256, 0, stream>>>(pts, cent, knn_);
  moments_kernel<<<2048, 256, 0, stream>>>(pts, knn_, partials);
  finalize0_kernel<<<1, 256, 0, stream>>>(partials,
      W_[0], B_[0], G_[0], BE_[0], W_[3], B_[3], G_[3], BE_[3],
      W_[6], B_[6], G_[6], BE_[6], scsh);
  pack_kernel<<<66, 256, 0, stream>>>(W_[1], W_[4], W_[7], W_[2], W_[5], W_[8], w1h2, w2h2);
  zero_kernel<<<768, 256, 0, stream>>>(cnt, 196608);
  hist_kernel<<<2048, 256, 0, stream>>>(knn_, cnt);

  run_branch<16, 32, 32, 64, 0>(pts, knn_, cnt, W_ + 0, B_ + 0, G_ + 0, BE_ + 0,
      scsh, partials, partials2, w1h2, w2h2, x1pts, x2pts, out, stream);
  run_branch<32, 64, 64, 128, 64>(pts, knn_, cnt + 65536, W_ + 3, B_ + 3, G_ + 3, BE_ + 3,
      scsh + 768, partials, partials2, w1h2 + 512, w2h2 + 1024, x1pts, x2pts, out, stream);
  run_branch<64, 64, 96, 128, 192>(pts, knn_, cnt + 131072, W_ + 6, B_ + 6, G_ + 6, BE_ + 6,
      scsh + 1536, partials, partials2, w1h2 + 2560, w2h2 + 5120, x1pts, x2pts, out, stream);
}